// Round 1
// baseline (640.725 us; speedup 1.0000x reference)
//
#include <hip/hip_runtime.h>
#include <hip/hip_bf16.h>

#define NN 50000
#define NE 800000
// IN=128, HID=32, HEADS=4, HC=128, OUT=40, EDIM=5

// ---------------------------------------------------------------------------
// K0: fold edge-weight matrices with attention vectors.
// wf1[j*4+h] = sum_c We1[j,128] column block h*32+c  *  att_edge1[h*32+c]
// wf2[j]    = sum_c We2[j,40][c] * att_edge2[c]
__global__ void fold_kernel(const float* __restrict__ We1, const float* __restrict__ ae1w,
                            const float* __restrict__ We2, const float* __restrict__ ae2w,
                            float* __restrict__ wf1, float* __restrict__ wf2) {
    int t = threadIdx.x;
    if (t < 20) {
        int j = t >> 2, h = t & 3;
        float s = 0.f;
        for (int c = 0; c < 32; ++c) s += We1[j * 128 + h * 32 + c] * ae1w[h * 32 + c];
        wf1[j * 4 + h] = s;
    }
    if (t >= 32 && t < 37) {
        int j = t - 32;
        float s = 0.f;
        for (int c = 0; c < 40; ++c) s += We2[j * 40 + c] * ae2w[c];
        wf2[j] = s;
    }
}

// ---------------------------------------------------------------------------
// K1: per-edge: in-degree count + folded edge logits for both layers.
__global__ __launch_bounds__(256) void edge_pre_kernel(
    const int* __restrict__ dst0, const float* __restrict__ eattr,
    const float* __restrict__ wf1, const float* __restrict__ wf2,
    int* __restrict__ cnt, float* __restrict__ ae1, float* __restrict__ ae2) {
    int e = blockIdx.x * 256 + threadIdx.x;
    if (e >= NE) return;
    atomicAdd(&cnt[dst0[e]], 1);
    float a[5];
#pragma unroll
    for (int j = 0; j < 5; ++j) a[j] = eattr[(size_t)e * 5 + j];
    float4 o;
    float* op = (float*)&o;
#pragma unroll
    for (int h = 0; h < 4; ++h) {
        float s = 0.f;
#pragma unroll
        for (int j = 0; j < 5; ++j) s += a[j] * wf1[j * 4 + h];
        op[h] = s;
    }
    *(float4*)&ae1[(size_t)e * 4] = o;
    float s2 = 0.f;
#pragma unroll
    for (int j = 0; j < 5; ++j) s2 += a[j] * wf2[j];
    ae2[e] = s2;
}

// ---------------------------------------------------------------------------
// K2: exclusive scan of cnt -> off (single block, 1024 threads).
__global__ void scan_kernel(const int* __restrict__ cnt, int* __restrict__ off) {
    __shared__ int sums[1024];
    const int C = (NN + 1023) / 1024;
    int t = threadIdx.x;
    int base = t * C;
    int s = 0;
    for (int i = 0; i < C; ++i) {
        int idx = base + i;
        if (idx < NN) s += cnt[idx];
    }
    sums[t] = s;
    __syncthreads();
    for (int d = 1; d < 1024; d <<= 1) {
        int v = (t >= d) ? sums[t - d] : 0;
        __syncthreads();
        sums[t] += v;
        __syncthreads();
    }
    int run = sums[t] - s;  // exclusive
    for (int i = 0; i < C; ++i) {
        int idx = base + i;
        if (idx < NN) { off[idx] = run; run += cnt[idx]; }
    }
    if (t == 1023) off[NN] = run;
}

// ---------------------------------------------------------------------------
// K3: fill CSR (grouped by dst).
__global__ __launch_bounds__(256) void csr_fill_kernel(
    const int* __restrict__ dst0, const int* __restrict__ off,
    int* __restrict__ cur, int* __restrict__ csr) {
    int e = blockIdx.x * 256 + threadIdx.x;
    if (e >= NE) return;
    int d = dst0[e];
    int p = atomicAdd(&cur[d], 1);
    csr[off[d] + p] = e;
}

// ---------------------------------------------------------------------------
// K4: per-node self-loop edge attr (mean of incoming) -> folded logits.
__global__ __launch_bounds__(256) void loop_pre_kernel(
    const int* __restrict__ off, const int* __restrict__ csr,
    const float* __restrict__ eattr, const float* __restrict__ wf1,
    const float* __restrict__ wf2, float* __restrict__ ae1L, float* __restrict__ ae2L) {
    int n = blockIdx.x * 256 + threadIdx.x;
    if (n >= NN) return;
    int b = off[n], e1 = off[n + 1];
    float s[5] = {0.f, 0.f, 0.f, 0.f, 0.f};
    for (int i = b; i < e1; ++i) {
        int e = csr[i];
#pragma unroll
        for (int j = 0; j < 5; ++j) s[j] += eattr[(size_t)e * 5 + j];
    }
    float inv = 1.f / fmaxf((float)(e1 - b), 1.f);
#pragma unroll
    for (int j = 0; j < 5; ++j) s[j] *= inv;
    float4 o;
    float* op = (float*)&o;
#pragma unroll
    for (int h = 0; h < 4; ++h) {
        float t = 0.f;
#pragma unroll
        for (int j = 0; j < 5; ++j) t += s[j] * wf1[j * 4 + h];
        op[h] = t;
    }
    *(float4*)&ae1L[(size_t)n * 4] = o;
    float t2 = 0.f;
#pragma unroll
    for (int j = 0; j < 5; ++j) t2 += s[j] * wf2[j];
    ae2L[n] = t2;
}

// ---------------------------------------------------------------------------
// K5: GEMM1: xs1[N,128] = x[N,128] @ W1[128,128]. Tile 64 rows x 128 cols,
// k chunked by 64 in LDS; thread = 8 rows x 4 cols.
__global__ __launch_bounds__(256) void gemm1_kernel(
    const float* __restrict__ A, const float* __restrict__ W, float* __restrict__ out) {
    __shared__ float sW[64 * 132];   // stride 132 breaks bank aliasing
    __shared__ float sXT[64 * 72];   // transposed x tile, stride 72
    int t = threadIdx.x;
    int row0 = blockIdx.x * 64;
    int cg = t & 31;   // cols 4cg..4cg+3
    int rg = t >> 5;   // rows rg*8..rg*8+7
    float acc[8][4];
#pragma unroll
    for (int i = 0; i < 8; ++i)
#pragma unroll
        for (int j = 0; j < 4; ++j) acc[i][j] = 0.f;

    for (int kk = 0; kk < 128; kk += 64) {
        for (int i = t; i < 64 * 128; i += 256) {
            int k = i >> 7, c = i & 127;
            sW[k * 132 + c] = W[(size_t)(kk + k) * 128 + c];
        }
        for (int i = t; i < 64 * 64; i += 256) {
            int r = i >> 6, k = i & 63;
            int gr = row0 + r;
            sXT[k * 72 + r] = (gr < NN) ? A[(size_t)gr * 128 + kk + k] : 0.f;
        }
        __syncthreads();
#pragma unroll 4
        for (int k = 0; k < 64; ++k) {
            float4 b = *(const float4*)&sW[k * 132 + cg * 4];
            float4 a0 = *(const float4*)&sXT[k * 72 + rg * 8];
            float4 a1 = *(const float4*)&sXT[k * 72 + rg * 8 + 4];
            float av[8] = {a0.x, a0.y, a0.z, a0.w, a1.x, a1.y, a1.z, a1.w};
#pragma unroll
            for (int i = 0; i < 8; ++i) {
                acc[i][0] += av[i] * b.x;
                acc[i][1] += av[i] * b.y;
                acc[i][2] += av[i] * b.z;
                acc[i][3] += av[i] * b.w;
            }
        }
        __syncthreads();
    }
#pragma unroll
    for (int i = 0; i < 8; ++i) {
        int gr = row0 + rg * 8 + i;
        if (gr < NN) *(float4*)&out[(size_t)gr * 128 + cg * 4] = *(float4*)&acc[i][0];
    }
}

// ---------------------------------------------------------------------------
// K6: per-node attention coefficients for layer 1: as1[n,h], ad1[n,h].
__global__ __launch_bounds__(256) void alpha1_kernel(
    const float* __restrict__ xs1, const float* __restrict__ asw,
    const float* __restrict__ adw, float* __restrict__ as1, float* __restrict__ ad1) {
    int wid = (blockIdx.x * 256 + threadIdx.x) >> 6;
    if (wid >= NN) return;
    int lane = threadIdx.x & 63;
    int c = lane * 2;
    float2 v = *(const float2*)&xs1[(size_t)wid * 128 + c];
    float pa = v.x * asw[c] + v.y * asw[c + 1];
    float pd = v.x * adw[c] + v.y * adw[c + 1];
#pragma unroll
    for (int d = 8; d >= 1; d >>= 1) {
        pa += __shfl_xor(pa, d, 16);
        pd += __shfl_xor(pd, d, 16);
    }
    if ((lane & 15) == 0) {
        as1[wid * 4 + (lane >> 4)] = pa;
        ad1[wid * 4 + (lane >> 4)] = pd;
    }
}

// ---------------------------------------------------------------------------
// K7: layer-1 GAT aggregation. One wave per dst node. Fused softmax
// (deferred denominator), bias, BN(eval), ELU.
__global__ __launch_bounds__(256) void gat1_kernel(
    const int* __restrict__ src0, const int* __restrict__ csr, const int* __restrict__ off,
    const float* __restrict__ xs1, const float* __restrict__ as1, const float* __restrict__ ad1,
    const float* __restrict__ ae1, const float* __restrict__ ae1L,
    const float* __restrict__ b1, const float* __restrict__ g1, const float* __restrict__ be1,
    const float* __restrict__ rm1, const float* __restrict__ rv1, float* __restrict__ h1out) {
    int wid = (blockIdx.x * 256 + threadIdx.x) >> 6;
    if (wid >= NN) return;
    int lane = threadIdx.x & 63;
    int n = wid;
    int e0 = off[n], e1 = off[n + 1];
    int deg = e1 - e0;
    int h = lane >> 4;
    float adh = ad1[n * 4 + h];
    float aL = as1[n * 4 + h] + adh + ae1L[n * 4 + h];
    aL = aL >= 0.f ? aL : 0.2f * aL;
    float m = aL;
    // pass A: per-head max. Lanes q=lane&15 split the edge list; 4 head groups.
    int q = lane & 15;
    for (int i = q; i < deg; i += 16) {
        int e = csr[e0 + i];
        int s = src0[e];
        float a = as1[s * 4 + h] + adh + ae1[(size_t)e * 4 + h];
        a = a >= 0.f ? a : 0.2f * a;
        m = fmaxf(m, a);
    }
#pragma unroll
    for (int d = 8; d >= 1; d >>= 1) m = fmaxf(m, __shfl_xor(m, d, 16));
    // pass B: weighted aggregation, serial over edges (whole wave per edge).
    float denom, acc0, acc1;
    {
        float w = __expf(aL - m);
        denom = w;
        float2 v = *(const float2*)&xs1[(size_t)n * 128 + lane * 2];
        acc0 = v.x * w;
        acc1 = v.y * w;
    }
    for (int i = 0; i < deg; ++i) {
        int e = csr[e0 + i];
        int s = src0[e];
        float a = as1[s * 4 + h] + adh + ae1[(size_t)e * 4 + h];
        a = a >= 0.f ? a : 0.2f * a;
        float w = __expf(a - m);
        denom += w;
        float2 v = *(const float2*)&xs1[(size_t)s * 128 + lane * 2];
        acc0 += v.x * w;
        acc1 += v.y * w;
    }
    float inv = 1.f / (denom + 1e-16f);
    int c0 = lane * 2;
    float o0 = acc0 * inv + b1[c0];
    float o1 = acc1 * inv + b1[c0 + 1];
    float sc0 = g1[c0] * rsqrtf(rv1[c0] + 1e-5f);
    float sc1 = g1[c0 + 1] * rsqrtf(rv1[c0 + 1] + 1e-5f);
    o0 = (o0 - rm1[c0]) * sc0 + be1[c0];
    o1 = (o1 - rm1[c0 + 1]) * sc1 + be1[c0 + 1];
    o0 = o0 > 0.f ? o0 : __expf(o0) - 1.f;
    o1 = o1 > 0.f ? o1 : __expf(o1) - 1.f;
    *(float2*)&h1out[(size_t)n * 128 + c0] = make_float2(o0, o1);
}

// ---------------------------------------------------------------------------
// K8: GEMM2: xs2[N,40] = h1[N,128] @ W2[128,40]. Tile 96 rows; thread 8r x 2c.
__global__ __launch_bounds__(256) void gemm2_kernel(
    const float* __restrict__ A, const float* __restrict__ W, float* __restrict__ out) {
    __shared__ float sW[128 * 40];
    __shared__ float sXT[128 * 104];  // stride 104
    int t = threadIdx.x;
    int row0 = blockIdx.x * 96;
    for (int i = t; i < 128 * 40; i += 256) sW[i] = W[i];
    for (int i = t; i < 128 * 96; i += 256) {
        int r = i >> 7, k = i & 127;
        int gr = row0 + r;
        sXT[k * 104 + r] = (gr < NN) ? A[(size_t)gr * 128 + k] : 0.f;
    }
    __syncthreads();
    if (t < 240) {
        int cg = t % 20;  // cols 2cg, 2cg+1
        int rg = t / 20;  // rows rg*8..rg*8+7
        float acc[8][2];
#pragma unroll
        for (int i = 0; i < 8; ++i) { acc[i][0] = 0.f; acc[i][1] = 0.f; }
#pragma unroll 4
        for (int k = 0; k < 128; ++k) {
            float2 b = *(const float2*)&sW[k * 40 + cg * 2];
            float4 a0 = *(const float4*)&sXT[k * 104 + rg * 8];
            float4 a1 = *(const float4*)&sXT[k * 104 + rg * 8 + 4];
            float av[8] = {a0.x, a0.y, a0.z, a0.w, a1.x, a1.y, a1.z, a1.w};
#pragma unroll
            for (int i = 0; i < 8; ++i) {
                acc[i][0] += av[i] * b.x;
                acc[i][1] += av[i] * b.y;
            }
        }
#pragma unroll
        for (int i = 0; i < 8; ++i) {
            int gr = row0 + rg * 8 + i;
            if (gr < NN) *(float2*)&out[(size_t)gr * 40 + cg * 2] = make_float2(acc[i][0], acc[i][1]);
        }
    }
}

// ---------------------------------------------------------------------------
// K9: per-node attention coefficients layer 2 (scalars).
__global__ __launch_bounds__(256) void alpha2_kernel(
    const float* __restrict__ xs2, const float* __restrict__ asw,
    const float* __restrict__ adw, float* __restrict__ as2, float* __restrict__ ad2) {
    int wid = (blockIdx.x * 256 + threadIdx.x) >> 6;
    if (wid >= NN) return;
    int lane = threadIdx.x & 63;
    float pa = 0.f, pd = 0.f;
    if (lane < 40) {
        float v = xs2[(size_t)wid * 40 + lane];
        pa = v * asw[lane];
        pd = v * adw[lane];
    }
#pragma unroll
    for (int d = 32; d >= 1; d >>= 1) {
        pa += __shfl_xor(pa, d);
        pd += __shfl_xor(pd, d);
    }
    if (lane == 0) { as2[wid] = pa; ad2[wid] = pd; }
}

// ---------------------------------------------------------------------------
// K10: layer-2 GAT aggregation + bias + BN + log_softmax. One wave per node.
__global__ __launch_bounds__(256) void gat2_kernel(
    const int* __restrict__ src0, const int* __restrict__ csr, const int* __restrict__ off,
    const float* __restrict__ xs2, const float* __restrict__ as2, const float* __restrict__ ad2,
    const float* __restrict__ ae2, const float* __restrict__ ae2L,
    const float* __restrict__ b2, const float* __restrict__ g2, const float* __restrict__ be2,
    const float* __restrict__ rm2, const float* __restrict__ rv2, float* __restrict__ outp) {
    int wid = (blockIdx.x * 256 + threadIdx.x) >> 6;
    if (wid >= NN) return;
    int lane = threadIdx.x & 63;
    int n = wid;
    int e0 = off[n], e1 = off[n + 1];
    int deg = e1 - e0;
    float adn = ad2[n];
    float aL = as2[n] + adn + ae2L[n];
    aL = aL >= 0.f ? aL : 0.2f * aL;
    float m = aL;
    for (int i = lane; i < deg; i += 64) {
        int e = csr[e0 + i];
        int s = src0[e];
        float a = as2[s] + adn + ae2[e];
        a = a >= 0.f ? a : 0.2f * a;
        m = fmaxf(m, a);
    }
#pragma unroll
    for (int d = 32; d >= 1; d >>= 1) m = fmaxf(m, __shfl_xor(m, d));
    float denom = __expf(aL - m);
    float acc = (lane < 40) ? xs2[(size_t)n * 40 + lane] * denom : 0.f;
    for (int i = 0; i < deg; ++i) {
        int e = csr[e0 + i];
        int s = src0[e];
        float a = as2[s] + adn + ae2[e];
        a = a >= 0.f ? a : 0.2f * a;
        float w = __expf(a - m);
        denom += w;
        if (lane < 40) acc += xs2[(size_t)s * 40 + lane] * w;
    }
    float v;
    if (lane < 40) {
        v = acc / (denom + 1e-16f) + b2[lane];
        float sc = g2[lane] * rsqrtf(rv2[lane] + 1e-5f);
        v = (v - rm2[lane]) * sc + be2[lane];
    } else {
        v = -3.0e38f;
    }
    float mx = v;
#pragma unroll
    for (int d = 32; d >= 1; d >>= 1) mx = fmaxf(mx, __shfl_xor(mx, d));
    float ex = (lane < 40) ? __expf(v - mx) : 0.f;
    float sm = ex;
#pragma unroll
    for (int d = 32; d >= 1; d >>= 1) sm += __shfl_xor(sm, d);
    if (lane < 40) outp[(size_t)n * 40 + lane] = v - mx - __logf(sm);
}

// ---------------------------------------------------------------------------
extern "C" void kernel_launch(void* const* d_in, const int* in_sizes, int n_in,
                              void* d_out, int out_size, void* d_ws, size_t ws_size,
                              hipStream_t stream) {
    const float* x     = (const float*)d_in[0];
    const int*   ei    = (const int*)d_in[1];
    const float* eattr = (const float*)d_in[2];
    const float* W1    = (const float*)d_in[3];
    const float* as1w  = (const float*)d_in[4];
    const float* ad1w  = (const float*)d_in[5];
    const float* ae1w  = (const float*)d_in[6];
    const float* We1   = (const float*)d_in[7];
    const float* b1    = (const float*)d_in[8];
    const float* W2    = (const float*)d_in[9];
    const float* as2w  = (const float*)d_in[10];
    const float* ad2w  = (const float*)d_in[11];
    const float* ae2w  = (const float*)d_in[12];
    const float* We2   = (const float*)d_in[13];
    const float* b2    = (const float*)d_in[14];
    const float* g1    = (const float*)d_in[15];
    const float* be1   = (const float*)d_in[16];
    const float* rm1   = (const float*)d_in[17];
    const float* rv1   = (const float*)d_in[18];
    const float* g2    = (const float*)d_in[19];
    const float* be2   = (const float*)d_in[20];
    const float* rm2   = (const float*)d_in[21];
    const float* rv2   = (const float*)d_in[22];

    const int* src0 = ei;
    const int* dst0 = ei + NE;

    char* p = (char*)d_ws;
    auto take = [&](size_t nbytes) {
        void* r = (void*)p;
        p += (nbytes + 255) & ~(size_t)255;
        return r;
    };
    float* wf1  = (float*)take(80);
    float* wf2  = (float*)take(20);
    int*   cnt  = (int*)take((size_t)NN * 4);
    int*   off  = (int*)take((size_t)(NN + 1) * 4);
    int*   cur  = (int*)take((size_t)NN * 4);
    int*   csr  = (int*)take((size_t)NE * 4);
    float* ae1  = (float*)take((size_t)NE * 16);
    float* ae2  = (float*)take((size_t)NE * 4);
    float* ae1L = (float*)take((size_t)NN * 16);
    float* ae2L = (float*)take((size_t)NN * 4);
    float* as1  = (float*)take((size_t)NN * 16);
    float* ad1  = (float*)take((size_t)NN * 16);
    float* as2  = (float*)take((size_t)NN * 4);
    float* ad2  = (float*)take((size_t)NN * 4);
    float* xs1  = (float*)take((size_t)NN * 512);
    float* h1   = (float*)take((size_t)NN * 512);
    float* xs2  = (float*)take((size_t)NN * 160);

    hipMemsetAsync(cnt, 0, (size_t)NN * 4, stream);
    hipMemsetAsync(cur, 0, (size_t)NN * 4, stream);

    fold_kernel<<<1, 64, 0, stream>>>(We1, ae1w, We2, ae2w, wf1, wf2);
    edge_pre_kernel<<<(NE + 255) / 256, 256, 0, stream>>>(dst0, eattr, wf1, wf2, cnt, ae1, ae2);
    scan_kernel<<<1, 1024, 0, stream>>>(cnt, off);
    csr_fill_kernel<<<(NE + 255) / 256, 256, 0, stream>>>(dst0, off, cur, csr);
    loop_pre_kernel<<<(NN + 255) / 256, 256, 0, stream>>>(off, csr, eattr, wf1, wf2, ae1L, ae2L);
    gemm1_kernel<<<(NN + 63) / 64, 256, 0, stream>>>(x, W1, xs1);
    alpha1_kernel<<<(NN + 3) / 4, 256, 0, stream>>>(xs1, as1w, ad1w, as1, ad1);
    gat1_kernel<<<(NN + 3) / 4, 256, 0, stream>>>(src0, csr, off, xs1, as1, ad1, ae1, ae1L,
                                                  b1, g1, be1, rm1, rv1, h1);
    gemm2_kernel<<<(NN + 95) / 96, 256, 0, stream>>>(h1, W2, xs2);
    alpha2_kernel<<<(NN + 3) / 4, 256, 0, stream>>>(xs2, as2w, ad2w, as2, ad2);
    gat2_kernel<<<(NN + 3) / 4, 256, 0, stream>>>(src0, csr, off, xs2, as2, ad2, ae2, ae2L,
                                                  b2, g2, be2, rm2, rv2, (float*)d_out);
}

// Round 2
// 435.161 us; speedup vs baseline: 1.4724x; 1.4724x over previous
//
#include <hip/hip_runtime.h>
#include <hip/hip_bf16.h>

#define NN 50000
#define NE 800000
// IN=128, HID=32, HEADS=4, HC=128, OUT=40, EDIM=5

// ---------------------------------------------------------------------------
// K0: fold edge-weight matrices with attention vectors.
__global__ void fold_kernel(const float* __restrict__ We1, const float* __restrict__ ae1w,
                            const float* __restrict__ We2, const float* __restrict__ ae2w,
                            float* __restrict__ wf1, float* __restrict__ wf2) {
    int t = threadIdx.x;
    if (t < 20) {
        int j = t >> 2, h = t & 3;
        float s = 0.f;
        for (int c = 0; c < 32; ++c) s += We1[j * 128 + h * 32 + c] * ae1w[h * 32 + c];
        wf1[j * 4 + h] = s;
    }
    if (t >= 32 && t < 37) {
        int j = t - 32;
        float s = 0.f;
        for (int c = 0; c < 40; ++c) s += We2[j * 40 + c] * ae2w[c];
        wf2[j] = s;
    }
}

// ---------------------------------------------------------------------------
// K1: in-degree count.
__global__ __launch_bounds__(256) void count_kernel(const int* __restrict__ dst0,
                                                    int* __restrict__ cnt) {
    int e = blockIdx.x * 256 + threadIdx.x;
    if (e >= NE) return;
    atomicAdd(&cnt[dst0[e]], 1);
}

// ---------------------------------------------------------------------------
// K2: exclusive scan of cnt -> off (single block, 1024 threads).
__global__ void scan_kernel(const int* __restrict__ cnt, int* __restrict__ off) {
    __shared__ int sums[1024];
    const int C = (NN + 1023) / 1024;
    int t = threadIdx.x;
    int base = t * C;
    int s = 0;
    for (int i = 0; i < C; ++i) {
        int idx = base + i;
        if (idx < NN) s += cnt[idx];
    }
    sums[t] = s;
    __syncthreads();
    for (int d = 1; d < 1024; d <<= 1) {
        int v = (t >= d) ? sums[t - d] : 0;
        __syncthreads();
        sums[t] += v;
        __syncthreads();
    }
    int run = sums[t] - s;  // exclusive
    for (int i = 0; i < C; ++i) {
        int idx = base + i;
        if (idx < NN) { off[idx] = run; run += cnt[idx]; }
    }
    if (t == 1023) off[NN] = run;
}

// ---------------------------------------------------------------------------
// K3: fill CSR in slot order with src + folded edge logits (no indirection
// left for the aggregation kernels).
__global__ __launch_bounds__(256) void fill_fold_kernel(
    const int* __restrict__ src0, const int* __restrict__ dst0,
    const float* __restrict__ eattr, const float* __restrict__ wf1,
    const float* __restrict__ wf2, const int* __restrict__ off, int* __restrict__ cur,
    int* __restrict__ csrsrc, float4* __restrict__ ae1p, float* __restrict__ ae2p) {
    int e = blockIdx.x * 256 + threadIdx.x;
    if (e >= NE) return;
    float a[5];
#pragma unroll
    for (int j = 0; j < 5; ++j) a[j] = eattr[(size_t)e * 5 + j];
    float4 o;
    float* op = (float*)&o;
#pragma unroll
    for (int h = 0; h < 4; ++h) {
        float s = 0.f;
#pragma unroll
        for (int j = 0; j < 5; ++j) s += a[j] * wf1[j * 4 + h];
        op[h] = s;
    }
    float s2 = 0.f;
#pragma unroll
    for (int j = 0; j < 5; ++j) s2 += a[j] * wf2[j];
    int d = dst0[e];
    int p = atomicAdd(&cur[d], 1);
    int pos = off[d] + p;
    csrsrc[pos] = src0[e];
    ae1p[pos] = o;
    ae2p[pos] = s2;
}

// ---------------------------------------------------------------------------
// K5: GEMM1: xs1[N,128] = x[N,128] @ W1[128,128].
__global__ __launch_bounds__(256) void gemm1_kernel(
    const float* __restrict__ A, const float* __restrict__ W, float* __restrict__ out) {
    __shared__ float sW[64 * 132];
    __shared__ float sXT[64 * 72];
    int t = threadIdx.x;
    int row0 = blockIdx.x * 64;
    int cg = t & 31;
    int rg = t >> 5;
    float acc[8][4];
#pragma unroll
    for (int i = 0; i < 8; ++i)
#pragma unroll
        for (int j = 0; j < 4; ++j) acc[i][j] = 0.f;

    for (int kk = 0; kk < 128; kk += 64) {
        for (int i = t; i < 64 * 128; i += 256) {
            int k = i >> 7, c = i & 127;
            sW[k * 132 + c] = W[(size_t)(kk + k) * 128 + c];
        }
        for (int i = t; i < 64 * 64; i += 256) {
            int r = i >> 6, k = i & 63;
            int gr = row0 + r;
            sXT[k * 72 + r] = (gr < NN) ? A[(size_t)gr * 128 + kk + k] : 0.f;
        }
        __syncthreads();
#pragma unroll 4
        for (int k = 0; k < 64; ++k) {
            float4 b = *(const float4*)&sW[k * 132 + cg * 4];
            float4 a0 = *(const float4*)&sXT[k * 72 + rg * 8];
            float4 a1 = *(const float4*)&sXT[k * 72 + rg * 8 + 4];
            float av[8] = {a0.x, a0.y, a0.z, a0.w, a1.x, a1.y, a1.z, a1.w};
#pragma unroll
            for (int i = 0; i < 8; ++i) {
                acc[i][0] += av[i] * b.x;
                acc[i][1] += av[i] * b.y;
                acc[i][2] += av[i] * b.z;
                acc[i][3] += av[i] * b.w;
            }
        }
        __syncthreads();
    }
#pragma unroll
    for (int i = 0; i < 8; ++i) {
        int gr = row0 + rg * 8 + i;
        if (gr < NN) *(float4*)&out[(size_t)gr * 128 + cg * 4] = *(float4*)&acc[i][0];
    }
}

// ---------------------------------------------------------------------------
// K6: per-node attention coefficients for layer 1.
__global__ __launch_bounds__(256) void alpha1_kernel(
    const float* __restrict__ xs1, const float* __restrict__ asw,
    const float* __restrict__ adw, float* __restrict__ as1, float* __restrict__ ad1) {
    int wid = (blockIdx.x * 256 + threadIdx.x) >> 6;
    if (wid >= NN) return;
    int lane = threadIdx.x & 63;
    int c = lane * 2;
    float2 v = *(const float2*)&xs1[(size_t)wid * 128 + c];
    float pa = v.x * asw[c] + v.y * asw[c + 1];
    float pd = v.x * adw[c] + v.y * adw[c + 1];
#pragma unroll
    for (int d = 8; d >= 1; d >>= 1) {
        pa += __shfl_xor(pa, d, 16);
        pd += __shfl_xor(pd, d, 16);
    }
    if ((lane & 15) == 0) {
        as1[wid * 4 + (lane >> 4)] = pa;
        ad1[wid * 4 + (lane >> 4)] = pd;
    }
}

// ---------------------------------------------------------------------------
// K7: layer-1 GAT aggregation. One wave per node. Parallel weight phase
// (64 edges/chunk, exp without max shift — softmax is shift-invariant and
// logits are O(1)), then pipelined serial gather phase. Self-loop folded
// in at the end (its logit = mean of folded edge logits; folding is linear).
__global__ __launch_bounds__(256) void gat1_kernel(
    const int* __restrict__ csrsrc, const int* __restrict__ off,
    const float4* __restrict__ ae1p, const float* __restrict__ xs1,
    const float4* __restrict__ as1, const float4* __restrict__ ad1,
    const float* __restrict__ b1, const float* __restrict__ g1, const float* __restrict__ be1,
    const float* __restrict__ rm1, const float* __restrict__ rv1, float* __restrict__ h1out) {
    int wid = (blockIdx.x * 256 + threadIdx.x) >> 6;
    if (wid >= NN) return;
    int lane = threadIdx.x & 63;
    int n = wid;
    int e0 = off[n], e1 = off[n + 1];
    int deg = e1 - e0;
    int h = lane >> 4;          // head owning this lane's feature columns
    int c0 = lane * 2;
    float4 adn = ad1[n];
    float4 asn = as1[n];
    float acc0 = 0.f, acc1 = 0.f;
    float dsum0 = 0.f, dsum1 = 0.f, dsum2 = 0.f, dsum3 = 0.f;
    float aes0 = 0.f, aes1 = 0.f, aes2 = 0.f, aes3 = 0.f;

    for (int base = 0; base < deg; base += 64) {
        int i = base + lane;
        int cn = min(64, deg - base);
        int s = 0;
        float w0 = 0.f, w1 = 0.f, w2 = 0.f, w3 = 0.f;
        if (i < deg) {
            s = csrsrc[e0 + i];
            float4 ae = ae1p[e0 + i];
            float4 av = as1[s];
            float a0 = av.x + adn.x + ae.x;
            float a1 = av.y + adn.y + ae.y;
            float a2 = av.z + adn.z + ae.z;
            float a3 = av.w + adn.w + ae.w;
            a0 = a0 >= 0.f ? a0 : 0.2f * a0;
            a1 = a1 >= 0.f ? a1 : 0.2f * a1;
            a2 = a2 >= 0.f ? a2 : 0.2f * a2;
            a3 = a3 >= 0.f ? a3 : 0.2f * a3;
            w0 = __expf(a0); w1 = __expf(a1); w2 = __expf(a2); w3 = __expf(a3);
            dsum0 += w0; dsum1 += w1; dsum2 += w2; dsum3 += w3;
            aes0 += ae.x; aes1 += ae.y; aes2 += ae.z; aes3 += ae.w;
        }
#pragma unroll 4
        for (int j = 0; j < cn; ++j) {
            int sj = __shfl(s, j);
            float u0 = __shfl(w0, j);
            float u1 = __shfl(w1, j);
            float u2 = __shfl(w2, j);
            float u3 = __shfl(w3, j);
            float wj = h == 0 ? u0 : (h == 1 ? u1 : (h == 2 ? u2 : u3));
            float2 v = *(const float2*)&xs1[(size_t)sj * 128 + c0];
            acc0 += wj * v.x;
            acc1 += wj * v.y;
        }
    }
    // wave reductions for denom + edge-logit mean
#pragma unroll
    for (int d = 32; d >= 1; d >>= 1) {
        dsum0 += __shfl_xor(dsum0, d);
        dsum1 += __shfl_xor(dsum1, d);
        dsum2 += __shfl_xor(dsum2, d);
        dsum3 += __shfl_xor(dsum3, d);
        aes0 += __shfl_xor(aes0, d);
        aes1 += __shfl_xor(aes1, d);
        aes2 += __shfl_xor(aes2, d);
        aes3 += __shfl_xor(aes3, d);
    }
    float invd = 1.f / fmaxf((float)deg, 1.f);
    float aL0 = asn.x + adn.x + aes0 * invd;
    float aL1 = asn.y + adn.y + aes1 * invd;
    float aL2 = asn.z + adn.z + aes2 * invd;
    float aL3 = asn.w + adn.w + aes3 * invd;
    aL0 = aL0 >= 0.f ? aL0 : 0.2f * aL0;
    aL1 = aL1 >= 0.f ? aL1 : 0.2f * aL1;
    aL2 = aL2 >= 0.f ? aL2 : 0.2f * aL2;
    aL3 = aL3 >= 0.f ? aL3 : 0.2f * aL3;
    float ws0 = __expf(aL0), ws1 = __expf(aL1), ws2 = __expf(aL2), ws3 = __expf(aL3);
    float wself = h == 0 ? ws0 : (h == 1 ? ws1 : (h == 2 ? ws2 : ws3));
    float dh = h == 0 ? dsum0 + ws0 : (h == 1 ? dsum1 + ws1 : (h == 2 ? dsum2 + ws2 : dsum3 + ws3));
    float2 vs = *(const float2*)&xs1[(size_t)n * 128 + c0];
    acc0 += wself * vs.x;
    acc1 += wself * vs.y;
    float inv = 1.f / (dh + 1e-16f);
    float o0 = acc0 * inv + b1[c0];
    float o1 = acc1 * inv + b1[c0 + 1];
    float sc0 = g1[c0] * rsqrtf(rv1[c0] + 1e-5f);
    float sc1 = g1[c0 + 1] * rsqrtf(rv1[c0 + 1] + 1e-5f);
    o0 = (o0 - rm1[c0]) * sc0 + be1[c0];
    o1 = (o1 - rm1[c0 + 1]) * sc1 + be1[c0 + 1];
    o0 = o0 > 0.f ? o0 : __expf(o0) - 1.f;
    o1 = o1 > 0.f ? o1 : __expf(o1) - 1.f;
    *(float2*)&h1out[(size_t)n * 128 + c0] = make_float2(o0, o1);
}

// ---------------------------------------------------------------------------
// K8: GEMM2: xs2[N,40] = h1[N,128] @ W2[128,40].
__global__ __launch_bounds__(256) void gemm2_kernel(
    const float* __restrict__ A, const float* __restrict__ W, float* __restrict__ out) {
    __shared__ float sW[128 * 40];
    __shared__ float sXT[128 * 104];
    int t = threadIdx.x;
    int row0 = blockIdx.x * 96;
    for (int i = t; i < 128 * 40; i += 256) sW[i] = W[i];
    for (int i = t; i < 128 * 96; i += 256) {
        int r = i >> 7, k = i & 127;
        int gr = row0 + r;
        sXT[k * 104 + r] = (gr < NN) ? A[(size_t)gr * 128 + k] : 0.f;
    }
    __syncthreads();
    if (t < 240) {
        int cg = t % 20;
        int rg = t / 20;
        float acc[8][2];
#pragma unroll
        for (int i = 0; i < 8; ++i) { acc[i][0] = 0.f; acc[i][1] = 0.f; }
#pragma unroll 4
        for (int k = 0; k < 128; ++k) {
            float2 b = *(const float2*)&sW[k * 40 + cg * 2];
            float4 a0 = *(const float4*)&sXT[k * 104 + rg * 8];
            float4 a1 = *(const float4*)&sXT[k * 104 + rg * 8 + 4];
            float av[8] = {a0.x, a0.y, a0.z, a0.w, a1.x, a1.y, a1.z, a1.w};
#pragma unroll
            for (int i = 0; i < 8; ++i) {
                acc[i][0] += av[i] * b.x;
                acc[i][1] += av[i] * b.y;
            }
        }
#pragma unroll
        for (int i = 0; i < 8; ++i) {
            int gr = row0 + rg * 8 + i;
            if (gr < NN) *(float2*)&out[(size_t)gr * 40 + cg * 2] = make_float2(acc[i][0], acc[i][1]);
        }
    }
}

// ---------------------------------------------------------------------------
// K9: per-node attention coefficients layer 2 (scalars).
__global__ __launch_bounds__(256) void alpha2_kernel(
    const float* __restrict__ xs2, const float* __restrict__ asw,
    const float* __restrict__ adw, float* __restrict__ as2, float* __restrict__ ad2) {
    int wid = (blockIdx.x * 256 + threadIdx.x) >> 6;
    if (wid >= NN) return;
    int lane = threadIdx.x & 63;
    float pa = 0.f, pd = 0.f;
    if (lane < 40) {
        float v = xs2[(size_t)wid * 40 + lane];
        pa = v * asw[lane];
        pd = v * adw[lane];
    }
#pragma unroll
    for (int d = 32; d >= 1; d >>= 1) {
        pa += __shfl_xor(pa, d);
        pd += __shfl_xor(pd, d);
    }
    if (lane == 0) { as2[wid] = pa; ad2[wid] = pd; }
}

// ---------------------------------------------------------------------------
// K10: layer-2 GAT aggregation + bias + BN + log_softmax. One wave per node.
__global__ __launch_bounds__(256) void gat2_kernel(
    const int* __restrict__ csrsrc, const int* __restrict__ off,
    const float* __restrict__ ae2p, const float* __restrict__ xs2,
    const float* __restrict__ as2, const float* __restrict__ ad2,
    const float* __restrict__ b2, const float* __restrict__ g2, const float* __restrict__ be2,
    const float* __restrict__ rm2, const float* __restrict__ rv2, float* __restrict__ outp) {
    int wid = (blockIdx.x * 256 + threadIdx.x) >> 6;
    if (wid >= NN) return;
    int lane = threadIdx.x & 63;
    int n = wid;
    int e0 = off[n], e1 = off[n + 1];
    int deg = e1 - e0;
    float adn = ad2[n];
    float asn = as2[n];
    int col = lane < 40 ? lane : 0;
    float acc = 0.f, dsum = 0.f, aesum = 0.f;

    for (int base = 0; base < deg; base += 64) {
        int i = base + lane;
        int cn = min(64, deg - base);
        int s = 0;
        float w = 0.f;
        if (i < deg) {
            s = csrsrc[e0 + i];
            float ae = ae2p[e0 + i];
            float a = as2[s] + adn + ae;
            a = a >= 0.f ? a : 0.2f * a;
            w = __expf(a);
            dsum += w;
            aesum += ae;
        }
#pragma unroll 4
        for (int j = 0; j < cn; ++j) {
            int sj = __shfl(s, j);
            float wj = __shfl(w, j);
            float v = xs2[(size_t)sj * 40 + col];
            acc += wj * v;
        }
    }
#pragma unroll
    for (int d = 32; d >= 1; d >>= 1) {
        dsum += __shfl_xor(dsum, d);
        aesum += __shfl_xor(aesum, d);
    }
    float invd = 1.f / fmaxf((float)deg, 1.f);
    float aL = asn + adn + aesum * invd;
    aL = aL >= 0.f ? aL : 0.2f * aL;
    float wself = __expf(aL);
    float denom = dsum + wself;
    acc += wself * xs2[(size_t)n * 40 + col];

    float v;
    if (lane < 40) {
        v = acc / (denom + 1e-16f) + b2[lane];
        float sc = g2[lane] * rsqrtf(rv2[lane] + 1e-5f);
        v = (v - rm2[lane]) * sc + be2[lane];
    } else {
        v = -3.0e38f;
    }
    float mx = v;
#pragma unroll
    for (int d = 32; d >= 1; d >>= 1) mx = fmaxf(mx, __shfl_xor(mx, d));
    float ex = (lane < 40) ? __expf(v - mx) : 0.f;
    float sm = ex;
#pragma unroll
    for (int d = 32; d >= 1; d >>= 1) sm += __shfl_xor(sm, d);
    if (lane < 40) outp[(size_t)n * 40 + lane] = v - mx - __logf(sm);
}

// ---------------------------------------------------------------------------
extern "C" void kernel_launch(void* const* d_in, const int* in_sizes, int n_in,
                              void* d_out, int out_size, void* d_ws, size_t ws_size,
                              hipStream_t stream) {
    const float* x     = (const float*)d_in[0];
    const int*   ei    = (const int*)d_in[1];
    const float* eattr = (const float*)d_in[2];
    const float* W1    = (const float*)d_in[3];
    const float* as1w  = (const float*)d_in[4];
    const float* ad1w  = (const float*)d_in[5];
    const float* ae1w  = (const float*)d_in[6];
    const float* We1   = (const float*)d_in[7];
    const float* b1    = (const float*)d_in[8];
    const float* W2    = (const float*)d_in[9];
    const float* as2w  = (const float*)d_in[10];
    const float* ad2w  = (const float*)d_in[11];
    const float* ae2w  = (const float*)d_in[12];
    const float* We2   = (const float*)d_in[13];
    const float* b2    = (const float*)d_in[14];
    const float* g1    = (const float*)d_in[15];
    const float* be1   = (const float*)d_in[16];
    const float* rm1   = (const float*)d_in[17];
    const float* rv1   = (const float*)d_in[18];
    const float* g2    = (const float*)d_in[19];
    const float* be2   = (const float*)d_in[20];
    const float* rm2   = (const float*)d_in[21];
    const float* rv2   = (const float*)d_in[22];

    const int* src0 = ei;
    const int* dst0 = ei + NE;

    char* p = (char*)d_ws;
    auto take = [&](size_t nbytes) {
        void* r = (void*)p;
        p += (nbytes + 255) & ~(size_t)255;
        return r;
    };
    float*  wf1    = (float*)take(80);
    float*  wf2    = (float*)take(20);
    int*    cnt    = (int*)take((size_t)NN * 4);
    int*    off    = (int*)take((size_t)(NN + 1) * 4);
    int*    cur    = (int*)take((size_t)NN * 4);
    int*    csrsrc = (int*)take((size_t)NE * 4);
    float4* ae1p   = (float4*)take((size_t)NE * 16);
    float*  ae2p   = (float*)take((size_t)NE * 4);
    float*  as1    = (float*)take((size_t)NN * 16);
    float*  ad1    = (float*)take((size_t)NN * 16);
    float*  as2    = (float*)take((size_t)NN * 4);
    float*  ad2    = (float*)take((size_t)NN * 4);
    float*  xs1    = (float*)take((size_t)NN * 512);
    float*  h1     = (float*)take((size_t)NN * 512);
    float*  xs2    = (float*)take((size_t)NN * 160);

    hipMemsetAsync(cnt, 0, (size_t)NN * 4, stream);
    hipMemsetAsync(cur, 0, (size_t)NN * 4, stream);

    fold_kernel<<<1, 64, 0, stream>>>(We1, ae1w, We2, ae2w, wf1, wf2);
    count_kernel<<<(NE + 255) / 256, 256, 0, stream>>>(dst0, cnt);
    scan_kernel<<<1, 1024, 0, stream>>>(cnt, off);
    fill_fold_kernel<<<(NE + 255) / 256, 256, 0, stream>>>(src0, dst0, eattr, wf1, wf2,
                                                           off, cur, csrsrc, ae1p, ae2p);
    gemm1_kernel<<<(NN + 63) / 64, 256, 0, stream>>>(x, W1, xs1);
    alpha1_kernel<<<(NN + 3) / 4, 256, 0, stream>>>(xs1, as1w, ad1w, as1, ad1);
    gat1_kernel<<<(NN + 3) / 4, 256, 0, stream>>>(csrsrc, off, ae1p, xs1, (const float4*)as1,
                                                  (const float4*)ad1, b1, g1, be1, rm1, rv1, h1);
    gemm2_kernel<<<(NN + 95) / 96, 256, 0, stream>>>(h1, W2, xs2);
    alpha2_kernel<<<(NN + 3) / 4, 256, 0, stream>>>(xs2, as2w, ad2w, as2, ad2);
    gat2_kernel<<<(NN + 3) / 4, 256, 0, stream>>>(csrsrc, off, ae2p, xs2, as2, ad2,
                                                  b2, g2, be2, rm2, rv2, (float*)d_out);
}

// Round 3
// 352.069 us; speedup vs baseline: 1.8199x; 1.2360x over previous
//
#include <hip/hip_runtime.h>
#include <hip/hip_bf16.h>

#define NN 50000
#define NE 800000
#define SCAN_NB ((NN + 255) / 256)   // 196 blocks
// IN=128, HID=32, HEADS=4, HC=128, OUT=40, EDIM=5

// ---------------------------------------------------------------------------
// K0: fold edge-weight matrices with attention vectors.
__global__ void fold_kernel(const float* __restrict__ We1, const float* __restrict__ ae1w,
                            const float* __restrict__ We2, const float* __restrict__ ae2w,
                            float* __restrict__ wf1, float* __restrict__ wf2) {
    int t = threadIdx.x;
    if (t < 20) {
        int j = t >> 2, h = t & 3;
        float s = 0.f;
        for (int c = 0; c < 32; ++c) s += We1[j * 128 + h * 32 + c] * ae1w[h * 32 + c];
        wf1[j * 4 + h] = s;
    }
    if (t >= 32 && t < 37) {
        int j = t - 32;
        float s = 0.f;
        for (int c = 0; c < 40; ++c) s += We2[j * 40 + c] * ae2w[c];
        wf2[j] = s;
    }
}

// ---------------------------------------------------------------------------
// K1: in-degree count.
__global__ __launch_bounds__(256) void count_kernel(const int* __restrict__ dst0,
                                                    int* __restrict__ cnt) {
    int e = blockIdx.x * 256 + threadIdx.x;
    if (e >= NE) return;
    atomicAdd(&cnt[dst0[e]], 1);
}

// ---------------------------------------------------------------------------
// K2a: per-block exclusive scan of cnt (256 elems/block) + block sums.
__global__ __launch_bounds__(256) void scan1_kernel(const int* __restrict__ cnt,
                                                    int* __restrict__ off,
                                                    int* __restrict__ bsum) {
    __shared__ int tmp[256];
    int t = threadIdx.x;
    int g = blockIdx.x * 256 + t;
    int v = (g < NN) ? cnt[g] : 0;
    tmp[t] = v;
    __syncthreads();
#pragma unroll
    for (int d = 1; d < 256; d <<= 1) {
        int u = (t >= d) ? tmp[t - d] : 0;
        __syncthreads();
        tmp[t] += u;
        __syncthreads();
    }
    if (g < NN) off[g] = tmp[t] - v;  // exclusive within block
    if (t == 255) bsum[blockIdx.x] = tmp[255];
}

// K2b: scan the block sums (single 256-thread block; SCAN_NB=196 <= 256).
__global__ __launch_bounds__(256) void scan2_kernel(int* __restrict__ bsum) {
    __shared__ int tmp[256];
    int t = threadIdx.x;
    int v = (t < SCAN_NB) ? bsum[t] : 0;
    tmp[t] = v;
    __syncthreads();
#pragma unroll
    for (int d = 1; d < 256; d <<= 1) {
        int u = (t >= d) ? tmp[t - d] : 0;
        __syncthreads();
        tmp[t] += u;
        __syncthreads();
    }
    if (t < SCAN_NB) bsum[t] = tmp[t] - v;  // exclusive block offsets
}

// K2c: add block offsets; last thread writes off[NN].
__global__ __launch_bounds__(256) void scan3_kernel(int* __restrict__ off,
                                                    const int* __restrict__ bsum,
                                                    const int* __restrict__ cnt) {
    int g = blockIdx.x * 256 + threadIdx.x;
    if (g < NN) {
        int o = off[g] + bsum[blockIdx.x];
        off[g] = o;
        if (g == NN - 1) off[NN] = o + cnt[g];
    }
}

// ---------------------------------------------------------------------------
// K3: fill CSR in slot order with src + folded edge logits.
__global__ __launch_bounds__(256) void fill_fold_kernel(
    const int* __restrict__ src0, const int* __restrict__ dst0,
    const float* __restrict__ eattr, const float* __restrict__ wf1,
    const float* __restrict__ wf2, const int* __restrict__ off, int* __restrict__ cur,
    int* __restrict__ csrsrc, float4* __restrict__ ae1p, float* __restrict__ ae2p) {
    int e = blockIdx.x * 256 + threadIdx.x;
    if (e >= NE) return;
    float a[5];
#pragma unroll
    for (int j = 0; j < 5; ++j) a[j] = eattr[(size_t)e * 5 + j];
    float4 o;
    float* op = (float*)&o;
#pragma unroll
    for (int h = 0; h < 4; ++h) {
        float s = 0.f;
#pragma unroll
        for (int j = 0; j < 5; ++j) s += a[j] * wf1[j * 4 + h];
        op[h] = s;
    }
    float s2 = 0.f;
#pragma unroll
    for (int j = 0; j < 5; ++j) s2 += a[j] * wf2[j];
    int d = dst0[e];
    int p = atomicAdd(&cur[d], 1);
    int pos = off[d] + p;
    csrsrc[pos] = src0[e];
    ae1p[pos] = o;
    ae2p[pos] = s2;
}

// ---------------------------------------------------------------------------
// K5: GEMM1: xs1[N,128] = x[N,128] @ W1[128,128].
__global__ __launch_bounds__(256) void gemm1_kernel(
    const float* __restrict__ A, const float* __restrict__ W, float* __restrict__ out) {
    __shared__ float sW[64 * 132];
    __shared__ float sXT[64 * 72];
    int t = threadIdx.x;
    int row0 = blockIdx.x * 64;
    int cg = t & 31;
    int rg = t >> 5;
    float acc[8][4];
#pragma unroll
    for (int i = 0; i < 8; ++i)
#pragma unroll
        for (int j = 0; j < 4; ++j) acc[i][j] = 0.f;

    for (int kk = 0; kk < 128; kk += 64) {
        for (int i = t; i < 64 * 128; i += 256) {
            int k = i >> 7, c = i & 127;
            sW[k * 132 + c] = W[(size_t)(kk + k) * 128 + c];
        }
        for (int i = t; i < 64 * 64; i += 256) {
            int r = i >> 6, k = i & 63;
            int gr = row0 + r;
            sXT[k * 72 + r] = (gr < NN) ? A[(size_t)gr * 128 + kk + k] : 0.f;
        }
        __syncthreads();
#pragma unroll 4
        for (int k = 0; k < 64; ++k) {
            float4 b = *(const float4*)&sW[k * 132 + cg * 4];
            float4 a0 = *(const float4*)&sXT[k * 72 + rg * 8];
            float4 a1 = *(const float4*)&sXT[k * 72 + rg * 8 + 4];
            float av[8] = {a0.x, a0.y, a0.z, a0.w, a1.x, a1.y, a1.z, a1.w};
#pragma unroll
            for (int i = 0; i < 8; ++i) {
                acc[i][0] += av[i] * b.x;
                acc[i][1] += av[i] * b.y;
                acc[i][2] += av[i] * b.z;
                acc[i][3] += av[i] * b.w;
            }
        }
        __syncthreads();
    }
#pragma unroll
    for (int i = 0; i < 8; ++i) {
        int gr = row0 + rg * 8 + i;
        if (gr < NN) *(float4*)&out[(size_t)gr * 128 + cg * 4] = *(float4*)&acc[i][0];
    }
}

// ---------------------------------------------------------------------------
// K6: per-node attention coefficients for layer 1.
__global__ __launch_bounds__(256) void alpha1_kernel(
    const float* __restrict__ xs1, const float* __restrict__ asw,
    const float* __restrict__ adw, float* __restrict__ as1, float* __restrict__ ad1) {
    int wid = (blockIdx.x * 256 + threadIdx.x) >> 6;
    if (wid >= NN) return;
    int lane = threadIdx.x & 63;
    int c = lane * 2;
    float2 v = *(const float2*)&xs1[(size_t)wid * 128 + c];
    float pa = v.x * asw[c] + v.y * asw[c + 1];
    float pd = v.x * adw[c] + v.y * adw[c + 1];
#pragma unroll
    for (int d = 8; d >= 1; d >>= 1) {
        pa += __shfl_xor(pa, d, 16);
        pd += __shfl_xor(pd, d, 16);
    }
    if ((lane & 15) == 0) {
        as1[wid * 4 + (lane >> 4)] = pa;
        ad1[wid * 4 + (lane >> 4)] = pd;
    }
}

// ---------------------------------------------------------------------------
// K7: layer-1 GAT aggregation. One wave per node.
__global__ __launch_bounds__(256) void gat1_kernel(
    const int* __restrict__ csrsrc, const int* __restrict__ off,
    const float4* __restrict__ ae1p, const float* __restrict__ xs1,
    const float4* __restrict__ as1, const float4* __restrict__ ad1,
    const float* __restrict__ b1, const float* __restrict__ g1, const float* __restrict__ be1,
    const float* __restrict__ rm1, const float* __restrict__ rv1, float* __restrict__ h1out) {
    int wid = (blockIdx.x * 256 + threadIdx.x) >> 6;
    if (wid >= NN) return;
    int lane = threadIdx.x & 63;
    int n = wid;
    int e0 = off[n], e1 = off[n + 1];
    int deg = e1 - e0;
    int h = lane >> 4;
    int c0 = lane * 2;
    float4 adn = ad1[n];
    float4 asn = as1[n];
    float acc0 = 0.f, acc1 = 0.f;
    float dsum0 = 0.f, dsum1 = 0.f, dsum2 = 0.f, dsum3 = 0.f;
    float aes0 = 0.f, aes1 = 0.f, aes2 = 0.f, aes3 = 0.f;

    for (int base = 0; base < deg; base += 64) {
        int i = base + lane;
        int cn = min(64, deg - base);
        int s = 0;
        float w0 = 0.f, w1 = 0.f, w2 = 0.f, w3 = 0.f;
        if (i < deg) {
            s = csrsrc[e0 + i];
            float4 ae = ae1p[e0 + i];
            float4 av = as1[s];
            float a0 = av.x + adn.x + ae.x;
            float a1 = av.y + adn.y + ae.y;
            float a2 = av.z + adn.z + ae.z;
            float a3 = av.w + adn.w + ae.w;
            a0 = a0 >= 0.f ? a0 : 0.2f * a0;
            a1 = a1 >= 0.f ? a1 : 0.2f * a1;
            a2 = a2 >= 0.f ? a2 : 0.2f * a2;
            a3 = a3 >= 0.f ? a3 : 0.2f * a3;
            w0 = __expf(a0); w1 = __expf(a1); w2 = __expf(a2); w3 = __expf(a3);
            dsum0 += w0; dsum1 += w1; dsum2 += w2; dsum3 += w3;
            aes0 += ae.x; aes1 += ae.y; aes2 += ae.z; aes3 += ae.w;
        }
#pragma unroll 4
        for (int j = 0; j < cn; ++j) {
            int sj = __shfl(s, j);
            float u0 = __shfl(w0, j);
            float u1 = __shfl(w1, j);
            float u2 = __shfl(w2, j);
            float u3 = __shfl(w3, j);
            float wj = h == 0 ? u0 : (h == 1 ? u1 : (h == 2 ? u2 : u3));
            float2 v = *(const float2*)&xs1[(size_t)sj * 128 + c0];
            acc0 += wj * v.x;
            acc1 += wj * v.y;
        }
    }
#pragma unroll
    for (int d = 32; d >= 1; d >>= 1) {
        dsum0 += __shfl_xor(dsum0, d);
        dsum1 += __shfl_xor(dsum1, d);
        dsum2 += __shfl_xor(dsum2, d);
        dsum3 += __shfl_xor(dsum3, d);
        aes0 += __shfl_xor(aes0, d);
        aes1 += __shfl_xor(aes1, d);
        aes2 += __shfl_xor(aes2, d);
        aes3 += __shfl_xor(aes3, d);
    }
    float invd = 1.f / fmaxf((float)deg, 1.f);
    float aL0 = asn.x + adn.x + aes0 * invd;
    float aL1 = asn.y + adn.y + aes1 * invd;
    float aL2 = asn.z + adn.z + aes2 * invd;
    float aL3 = asn.w + adn.w + aes3 * invd;
    aL0 = aL0 >= 0.f ? aL0 : 0.2f * aL0;
    aL1 = aL1 >= 0.f ? aL1 : 0.2f * aL1;
    aL2 = aL2 >= 0.f ? aL2 : 0.2f * aL2;
    aL3 = aL3 >= 0.f ? aL3 : 0.2f * aL3;
    float ws0 = __expf(aL0), ws1 = __expf(aL1), ws2 = __expf(aL2), ws3 = __expf(aL3);
    float wself = h == 0 ? ws0 : (h == 1 ? ws1 : (h == 2 ? ws2 : ws3));
    float dh = h == 0 ? dsum0 + ws0 : (h == 1 ? dsum1 + ws1 : (h == 2 ? dsum2 + ws2 : dsum3 + ws3));
    float2 vs = *(const float2*)&xs1[(size_t)n * 128 + c0];
    acc0 += wself * vs.x;
    acc1 += wself * vs.y;
    float inv = 1.f / (dh + 1e-16f);
    float o0 = acc0 * inv + b1[c0];
    float o1 = acc1 * inv + b1[c0 + 1];
    float sc0 = g1[c0] * rsqrtf(rv1[c0] + 1e-5f);
    float sc1 = g1[c0 + 1] * rsqrtf(rv1[c0 + 1] + 1e-5f);
    o0 = (o0 - rm1[c0]) * sc0 + be1[c0];
    o1 = (o1 - rm1[c0 + 1]) * sc1 + be1[c0 + 1];
    o0 = o0 > 0.f ? o0 : __expf(o0) - 1.f;
    o1 = o1 > 0.f ? o1 : __expf(o1) - 1.f;
    *(float2*)&h1out[(size_t)n * 128 + c0] = make_float2(o0, o1);
}

// ---------------------------------------------------------------------------
// K8: GEMM2: xs2[N,40] = h1[N,128] @ W2[128,40].
__global__ __launch_bounds__(256) void gemm2_kernel(
    const float* __restrict__ A, const float* __restrict__ W, float* __restrict__ out) {
    __shared__ float sW[128 * 40];
    __shared__ float sXT[128 * 104];
    int t = threadIdx.x;
    int row0 = blockIdx.x * 96;
    for (int i = t; i < 128 * 40; i += 256) sW[i] = W[i];
    for (int i = t; i < 128 * 96; i += 256) {
        int r = i >> 7, k = i & 127;
        int gr = row0 + r;
        sXT[k * 104 + r] = (gr < NN) ? A[(size_t)gr * 128 + k] : 0.f;
    }
    __syncthreads();
    if (t < 240) {
        int cg = t % 20;
        int rg = t / 20;
        float acc[8][2];
#pragma unroll
        for (int i = 0; i < 8; ++i) { acc[i][0] = 0.f; acc[i][1] = 0.f; }
#pragma unroll 4
        for (int k = 0; k < 128; ++k) {
            float2 b = *(const float2*)&sW[k * 40 + cg * 2];
            float4 a0 = *(const float4*)&sXT[k * 104 + rg * 8];
            float4 a1 = *(const float4*)&sXT[k * 104 + rg * 8 + 4];
            float av[8] = {a0.x, a0.y, a0.z, a0.w, a1.x, a1.y, a1.z, a1.w};
#pragma unroll
            for (int i = 0; i < 8; ++i) {
                acc[i][0] += av[i] * b.x;
                acc[i][1] += av[i] * b.y;
            }
        }
#pragma unroll
        for (int i = 0; i < 8; ++i) {
            int gr = row0 + rg * 8 + i;
            if (gr < NN) *(float2*)&out[(size_t)gr * 40 + cg * 2] = make_float2(acc[i][0], acc[i][1]);
        }
    }
}

// ---------------------------------------------------------------------------
// K9: per-node attention coefficients layer 2 (scalars).
__global__ __launch_bounds__(256) void alpha2_kernel(
    const float* __restrict__ xs2, const float* __restrict__ asw,
    const float* __restrict__ adw, float* __restrict__ as2, float* __restrict__ ad2) {
    int wid = (blockIdx.x * 256 + threadIdx.x) >> 6;
    if (wid >= NN) return;
    int lane = threadIdx.x & 63;
    float pa = 0.f, pd = 0.f;
    if (lane < 40) {
        float v = xs2[(size_t)wid * 40 + lane];
        pa = v * asw[lane];
        pd = v * adw[lane];
    }
#pragma unroll
    for (int d = 32; d >= 1; d >>= 1) {
        pa += __shfl_xor(pa, d);
        pd += __shfl_xor(pd, d);
    }
    if (lane == 0) { as2[wid] = pa; ad2[wid] = pd; }
}

// ---------------------------------------------------------------------------
// K10: layer-2 GAT aggregation + bias + BN + log_softmax. One wave per node.
__global__ __launch_bounds__(256) void gat2_kernel(
    const int* __restrict__ csrsrc, const int* __restrict__ off,
    const float* __restrict__ ae2p, const float* __restrict__ xs2,
    const float* __restrict__ as2, const float* __restrict__ ad2,
    const float* __restrict__ b2, const float* __restrict__ g2, const float* __restrict__ be2,
    const float* __restrict__ rm2, const float* __restrict__ rv2, float* __restrict__ outp) {
    int wid = (blockIdx.x * 256 + threadIdx.x) >> 6;
    if (wid >= NN) return;
    int lane = threadIdx.x & 63;
    int n = wid;
    int e0 = off[n], e1 = off[n + 1];
    int deg = e1 - e0;
    float adn = ad2[n];
    float asn = as2[n];
    int col = lane < 40 ? lane : 0;
    float acc = 0.f, dsum = 0.f, aesum = 0.f;

    for (int base = 0; base < deg; base += 64) {
        int i = base + lane;
        int cn = min(64, deg - base);
        int s = 0;
        float w = 0.f;
        if (i < deg) {
            s = csrsrc[e0 + i];
            float ae = ae2p[e0 + i];
            float a = as2[s] + adn + ae;
            a = a >= 0.f ? a : 0.2f * a;
            w = __expf(a);
            dsum += w;
            aesum += ae;
        }
#pragma unroll 4
        for (int j = 0; j < cn; ++j) {
            int sj = __shfl(s, j);
            float wj = __shfl(w, j);
            float v = xs2[(size_t)sj * 40 + col];
            acc += wj * v;
        }
    }
#pragma unroll
    for (int d = 32; d >= 1; d >>= 1) {
        dsum += __shfl_xor(dsum, d);
        aesum += __shfl_xor(aesum, d);
    }
    float invd = 1.f / fmaxf((float)deg, 1.f);
    float aL = asn + adn + aesum * invd;
    aL = aL >= 0.f ? aL : 0.2f * aL;
    float wself = __expf(aL);
    float denom = dsum + wself;
    acc += wself * xs2[(size_t)n * 40 + col];

    float v;
    if (lane < 40) {
        v = acc / (denom + 1e-16f) + b2[lane];
        float sc = g2[lane] * rsqrtf(rv2[lane] + 1e-5f);
        v = (v - rm2[lane]) * sc + be2[lane];
    } else {
        v = -3.0e38f;
    }
    float mx = v;
#pragma unroll
    for (int d = 32; d >= 1; d >>= 1) mx = fmaxf(mx, __shfl_xor(mx, d));
    float ex = (lane < 40) ? __expf(v - mx) : 0.f;
    float sm = ex;
#pragma unroll
    for (int d = 32; d >= 1; d >>= 1) sm += __shfl_xor(sm, d);
    if (lane < 40) outp[(size_t)n * 40 + lane] = v - mx - __logf(sm);
}

// ---------------------------------------------------------------------------
extern "C" void kernel_launch(void* const* d_in, const int* in_sizes, int n_in,
                              void* d_out, int out_size, void* d_ws, size_t ws_size,
                              hipStream_t stream) {
    const float* x     = (const float*)d_in[0];
    const int*   ei    = (const int*)d_in[1];
    const float* eattr = (const float*)d_in[2];
    const float* W1    = (const float*)d_in[3];
    const float* as1w  = (const float*)d_in[4];
    const float* ad1w  = (const float*)d_in[5];
    const float* ae1w  = (const float*)d_in[6];
    const float* We1   = (const float*)d_in[7];
    const float* b1    = (const float*)d_in[8];
    const float* W2    = (const float*)d_in[9];
    const float* as2w  = (const float*)d_in[10];
    const float* ad2w  = (const float*)d_in[11];
    const float* ae2w  = (const float*)d_in[12];
    const float* We2   = (const float*)d_in[13];
    const float* b2    = (const float*)d_in[14];
    const float* g1    = (const float*)d_in[15];
    const float* be1   = (const float*)d_in[16];
    const float* rm1   = (const float*)d_in[17];
    const float* rv1   = (const float*)d_in[18];
    const float* g2    = (const float*)d_in[19];
    const float* be2   = (const float*)d_in[20];
    const float* rm2   = (const float*)d_in[21];
    const float* rv2   = (const float*)d_in[22];

    const int* src0 = ei;
    const int* dst0 = ei + NE;

    char* p = (char*)d_ws;
    auto take = [&](size_t nbytes) {
        void* r = (void*)p;
        p += (nbytes + 255) & ~(size_t)255;
        return r;
    };
    float*  wf1    = (float*)take(80);
    float*  wf2    = (float*)take(20);
    int*    cnt    = (int*)take((size_t)NN * 4);
    int*    off    = (int*)take((size_t)(NN + 1) * 4);
    int*    bsum   = (int*)take((size_t)SCAN_NB * 4);
    int*    cur    = (int*)take((size_t)NN * 4);
    int*    csrsrc = (int*)take((size_t)NE * 4);
    float4* ae1p   = (float4*)take((size_t)NE * 16);
    float*  ae2p   = (float*)take((size_t)NE * 4);
    float*  as1    = (float*)take((size_t)NN * 16);
    float*  ad1    = (float*)take((size_t)NN * 16);
    float*  as2    = (float*)take((size_t)NN * 4);
    float*  ad2    = (float*)take((size_t)NN * 4);
    float*  xs1    = (float*)take((size_t)NN * 512);
    float*  h1     = (float*)take((size_t)NN * 512);
    float*  xs2    = (float*)take((size_t)NN * 160);

    hipMemsetAsync(cnt, 0, (size_t)NN * 4, stream);
    hipMemsetAsync(cur, 0, (size_t)NN * 4, stream);

    fold_kernel<<<1, 64, 0, stream>>>(We1, ae1w, We2, ae2w, wf1, wf2);
    count_kernel<<<(NE + 255) / 256, 256, 0, stream>>>(dst0, cnt);
    scan1_kernel<<<SCAN_NB, 256, 0, stream>>>(cnt, off, bsum);
    scan2_kernel<<<1, 256, 0, stream>>>(bsum);
    scan3_kernel<<<SCAN_NB, 256, 0, stream>>>(off, bsum, cnt);
    fill_fold_kernel<<<(NE + 255) / 256, 256, 0, stream>>>(src0, dst0, eattr, wf1, wf2,
                                                           off, cur, csrsrc, ae1p, ae2p);
    gemm1_kernel<<<(NN + 63) / 64, 256, 0, stream>>>(x, W1, xs1);
    alpha1_kernel<<<(NN + 3) / 4, 256, 0, stream>>>(xs1, as1w, ad1w, as1, ad1);
    gat1_kernel<<<(NN + 3) / 4, 256, 0, stream>>>(csrsrc, off, ae1p, xs1, (const float4*)as1,
                                                  (const float4*)ad1, b1, g1, be1, rm1, rv1, h1);
    gemm2_kernel<<<(NN + 95) / 96, 256, 0, stream>>>(h1, W2, xs2);
    alpha2_kernel<<<(NN + 3) / 4, 256, 0, stream>>>(xs2, as2w, ad2w, as2, ad2);
    gat2_kernel<<<(NN + 3) / 4, 256, 0, stream>>>(csrsrc, off, ae2p, xs2, as2, ad2,
                                                  b2, g2, be2, rm2, rv2, (float*)d_out);
}

// Round 4
// 337.624 us; speedup vs baseline: 1.8977x; 1.0428x over previous
//
#include <hip/hip_runtime.h>
#include <hip/hip_bf16.h>

#define NN 50000
#define NE 800000
#define SCAN_NB ((NN + 255) / 256)   // 196 blocks
// IN=128, HID=32, HEADS=4, HC=128, OUT=40, EDIM=5

// bf16 pack/unpack helpers (RNE rounding).
__device__ __forceinline__ unsigned f2bf2(float a, float b) {
    unsigned ua = __float_as_uint(a);
    ua = (ua + 0x7fffu + ((ua >> 16) & 1u)) >> 16;
    unsigned ub = __float_as_uint(b);
    ub = (ub + 0x7fffu + ((ub >> 16) & 1u)) >> 16;
    return ua | (ub << 16);
}
__device__ __forceinline__ float bf_lo(unsigned u) { return __uint_as_float(u << 16); }
__device__ __forceinline__ float bf_hi(unsigned u) { return __uint_as_float(u & 0xffff0000u); }

// ---------------------------------------------------------------------------
// K0: fold edge-weight matrices with attention vectors.
__global__ void fold_kernel(const float* __restrict__ We1, const float* __restrict__ ae1w,
                            const float* __restrict__ We2, const float* __restrict__ ae2w,
                            float* __restrict__ wf1, float* __restrict__ wf2) {
    int t = threadIdx.x;
    if (t < 20) {
        int j = t >> 2, h = t & 3;
        float s = 0.f;
        for (int c = 0; c < 32; ++c) s += We1[j * 128 + h * 32 + c] * ae1w[h * 32 + c];
        wf1[j * 4 + h] = s;
    }
    if (t >= 32 && t < 37) {
        int j = t - 32;
        float s = 0.f;
        for (int c = 0; c < 40; ++c) s += We2[j * 40 + c] * ae2w[c];
        wf2[j] = s;
    }
}

// ---------------------------------------------------------------------------
// K1: in-degree count.
__global__ __launch_bounds__(256) void count_kernel(const int* __restrict__ dst0,
                                                    int* __restrict__ cnt) {
    int e = blockIdx.x * 256 + threadIdx.x;
    if (e >= NE) return;
    atomicAdd(&cnt[dst0[e]], 1);
}

// ---------------------------------------------------------------------------
// K2a/b/c: two-level exclusive scan.
__global__ __launch_bounds__(256) void scan1_kernel(const int* __restrict__ cnt,
                                                    int* __restrict__ off,
                                                    int* __restrict__ bsum) {
    __shared__ int tmp[256];
    int t = threadIdx.x;
    int g = blockIdx.x * 256 + t;
    int v = (g < NN) ? cnt[g] : 0;
    tmp[t] = v;
    __syncthreads();
#pragma unroll
    for (int d = 1; d < 256; d <<= 1) {
        int u = (t >= d) ? tmp[t - d] : 0;
        __syncthreads();
        tmp[t] += u;
        __syncthreads();
    }
    if (g < NN) off[g] = tmp[t] - v;
    if (t == 255) bsum[blockIdx.x] = tmp[255];
}

__global__ __launch_bounds__(256) void scan2_kernel(int* __restrict__ bsum) {
    __shared__ int tmp[256];
    int t = threadIdx.x;
    int v = (t < SCAN_NB) ? bsum[t] : 0;
    tmp[t] = v;
    __syncthreads();
#pragma unroll
    for (int d = 1; d < 256; d <<= 1) {
        int u = (t >= d) ? tmp[t - d] : 0;
        __syncthreads();
        tmp[t] += u;
        __syncthreads();
    }
    if (t < SCAN_NB) bsum[t] = tmp[t] - v;
}

__global__ __launch_bounds__(256) void scan3_kernel(int* __restrict__ off,
                                                    const int* __restrict__ bsum,
                                                    const int* __restrict__ cnt) {
    int g = blockIdx.x * 256 + threadIdx.x;
    if (g < NN) {
        int o = off[g] + bsum[blockIdx.x];
        off[g] = o;
        if (g == NN - 1) off[NN] = o + cnt[g];
    }
}

// ---------------------------------------------------------------------------
// K3: fill CSR in slot order: src (int), layer-1 logits (bf16x4), layer-2
// logit (fp32).
__global__ __launch_bounds__(256) void fill_fold_kernel(
    const int* __restrict__ src0, const int* __restrict__ dst0,
    const float* __restrict__ eattr, const float* __restrict__ wf1,
    const float* __restrict__ wf2, const int* __restrict__ off, int* __restrict__ cur,
    int* __restrict__ csrsrc, uint2* __restrict__ ae1b, float* __restrict__ ae2p) {
    int e = blockIdx.x * 256 + threadIdx.x;
    if (e >= NE) return;
    float a[5];
#pragma unroll
    for (int j = 0; j < 5; ++j) a[j] = eattr[(size_t)e * 5 + j];
    float o[4];
#pragma unroll
    for (int h = 0; h < 4; ++h) {
        float s = 0.f;
#pragma unroll
        for (int j = 0; j < 5; ++j) s += a[j] * wf1[j * 4 + h];
        o[h] = s;
    }
    float s2 = 0.f;
#pragma unroll
    for (int j = 0; j < 5; ++j) s2 += a[j] * wf2[j];
    int d = dst0[e];
    int p = atomicAdd(&cur[d], 1);
    int pos = off[d] + p;
    csrsrc[pos] = src0[e];
    ae1b[pos] = make_uint2(f2bf2(o[0], o[1]), f2bf2(o[2], o[3]));
    ae2p[pos] = s2;
}

// ---------------------------------------------------------------------------
// K5: GEMM1: xs1[N,128](bf16) = x[N,128] @ W1[128,128].
__global__ __launch_bounds__(256) void gemm1_kernel(
    const float* __restrict__ A, const float* __restrict__ W, unsigned* __restrict__ out) {
    __shared__ float sW[64 * 132];
    __shared__ float sXT[64 * 72];
    int t = threadIdx.x;
    int row0 = blockIdx.x * 64;
    int cg = t & 31;
    int rg = t >> 5;
    float acc[8][4];
#pragma unroll
    for (int i = 0; i < 8; ++i)
#pragma unroll
        for (int j = 0; j < 4; ++j) acc[i][j] = 0.f;

    for (int kk = 0; kk < 128; kk += 64) {
        for (int i = t; i < 64 * 128; i += 256) {
            int k = i >> 7, c = i & 127;
            sW[k * 132 + c] = W[(size_t)(kk + k) * 128 + c];
        }
        for (int i = t; i < 64 * 64; i += 256) {
            int r = i >> 6, k = i & 63;
            int gr = row0 + r;
            sXT[k * 72 + r] = (gr < NN) ? A[(size_t)gr * 128 + kk + k] : 0.f;
        }
        __syncthreads();
#pragma unroll 4
        for (int k = 0; k < 64; ++k) {
            float4 b = *(const float4*)&sW[k * 132 + cg * 4];
            float4 a0 = *(const float4*)&sXT[k * 72 + rg * 8];
            float4 a1 = *(const float4*)&sXT[k * 72 + rg * 8 + 4];
            float av[8] = {a0.x, a0.y, a0.z, a0.w, a1.x, a1.y, a1.z, a1.w};
#pragma unroll
            for (int i = 0; i < 8; ++i) {
                acc[i][0] += av[i] * b.x;
                acc[i][1] += av[i] * b.y;
                acc[i][2] += av[i] * b.z;
                acc[i][3] += av[i] * b.w;
            }
        }
        __syncthreads();
    }
#pragma unroll
    for (int i = 0; i < 8; ++i) {
        int gr = row0 + rg * 8 + i;
        if (gr < NN) {
            uint2 o = make_uint2(f2bf2(acc[i][0], acc[i][1]), f2bf2(acc[i][2], acc[i][3]));
            *(uint2*)&out[(size_t)gr * 64 + cg * 2] = o;
        }
    }
}

// ---------------------------------------------------------------------------
// K6: per-node attention coefficients for layer 1 (from bf16 xs1).
__global__ __launch_bounds__(256) void alpha1_kernel(
    const unsigned* __restrict__ xs1u, const float* __restrict__ asw,
    const float* __restrict__ adw, float* __restrict__ as1, float* __restrict__ ad1) {
    int wid = (blockIdx.x * 256 + threadIdx.x) >> 6;
    if (wid >= NN) return;
    int lane = threadIdx.x & 63;
    int c = lane * 2;
    unsigned u = xs1u[(size_t)wid * 64 + lane];
    float vx = bf_lo(u), vy = bf_hi(u);
    float pa = vx * asw[c] + vy * asw[c + 1];
    float pd = vx * adw[c] + vy * adw[c + 1];
#pragma unroll
    for (int d = 8; d >= 1; d >>= 1) {
        pa += __shfl_xor(pa, d, 16);
        pd += __shfl_xor(pd, d, 16);
    }
    if ((lane & 15) == 0) {
        as1[wid * 4 + (lane >> 4)] = pa;
        ad1[wid * 4 + (lane >> 4)] = pd;
    }
}

// ---------------------------------------------------------------------------
// K7: layer-1 GAT aggregation (bf16 feature gathers, bf16 h1 output).
__global__ __launch_bounds__(256) void gat1_kernel(
    const int* __restrict__ csrsrc, const int* __restrict__ off,
    const uint2* __restrict__ ae1b, const unsigned* __restrict__ xs1u,
    const float4* __restrict__ as1, const float4* __restrict__ ad1,
    const float* __restrict__ b1, const float* __restrict__ g1, const float* __restrict__ be1,
    const float* __restrict__ rm1, const float* __restrict__ rv1, unsigned* __restrict__ h1u) {
    int wid = (blockIdx.x * 256 + threadIdx.x) >> 6;
    if (wid >= NN) return;
    int lane = threadIdx.x & 63;
    int n = wid;
    int e0 = off[n], e1 = off[n + 1];
    int deg = e1 - e0;
    int h = lane >> 4;
    int c0 = lane * 2;
    float4 adn = ad1[n];
    float4 asn = as1[n];
    float acc0 = 0.f, acc1 = 0.f;
    float dsum0 = 0.f, dsum1 = 0.f, dsum2 = 0.f, dsum3 = 0.f;
    float aes0 = 0.f, aes1 = 0.f, aes2 = 0.f, aes3 = 0.f;

    for (int base = 0; base < deg; base += 64) {
        int i = base + lane;
        int cn = min(64, deg - base);
        int s = 0;
        float w0 = 0.f, w1 = 0.f, w2 = 0.f, w3 = 0.f;
        if (i < deg) {
            s = csrsrc[e0 + i];
            uint2 aeu = ae1b[e0 + i];
            float aex = bf_lo(aeu.x), aey = bf_hi(aeu.x);
            float aez = bf_lo(aeu.y), aew = bf_hi(aeu.y);
            float4 av = as1[s];
            float a0 = av.x + adn.x + aex;
            float a1 = av.y + adn.y + aey;
            float a2 = av.z + adn.z + aez;
            float a3 = av.w + adn.w + aew;
            a0 = a0 >= 0.f ? a0 : 0.2f * a0;
            a1 = a1 >= 0.f ? a1 : 0.2f * a1;
            a2 = a2 >= 0.f ? a2 : 0.2f * a2;
            a3 = a3 >= 0.f ? a3 : 0.2f * a3;
            w0 = __expf(a0); w1 = __expf(a1); w2 = __expf(a2); w3 = __expf(a3);
            dsum0 += w0; dsum1 += w1; dsum2 += w2; dsum3 += w3;
            aes0 += aex; aes1 += aey; aes2 += aez; aes3 += aew;
        }
#pragma unroll 4
        for (int j = 0; j < cn; ++j) {
            int sj = __shfl(s, j);
            float u0 = __shfl(w0, j);
            float u1 = __shfl(w1, j);
            float u2 = __shfl(w2, j);
            float u3 = __shfl(w3, j);
            float wj = h == 0 ? u0 : (h == 1 ? u1 : (h == 2 ? u2 : u3));
            unsigned u = xs1u[(size_t)sj * 64 + lane];
            acc0 += wj * bf_lo(u);
            acc1 += wj * bf_hi(u);
        }
    }
#pragma unroll
    for (int d = 32; d >= 1; d >>= 1) {
        dsum0 += __shfl_xor(dsum0, d);
        dsum1 += __shfl_xor(dsum1, d);
        dsum2 += __shfl_xor(dsum2, d);
        dsum3 += __shfl_xor(dsum3, d);
        aes0 += __shfl_xor(aes0, d);
        aes1 += __shfl_xor(aes1, d);
        aes2 += __shfl_xor(aes2, d);
        aes3 += __shfl_xor(aes3, d);
    }
    float invd = 1.f / fmaxf((float)deg, 1.f);
    float aL0 = asn.x + adn.x + aes0 * invd;
    float aL1 = asn.y + adn.y + aes1 * invd;
    float aL2 = asn.z + adn.z + aes2 * invd;
    float aL3 = asn.w + adn.w + aes3 * invd;
    aL0 = aL0 >= 0.f ? aL0 : 0.2f * aL0;
    aL1 = aL1 >= 0.f ? aL1 : 0.2f * aL1;
    aL2 = aL2 >= 0.f ? aL2 : 0.2f * aL2;
    aL3 = aL3 >= 0.f ? aL3 : 0.2f * aL3;
    float ws0 = __expf(aL0), ws1 = __expf(aL1), ws2 = __expf(aL2), ws3 = __expf(aL3);
    float wself = h == 0 ? ws0 : (h == 1 ? ws1 : (h == 2 ? ws2 : ws3));
    float dh = h == 0 ? dsum0 + ws0 : (h == 1 ? dsum1 + ws1 : (h == 2 ? dsum2 + ws2 : dsum3 + ws3));
    unsigned us = xs1u[(size_t)n * 64 + lane];
    acc0 += wself * bf_lo(us);
    acc1 += wself * bf_hi(us);
    float inv = 1.f / (dh + 1e-16f);
    float o0 = acc0 * inv + b1[c0];
    float o1 = acc1 * inv + b1[c0 + 1];
    float sc0 = g1[c0] * rsqrtf(rv1[c0] + 1e-5f);
    float sc1 = g1[c0 + 1] * rsqrtf(rv1[c0 + 1] + 1e-5f);
    o0 = (o0 - rm1[c0]) * sc0 + be1[c0];
    o1 = (o1 - rm1[c0 + 1]) * sc1 + be1[c0 + 1];
    o0 = o0 > 0.f ? o0 : __expf(o0) - 1.f;
    o1 = o1 > 0.f ? o1 : __expf(o1) - 1.f;
    h1u[(size_t)n * 64 + lane] = f2bf2(o0, o1);
}

// ---------------------------------------------------------------------------
// K8: GEMM2: xs2[N,40](bf16, stride 64) = h1(bf16)[N,128] @ W2[128,40].
__global__ __launch_bounds__(256) void gemm2_kernel(
    const unsigned* __restrict__ A, const float* __restrict__ W, unsigned* __restrict__ out) {
    __shared__ float sW[128 * 40];
    __shared__ float sXT[128 * 104];
    int t = threadIdx.x;
    int row0 = blockIdx.x * 96;
    for (int i = t; i < 128 * 40; i += 256) sW[i] = W[i];
    for (int i = t; i < 96 * 64; i += 256) {
        int r = i >> 6, ku = i & 63;
        int gr = row0 + r;
        unsigned u = (gr < NN) ? A[(size_t)gr * 64 + ku] : 0u;
        sXT[(2 * ku) * 104 + r] = bf_lo(u);
        sXT[(2 * ku + 1) * 104 + r] = bf_hi(u);
    }
    __syncthreads();
    if (t < 240) {
        int cg = t % 20;
        int rg = t / 20;
        float acc[8][2];
#pragma unroll
        for (int i = 0; i < 8; ++i) { acc[i][0] = 0.f; acc[i][1] = 0.f; }
#pragma unroll 4
        for (int k = 0; k < 128; ++k) {
            float2 b = *(const float2*)&sW[k * 40 + cg * 2];
            float4 a0 = *(const float4*)&sXT[k * 104 + rg * 8];
            float4 a1 = *(const float4*)&sXT[k * 104 + rg * 8 + 4];
            float av[8] = {a0.x, a0.y, a0.z, a0.w, a1.x, a1.y, a1.z, a1.w};
#pragma unroll
            for (int i = 0; i < 8; ++i) {
                acc[i][0] += av[i] * b.x;
                acc[i][1] += av[i] * b.y;
            }
        }
#pragma unroll
        for (int i = 0; i < 8; ++i) {
            int gr = row0 + rg * 8 + i;
            if (gr < NN) out[(size_t)gr * 32 + cg] = f2bf2(acc[i][0], acc[i][1]);
        }
    }
}

// ---------------------------------------------------------------------------
// K9: per-node attention coefficients layer 2 (from bf16 xs2).
__global__ __launch_bounds__(256) void alpha2_kernel(
    const unsigned* __restrict__ xs2u, const float* __restrict__ asw,
    const float* __restrict__ adw, float* __restrict__ as2, float* __restrict__ ad2) {
    int wid = (blockIdx.x * 256 + threadIdx.x) >> 6;
    if (wid >= NN) return;
    int lane = threadIdx.x & 63;
    float pa = 0.f, pd = 0.f;
    if (lane < 20) {
        unsigned u = xs2u[(size_t)wid * 32 + lane];
        float vx = bf_lo(u), vy = bf_hi(u);
        int c = lane * 2;
        pa = vx * asw[c] + vy * asw[c + 1];
        pd = vx * adw[c] + vy * adw[c + 1];
    }
#pragma unroll
    for (int d = 16; d >= 1; d >>= 1) {
        pa += __shfl_xor(pa, d, 32);
        pd += __shfl_xor(pd, d, 32);
    }
    if (lane == 0) { as2[wid] = pa; ad2[wid] = pd; }
}

// ---------------------------------------------------------------------------
// K10: layer-2 GAT aggregation + bias + BN + log_softmax.
__global__ __launch_bounds__(256) void gat2_kernel(
    const int* __restrict__ csrsrc, const int* __restrict__ off,
    const float* __restrict__ ae2p, const unsigned* __restrict__ xs2u,
    const float* __restrict__ as2, const float* __restrict__ ad2,
    const float* __restrict__ b2, const float* __restrict__ g2, const float* __restrict__ be2,
    const float* __restrict__ rm2, const float* __restrict__ rv2, float* __restrict__ outp) {
    int wid = (blockIdx.x * 256 + threadIdx.x) >> 6;
    if (wid >= NN) return;
    int lane = threadIdx.x & 63;
    int n = wid;
    int e0 = off[n], e1 = off[n + 1];
    int deg = e1 - e0;
    float adn = ad2[n];
    float asn = as2[n];
    float acc0 = 0.f, acc1 = 0.f, dsum = 0.f, aesum = 0.f;

    for (int base = 0; base < deg; base += 64) {
        int i = base + lane;
        int cn = min(64, deg - base);
        int s = 0;
        float w = 0.f;
        if (i < deg) {
            s = csrsrc[e0 + i];
            float ae = ae2p[e0 + i];
            float a = as2[s] + adn + ae;
            a = a >= 0.f ? a : 0.2f * a;
            w = __expf(a);
            dsum += w;
            aesum += ae;
        }
#pragma unroll 4
        for (int j = 0; j < cn; ++j) {
            int sj = __shfl(s, j);
            float wj = __shfl(w, j);
            if (lane < 20) {
                unsigned u = xs2u[(size_t)sj * 32 + lane];
                acc0 += wj * bf_lo(u);
                acc1 += wj * bf_hi(u);
            }
        }
    }
#pragma unroll
    for (int d = 32; d >= 1; d >>= 1) {
        dsum += __shfl_xor(dsum, d);
        aesum += __shfl_xor(aesum, d);
    }
    float invd = 1.f / fmaxf((float)deg, 1.f);
    float aL = asn + adn + aesum * invd;
    aL = aL >= 0.f ? aL : 0.2f * aL;
    float wself = __expf(aL);
    float denom = dsum + wself;

    float v0 = 0.f, v1 = 0.f;
    if (lane < 20) {
        unsigned u = xs2u[(size_t)n * 32 + lane];
        acc0 += wself * bf_lo(u);
        acc1 += wself * bf_hi(u);
        int c = lane * 2;
        float inv = 1.f / (denom + 1e-16f);
        v0 = acc0 * inv + b2[c];
        v1 = acc1 * inv + b2[c + 1];
        float sc0 = g2[c] * rsqrtf(rv2[c] + 1e-5f);
        float sc1 = g2[c + 1] * rsqrtf(rv2[c + 1] + 1e-5f);
        v0 = (v0 - rm2[c]) * sc0 + be2[c];
        v1 = (v1 - rm2[c + 1]) * sc1 + be2[c + 1];
    }
    float mx = (lane < 20) ? fmaxf(v0, v1) : -3.0e38f;
#pragma unroll
    for (int d = 32; d >= 1; d >>= 1) mx = fmaxf(mx, __shfl_xor(mx, d));
    float ex = (lane < 20) ? __expf(v0 - mx) + __expf(v1 - mx) : 0.f;
#pragma unroll
    for (int d = 32; d >= 1; d >>= 1) ex += __shfl_xor(ex, d);
    if (lane < 20) {
        float ls = __logf(ex);
        *(float2*)&outp[(size_t)n * 40 + lane * 2] = make_float2(v0 - mx - ls, v1 - mx - ls);
    }
}

// ---------------------------------------------------------------------------
extern "C" void kernel_launch(void* const* d_in, const int* in_sizes, int n_in,
                              void* d_out, int out_size, void* d_ws, size_t ws_size,
                              hipStream_t stream) {
    const float* x     = (const float*)d_in[0];
    const int*   ei    = (const int*)d_in[1];
    const float* eattr = (const float*)d_in[2];
    const float* W1    = (const float*)d_in[3];
    const float* as1w  = (const float*)d_in[4];
    const float* ad1w  = (const float*)d_in[5];
    const float* ae1w  = (const float*)d_in[6];
    const float* We1   = (const float*)d_in[7];
    const float* b1    = (const float*)d_in[8];
    const float* W2    = (const float*)d_in[9];
    const float* as2w  = (const float*)d_in[10];
    const float* ad2w  = (const float*)d_in[11];
    const float* ae2w  = (const float*)d_in[12];
    const float* We2   = (const float*)d_in[13];
    const float* b2    = (const float*)d_in[14];
    const float* g1    = (const float*)d_in[15];
    const float* be1   = (const float*)d_in[16];
    const float* rm1   = (const float*)d_in[17];
    const float* rv1   = (const float*)d_in[18];
    const float* g2    = (const float*)d_in[19];
    const float* be2   = (const float*)d_in[20];
    const float* rm2   = (const float*)d_in[21];
    const float* rv2   = (const float*)d_in[22];

    const int* src0 = ei;
    const int* dst0 = ei + NE;

    char* p = (char*)d_ws;
    auto take = [&](size_t nbytes) {
        void* r = (void*)p;
        p += (nbytes + 255) & ~(size_t)255;
        return r;
    };
    float*    wf1    = (float*)take(80);
    float*    wf2    = (float*)take(20);
    int*      cnt    = (int*)take((size_t)NN * 4);
    int*      off    = (int*)take((size_t)(NN + 1) * 4);
    int*      bsum   = (int*)take((size_t)SCAN_NB * 4);
    int*      cur    = (int*)take((size_t)NN * 4);
    int*      csrsrc = (int*)take((size_t)NE * 4);
    uint2*    ae1b   = (uint2*)take((size_t)NE * 8);
    float*    ae2p   = (float*)take((size_t)NE * 4);
    float*    as1    = (float*)take((size_t)NN * 16);
    float*    ad1    = (float*)take((size_t)NN * 16);
    float*    as2    = (float*)take((size_t)NN * 4);
    float*    ad2    = (float*)take((size_t)NN * 4);
    unsigned* xs1u   = (unsigned*)take((size_t)NN * 256);  // 64 uints/row (bf16x2)
    unsigned* h1u    = (unsigned*)take((size_t)NN * 256);
    unsigned* xs2u   = (unsigned*)take((size_t)NN * 128);  // 32 uints/row, cols 0..39 used

    hipMemsetAsync(cnt, 0, (size_t)NN * 4, stream);
    hipMemsetAsync(cur, 0, (size_t)NN * 4, stream);

    fold_kernel<<<1, 64, 0, stream>>>(We1, ae1w, We2, ae2w, wf1, wf2);
    count_kernel<<<(NE + 255) / 256, 256, 0, stream>>>(dst0, cnt);
    scan1_kernel<<<SCAN_NB, 256, 0, stream>>>(cnt, off, bsum);
    scan2_kernel<<<1, 256, 0, stream>>>(bsum);
    scan3_kernel<<<SCAN_NB, 256, 0, stream>>>(off, bsum, cnt);
    fill_fold_kernel<<<(NE + 255) / 256, 256, 0, stream>>>(src0, dst0, eattr, wf1, wf2,
                                                           off, cur, csrsrc, ae1b, ae2p);
    gemm1_kernel<<<(NN + 63) / 64, 256, 0, stream>>>(x, W1, xs1u);
    alpha1_kernel<<<(NN + 3) / 4, 256, 0, stream>>>(xs1u, as1w, ad1w, as1, ad1);
    gat1_kernel<<<(NN + 3) / 4, 256, 0, stream>>>(csrsrc, off, ae1b, xs1u, (const float4*)as1,
                                                  (const float4*)ad1, b1, g1, be1, rm1, rv1, h1u);
    gemm2_kernel<<<(NN + 95) / 96, 256, 0, stream>>>(h1u, W2, xs2u);
    alpha2_kernel<<<(NN + 3) / 4, 256, 0, stream>>>(xs2u, as2w, ad2w, as2, ad2);
    gat2_kernel<<<(NN + 3) / 4, 256, 0, stream>>>(csrsrc, off, ae2p, xs2u, as2, ad2,
                                                  b2, g2, be2, rm2, rv2, (float*)d_out);
}

// Round 5
// 281.361 us; speedup vs baseline: 2.2772x; 1.2000x over previous
//
#include <hip/hip_runtime.h>
#include <hip/hip_bf16.h>

#define NN 50000
#define NE 800000
#define SCAN_NB ((NN + 255) / 256)   // 196 blocks
// IN=128, HID=32, HEADS=4, HC=128, OUT=40, EDIM=5

// bf16 pack/unpack helpers (RNE rounding).
__device__ __forceinline__ unsigned f2bf2(float a, float b) {
    unsigned ua = __float_as_uint(a);
    ua = (ua + 0x7fffu + ((ua >> 16) & 1u)) >> 16;
    unsigned ub = __float_as_uint(b);
    ub = (ub + 0x7fffu + ((ub >> 16) & 1u)) >> 16;
    return ua | (ub << 16);
}
__device__ __forceinline__ float bf_lo(unsigned u) { return __uint_as_float(u << 16); }
__device__ __forceinline__ float bf_hi(unsigned u) { return __uint_as_float(u & 0xffff0000u); }

// ---------------------------------------------------------------------------
// K0: fold edge-weight matrices with attention vectors.
__global__ void fold_kernel(const float* __restrict__ We1, const float* __restrict__ ae1w,
                            const float* __restrict__ We2, const float* __restrict__ ae2w,
                            float* __restrict__ wf1, float* __restrict__ wf2) {
    int t = threadIdx.x;
    if (t < 20) {
        int j = t >> 2, h = t & 3;
        float s = 0.f;
        for (int c = 0; c < 32; ++c) s += We1[j * 128 + h * 32 + c] * ae1w[h * 32 + c];
        wf1[j * 4 + h] = s;
    }
    if (t >= 32 && t < 37) {
        int j = t - 32;
        float s = 0.f;
        for (int c = 0; c < 40; ++c) s += We2[j * 40 + c] * ae2w[c];
        wf2[j] = s;
    }
}

// ---------------------------------------------------------------------------
// K1: in-degree count.
__global__ __launch_bounds__(256) void count_kernel(const int* __restrict__ dst0,
                                                    int* __restrict__ cnt) {
    int e = blockIdx.x * 256 + threadIdx.x;
    if (e >= NE) return;
    atomicAdd(&cnt[dst0[e]], 1);
}

// ---------------------------------------------------------------------------
// K2a/b/c: two-level exclusive scan.
__global__ __launch_bounds__(256) void scan1_kernel(const int* __restrict__ cnt,
                                                    int* __restrict__ off,
                                                    int* __restrict__ bsum) {
    __shared__ int tmp[256];
    int t = threadIdx.x;
    int g = blockIdx.x * 256 + t;
    int v = (g < NN) ? cnt[g] : 0;
    tmp[t] = v;
    __syncthreads();
#pragma unroll
    for (int d = 1; d < 256; d <<= 1) {
        int u = (t >= d) ? tmp[t - d] : 0;
        __syncthreads();
        tmp[t] += u;
        __syncthreads();
    }
    if (g < NN) off[g] = tmp[t] - v;
    if (t == 255) bsum[blockIdx.x] = tmp[255];
}

__global__ __launch_bounds__(256) void scan2_kernel(int* __restrict__ bsum) {
    __shared__ int tmp[256];
    int t = threadIdx.x;
    int v = (t < SCAN_NB) ? bsum[t] : 0;
    tmp[t] = v;
    __syncthreads();
#pragma unroll
    for (int d = 1; d < 256; d <<= 1) {
        int u = (t >= d) ? tmp[t - d] : 0;
        __syncthreads();
        tmp[t] += u;
        __syncthreads();
    }
    if (t < SCAN_NB) bsum[t] = tmp[t] - v;
}

__global__ __launch_bounds__(256) void scan3_kernel(int* __restrict__ off,
                                                    const int* __restrict__ bsum,
                                                    const int* __restrict__ cnt) {
    int g = blockIdx.x * 256 + threadIdx.x;
    if (g < NN) {
        int o = off[g] + bsum[blockIdx.x];
        off[g] = o;
        if (g == NN - 1) off[NN] = o + cnt[g];
    }
}

// ---------------------------------------------------------------------------
// K3: fill CSR in slot order: src (int), layer-1 logits (bf16x4), layer-2
// logit (fp32).
__global__ __launch_bounds__(256) void fill_fold_kernel(
    const int* __restrict__ src0, const int* __restrict__ dst0,
    const float* __restrict__ eattr, const float* __restrict__ wf1,
    const float* __restrict__ wf2, const int* __restrict__ off, int* __restrict__ cur,
    int* __restrict__ csrsrc, uint2* __restrict__ ae1b, float* __restrict__ ae2p) {
    int e = blockIdx.x * 256 + threadIdx.x;
    if (e >= NE) return;
    float a[5];
#pragma unroll
    for (int j = 0; j < 5; ++j) a[j] = eattr[(size_t)e * 5 + j];
    float o[4];
#pragma unroll
    for (int h = 0; h < 4; ++h) {
        float s = 0.f;
#pragma unroll
        for (int j = 0; j < 5; ++j) s += a[j] * wf1[j * 4 + h];
        o[h] = s;
    }
    float s2 = 0.f;
#pragma unroll
    for (int j = 0; j < 5; ++j) s2 += a[j] * wf2[j];
    int d = dst0[e];
    int p = atomicAdd(&cur[d], 1);
    int pos = off[d] + p;
    csrsrc[pos] = src0[e];
    ae1b[pos] = make_uint2(f2bf2(o[0], o[1]), f2bf2(o[2], o[3]));
    ae2p[pos] = s2;
}

// ---------------------------------------------------------------------------
// K5: GEMM1: xs1[N,128](bf16) = x[N,128] @ W1[128,128].
__global__ __launch_bounds__(256) void gemm1_kernel(
    const float* __restrict__ A, const float* __restrict__ W, unsigned* __restrict__ out) {
    __shared__ float sW[64 * 132];
    __shared__ float sXT[64 * 72];
    int t = threadIdx.x;
    int row0 = blockIdx.x * 64;
    int cg = t & 31;
    int rg = t >> 5;
    float acc[8][4];
#pragma unroll
    for (int i = 0; i < 8; ++i)
#pragma unroll
        for (int j = 0; j < 4; ++j) acc[i][j] = 0.f;

    for (int kk = 0; kk < 128; kk += 64) {
        for (int i = t; i < 64 * 128; i += 256) {
            int k = i >> 7, c = i & 127;
            sW[k * 132 + c] = W[(size_t)(kk + k) * 128 + c];
        }
        for (int i = t; i < 64 * 64; i += 256) {
            int r = i >> 6, k = i & 63;
            int gr = row0 + r;
            sXT[k * 72 + r] = (gr < NN) ? A[(size_t)gr * 128 + kk + k] : 0.f;
        }
        __syncthreads();
#pragma unroll 4
        for (int k = 0; k < 64; ++k) {
            float4 b = *(const float4*)&sW[k * 132 + cg * 4];
            float4 a0 = *(const float4*)&sXT[k * 72 + rg * 8];
            float4 a1 = *(const float4*)&sXT[k * 72 + rg * 8 + 4];
            float av[8] = {a0.x, a0.y, a0.z, a0.w, a1.x, a1.y, a1.z, a1.w};
#pragma unroll
            for (int i = 0; i < 8; ++i) {
                acc[i][0] += av[i] * b.x;
                acc[i][1] += av[i] * b.y;
                acc[i][2] += av[i] * b.z;
                acc[i][3] += av[i] * b.w;
            }
        }
        __syncthreads();
    }
#pragma unroll
    for (int i = 0; i < 8; ++i) {
        int gr = row0 + rg * 8 + i;
        if (gr < NN) {
            uint2 o = make_uint2(f2bf2(acc[i][0], acc[i][1]), f2bf2(acc[i][2], acc[i][3]));
            *(uint2*)&out[(size_t)gr * 64 + cg * 2] = o;
        }
    }
}

// ---------------------------------------------------------------------------
// K6: per-node attention coefficients for layer 1 (from bf16 xs1).
__global__ __launch_bounds__(256) void alpha1_kernel(
    const unsigned* __restrict__ xs1u, const float* __restrict__ asw,
    const float* __restrict__ adw, float* __restrict__ as1, float* __restrict__ ad1) {
    int wid = (blockIdx.x * 256 + threadIdx.x) >> 6;
    if (wid >= NN) return;
    int lane = threadIdx.x & 63;
    int c = lane * 2;
    unsigned u = xs1u[(size_t)wid * 64 + lane];
    float vx = bf_lo(u), vy = bf_hi(u);
    float pa = vx * asw[c] + vy * asw[c + 1];
    float pd = vx * adw[c] + vy * adw[c + 1];
#pragma unroll
    for (int d = 8; d >= 1; d >>= 1) {
        pa += __shfl_xor(pa, d, 16);
        pd += __shfl_xor(pd, d, 16);
    }
    if ((lane & 15) == 0) {
        as1[wid * 4 + (lane >> 4)] = pa;
        ad1[wid * 4 + (lane >> 4)] = pd;
    }
}

// ---------------------------------------------------------------------------
// K7: layer-1 GAT aggregation. One wave per node. Weight phase stages
// (s, w[4]) for a 64-edge chunk into per-wave LDS; gather phase processes
// 4 edges/iteration (16 lanes x uint4 each = full 256B row per edge).
__global__ __launch_bounds__(256) void gat1_kernel(
    const int* __restrict__ csrsrc, const int* __restrict__ off,
    const uint2* __restrict__ ae1b, const unsigned* __restrict__ xs1u,
    const float4* __restrict__ as1, const float4* __restrict__ ad1,
    const float* __restrict__ b1, const float* __restrict__ g1, const float* __restrict__ be1,
    const float* __restrict__ rm1, const float* __restrict__ rv1, unsigned* __restrict__ h1u) {
    __shared__ int   lds_s[4][72];
    __shared__ float lds_w[4][288];
    int wid = (blockIdx.x * 256 + threadIdx.x) >> 6;
    if (wid >= NN) return;
    int lane = threadIdx.x & 63;
    int warp = threadIdx.x >> 6;
    int n = wid;
    int e0 = off[n], e1 = off[n + 1];
    int deg = e1 - e0;
    int grp = lane >> 4;        // which edge of the 4-pack
    int c4 = lane & 15;         // uint4 index within row (features 8c4..8c4+7)
    int qh = c4 >> 2;           // head owning these features
    // zero the pad region (read when cn%4 != 0)
    if (lane < 8) {
        lds_s[warp][64 + lane] = 0;
        *(float4*)&lds_w[warp][(64 + lane) * 4] = make_float4(0.f, 0.f, 0.f, 0.f);
    }
    float4 adn = ad1[n];
    float4 asn = as1[n];
    float acc[8];
#pragma unroll
    for (int k = 0; k < 8; ++k) acc[k] = 0.f;
    float dsum0 = 0.f, dsum1 = 0.f, dsum2 = 0.f, dsum3 = 0.f;
    float aes0 = 0.f, aes1 = 0.f, aes2 = 0.f, aes3 = 0.f;

    for (int base = 0; base < deg; base += 64) {
        int i = base + lane;
        int cn = min(64, deg - base);
        int s = 0;
        float w0 = 0.f, w1 = 0.f, w2 = 0.f, w3 = 0.f;
        if (i < deg) {
            s = csrsrc[e0 + i];
            uint2 aeu = ae1b[e0 + i];
            float aex = bf_lo(aeu.x), aey = bf_hi(aeu.x);
            float aez = bf_lo(aeu.y), aew = bf_hi(aeu.y);
            float4 av = as1[s];
            float a0 = av.x + adn.x + aex;
            float a1 = av.y + adn.y + aey;
            float a2 = av.z + adn.z + aez;
            float a3 = av.w + adn.w + aew;
            a0 = a0 >= 0.f ? a0 : 0.2f * a0;
            a1 = a1 >= 0.f ? a1 : 0.2f * a1;
            a2 = a2 >= 0.f ? a2 : 0.2f * a2;
            a3 = a3 >= 0.f ? a3 : 0.2f * a3;
            w0 = __expf(a0); w1 = __expf(a1); w2 = __expf(a2); w3 = __expf(a3);
            dsum0 += w0; dsum1 += w1; dsum2 += w2; dsum3 += w3;
            aes0 += aex; aes1 += aey; aes2 += aez; aes3 += aew;
        }
        lds_s[warp][lane] = s;
        *(float4*)&lds_w[warp][lane * 4] = make_float4(w0, w1, w2, w3);
        __builtin_amdgcn_wave_barrier();
#pragma unroll 2
        for (int j = 0; j < cn; j += 4) {
            int jj = j + grp;
            int sj = lds_s[warp][jj];
            float wj = lds_w[warp][jj * 4 + qh];
            uint4 u = *(const uint4*)&xs1u[(size_t)sj * 64 + c4 * 4];
            acc[0] += wj * bf_lo(u.x); acc[1] += wj * bf_hi(u.x);
            acc[2] += wj * bf_lo(u.y); acc[3] += wj * bf_hi(u.y);
            acc[4] += wj * bf_lo(u.z); acc[5] += wj * bf_hi(u.z);
            acc[6] += wj * bf_lo(u.w); acc[7] += wj * bf_hi(u.w);
        }
        __builtin_amdgcn_wave_barrier();
    }
    // fold the 4 edge-groups together: lane -> sum over {lane, ^16, ^32, ^48}
#pragma unroll
    for (int k = 0; k < 8; ++k) {
        acc[k] += __shfl_xor(acc[k], 16);
        acc[k] += __shfl_xor(acc[k], 32);
    }
    // wave reductions for denom + edge-logit mean
#pragma unroll
    for (int d = 32; d >= 1; d >>= 1) {
        dsum0 += __shfl_xor(dsum0, d);
        dsum1 += __shfl_xor(dsum1, d);
        dsum2 += __shfl_xor(dsum2, d);
        dsum3 += __shfl_xor(dsum3, d);
        aes0 += __shfl_xor(aes0, d);
        aes1 += __shfl_xor(aes1, d);
        aes2 += __shfl_xor(aes2, d);
        aes3 += __shfl_xor(aes3, d);
    }
    if (grp == 0) {  // lanes 0..15 own the full row now
        float invd = 1.f / fmaxf((float)deg, 1.f);
        float aL0 = asn.x + adn.x + aes0 * invd;
        float aL1 = asn.y + adn.y + aes1 * invd;
        float aL2 = asn.z + adn.z + aes2 * invd;
        float aL3 = asn.w + adn.w + aes3 * invd;
        aL0 = aL0 >= 0.f ? aL0 : 0.2f * aL0;
        aL1 = aL1 >= 0.f ? aL1 : 0.2f * aL1;
        aL2 = aL2 >= 0.f ? aL2 : 0.2f * aL2;
        aL3 = aL3 >= 0.f ? aL3 : 0.2f * aL3;
        float ws0 = __expf(aL0), ws1 = __expf(aL1), ws2 = __expf(aL2), ws3 = __expf(aL3);
        float wself = qh == 0 ? ws0 : (qh == 1 ? ws1 : (qh == 2 ? ws2 : ws3));
        float dh = qh == 0 ? dsum0 + ws0 : (qh == 1 ? dsum1 + ws1 : (qh == 2 ? dsum2 + ws2 : dsum3 + ws3));
        uint4 us = *(const uint4*)&xs1u[(size_t)n * 64 + c4 * 4];
        acc[0] += wself * bf_lo(us.x); acc[1] += wself * bf_hi(us.x);
        acc[2] += wself * bf_lo(us.y); acc[3] += wself * bf_hi(us.y);
        acc[4] += wself * bf_lo(us.z); acc[5] += wself * bf_hi(us.z);
        acc[6] += wself * bf_lo(us.w); acc[7] += wself * bf_hi(us.w);
        float inv = 1.f / (dh + 1e-16f);
        int c = c4 * 8;
        uint4 ou;
        unsigned* op = (unsigned*)&ou;
#pragma unroll
        for (int k2 = 0; k2 < 4; ++k2) {
            int c0 = c + 2 * k2, c1 = c + 2 * k2 + 1;
            float o0 = acc[2 * k2] * inv + b1[c0];
            float o1 = acc[2 * k2 + 1] * inv + b1[c1];
            float sc0 = g1[c0] * rsqrtf(rv1[c0] + 1e-5f);
            float sc1 = g1[c1] * rsqrtf(rv1[c1] + 1e-5f);
            o0 = (o0 - rm1[c0]) * sc0 + be1[c0];
            o1 = (o1 - rm1[c1]) * sc1 + be1[c1];
            o0 = o0 > 0.f ? o0 : __expf(o0) - 1.f;
            o1 = o1 > 0.f ? o1 : __expf(o1) - 1.f;
            op[k2] = f2bf2(o0, o1);
        }
        *(uint4*)&h1u[(size_t)n * 64 + c4 * 4] = ou;
    }
}

// ---------------------------------------------------------------------------
// K8: GEMM2: xs2[N,40](bf16, stride 64) = h1(bf16)[N,128] @ W2[128,40].
__global__ __launch_bounds__(256) void gemm2_kernel(
    const unsigned* __restrict__ A, const float* __restrict__ W, unsigned* __restrict__ out) {
    __shared__ float sW[128 * 40];
    __shared__ float sXT[128 * 104];
    int t = threadIdx.x;
    int row0 = blockIdx.x * 96;
    for (int i = t; i < 128 * 40; i += 256) sW[i] = W[i];
    for (int i = t; i < 96 * 64; i += 256) {
        int r = i >> 6, ku = i & 63;
        int gr = row0 + r;
        unsigned u = (gr < NN) ? A[(size_t)gr * 64 + ku] : 0u;
        sXT[(2 * ku) * 104 + r] = bf_lo(u);
        sXT[(2 * ku + 1) * 104 + r] = bf_hi(u);
    }
    __syncthreads();
    if (t < 240) {
        int cg = t % 20;
        int rg = t / 20;
        float acc[8][2];
#pragma unroll
        for (int i = 0; i < 8; ++i) { acc[i][0] = 0.f; acc[i][1] = 0.f; }
#pragma unroll 4
        for (int k = 0; k < 128; ++k) {
            float2 b = *(const float2*)&sW[k * 40 + cg * 2];
            float4 a0 = *(const float4*)&sXT[k * 104 + rg * 8];
            float4 a1 = *(const float4*)&sXT[k * 104 + rg * 8 + 4];
            float av[8] = {a0.x, a0.y, a0.z, a0.w, a1.x, a1.y, a1.z, a1.w};
#pragma unroll
            for (int i = 0; i < 8; ++i) {
                acc[i][0] += av[i] * b.x;
                acc[i][1] += av[i] * b.y;
            }
        }
#pragma unroll
        for (int i = 0; i < 8; ++i) {
            int gr = row0 + rg * 8 + i;
            if (gr < NN) out[(size_t)gr * 32 + cg] = f2bf2(acc[i][0], acc[i][1]);
        }
    }
}

// ---------------------------------------------------------------------------
// K9: per-node attention coefficients layer 2 (from bf16 xs2).
__global__ __launch_bounds__(256) void alpha2_kernel(
    const unsigned* __restrict__ xs2u, const float* __restrict__ asw,
    const float* __restrict__ adw, float* __restrict__ as2, float* __restrict__ ad2) {
    int wid = (blockIdx.x * 256 + threadIdx.x) >> 6;
    if (wid >= NN) return;
    int lane = threadIdx.x & 63;
    float pa = 0.f, pd = 0.f;
    if (lane < 20) {
        unsigned u = xs2u[(size_t)wid * 32 + lane];
        float vx = bf_lo(u), vy = bf_hi(u);
        int c = lane * 2;
        pa = vx * asw[c] + vy * asw[c + 1];
        pd = vx * adw[c] + vy * adw[c + 1];
    }
#pragma unroll
    for (int d = 16; d >= 1; d >>= 1) {
        pa += __shfl_xor(pa, d, 32);
        pd += __shfl_xor(pd, d, 32);
    }
    if (lane == 0) { as2[wid] = pa; ad2[wid] = pd; }
}

// ---------------------------------------------------------------------------
// K10: layer-2 GAT aggregation + bias + BN + log_softmax. LDS-staged weights,
// 3 edges/iteration (20 lanes each).
__global__ __launch_bounds__(256) void gat2_kernel(
    const int* __restrict__ csrsrc, const int* __restrict__ off,
    const float* __restrict__ ae2p, const unsigned* __restrict__ xs2u,
    const float* __restrict__ as2, const float* __restrict__ ad2,
    const float* __restrict__ b2, const float* __restrict__ g2, const float* __restrict__ be2,
    const float* __restrict__ rm2, const float* __restrict__ rv2, float* __restrict__ outp) {
    __shared__ int   lds_s[4][72];
    __shared__ float lds_w[4][72];
    int wid = (blockIdx.x * 256 + threadIdx.x) >> 6;
    if (wid >= NN) return;
    int lane = threadIdx.x & 63;
    int warp = threadIdx.x >> 6;
    int n = wid;
    int e0 = off[n], e1 = off[n + 1];
    int deg = e1 - e0;
    int grp3 = lane / 20;               // 0,1,2 active; 3 = idle lanes 60..63
    int col = lane - grp3 * 20;
    bool act = grp3 < 3;
    if (lane < 8) {
        lds_s[warp][64 + lane] = 0;
        lds_w[warp][64 + lane] = 0.f;
    }
    float adn = ad2[n];
    float asn = as2[n];
    float acc0 = 0.f, acc1 = 0.f, dsum = 0.f, aesum = 0.f;

    for (int base = 0; base < deg; base += 64) {
        int i = base + lane;
        int cn = min(64, deg - base);
        int s = 0;
        float w = 0.f;
        if (i < deg) {
            s = csrsrc[e0 + i];
            float ae = ae2p[e0 + i];
            float a = as2[s] + adn + ae;
            a = a >= 0.f ? a : 0.2f * a;
            w = __expf(a);
            dsum += w;
            aesum += ae;
        }
        lds_s[warp][lane] = s;
        lds_w[warp][lane] = w;
        __builtin_amdgcn_wave_barrier();
#pragma unroll 2
        for (int j = 0; j < cn; j += 3) {
            int jj = j + (act ? grp3 : 0);
            int sj = lds_s[warp][jj];
            float wj = act ? lds_w[warp][jj] : 0.f;
            unsigned u = xs2u[(size_t)sj * 32 + col];
            acc0 += wj * bf_lo(u);
            acc1 += wj * bf_hi(u);
        }
        __builtin_amdgcn_wave_barrier();
    }
    // fold the 3 edge-groups: lane<20 pulls same-col partials from +20, +40
    {
        float p0 = __shfl(acc0, (lane + 20) & 63);
        float p1 = __shfl(acc1, (lane + 20) & 63);
        float q0 = __shfl(acc0, (lane + 40) & 63);
        float q1 = __shfl(acc1, (lane + 40) & 63);
        acc0 += p0 + q0;
        acc1 += p1 + q1;
    }
#pragma unroll
    for (int d = 32; d >= 1; d >>= 1) {
        dsum += __shfl_xor(dsum, d);
        aesum += __shfl_xor(aesum, d);
    }
    float invd = 1.f / fmaxf((float)deg, 1.f);
    float aL = asn + adn + aesum * invd;
    aL = aL >= 0.f ? aL : 0.2f * aL;
    float wself = __expf(aL);
    float denom = dsum + wself;

    float v0 = 0.f, v1 = 0.f;
    if (lane < 20) {
        unsigned u = xs2u[(size_t)n * 32 + lane];
        acc0 += wself * bf_lo(u);
        acc1 += wself * bf_hi(u);
        int c = lane * 2;
        float inv = 1.f / (denom + 1e-16f);
        v0 = acc0 * inv + b2[c];
        v1 = acc1 * inv + b2[c + 1];
        float sc0 = g2[c] * rsqrtf(rv2[c] + 1e-5f);
        float sc1 = g2[c + 1] * rsqrtf(rv2[c + 1] + 1e-5f);
        v0 = (v0 - rm2[c]) * sc0 + be2[c];
        v1 = (v1 - rm2[c + 1]) * sc1 + be2[c + 1];
    }
    float mx = (lane < 20) ? fmaxf(v0, v1) : -3.0e38f;
#pragma unroll
    for (int d = 32; d >= 1; d >>= 1) mx = fmaxf(mx, __shfl_xor(mx, d));
    float ex = (lane < 20) ? __expf(v0 - mx) + __expf(v1 - mx) : 0.f;
#pragma unroll
    for (int d = 32; d >= 1; d >>= 1) ex += __shfl_xor(ex, d);
    if (lane < 20) {
        float ls = __logf(ex);
        *(float2*)&outp[(size_t)n * 40 + lane * 2] = make_float2(v0 - mx - ls, v1 - mx - ls);
    }
}

// ---------------------------------------------------------------------------
extern "C" void kernel_launch(void* const* d_in, const int* in_sizes, int n_in,
                              void* d_out, int out_size, void* d_ws, size_t ws_size,
                              hipStream_t stream) {
    const float* x     = (const float*)d_in[0];
    const int*   ei    = (const int*)d_in[1];
    const float* eattr = (const float*)d_in[2];
    const float* W1    = (const float*)d_in[3];
    const float* as1w  = (const float*)d_in[4];
    const float* ad1w  = (const float*)d_in[5];
    const float* ae1w  = (const float*)d_in[6];
    const float* We1   = (const float*)d_in[7];
    const float* b1    = (const float*)d_in[8];
    const float* W2    = (const float*)d_in[9];
    const float* as2w  = (const float*)d_in[10];
    const float* ad2w  = (const float*)d_in[11];
    const float* ae2w  = (const float*)d_in[12];
    const float* We2   = (const float*)d_in[13];
    const float* b2    = (const float*)d_in[14];
    const float* g1    = (const float*)d_in[15];
    const float* be1   = (const float*)d_in[16];
    const float* rm1   = (const float*)d_in[17];
    const float* rv1   = (const float*)d_in[18];
    const float* g2    = (const float*)d_in[19];
    const float* be2   = (const float*)d_in[20];
    const float* rm2   = (const float*)d_in[21];
    const float* rv2   = (const float*)d_in[22];

    const int* src0 = ei;
    const int* dst0 = ei + NE;

    char* p = (char*)d_ws;
    auto take = [&](size_t nbytes) {
        void* r = (void*)p;
        p += (nbytes + 255) & ~(size_t)255;
        return r;
    };
    float*    wf1    = (float*)take(80);
    float*    wf2    = (float*)take(20);
    int*      cnt    = (int*)take((size_t)NN * 4);
    int*      off    = (int*)take((size_t)(NN + 1) * 4);
    int*      bsum   = (int*)take((size_t)SCAN_NB * 4);
    int*      cur    = (int*)take((size_t)NN * 4);
    int*      csrsrc = (int*)take((size_t)NE * 4);
    uint2*    ae1b   = (uint2*)take((size_t)NE * 8);
    float*    ae2p   = (float*)take((size_t)NE * 4);
    float*    as1    = (float*)take((size_t)NN * 16);
    float*    ad1    = (float*)take((size_t)NN * 16);
    float*    as2    = (float*)take((size_t)NN * 4);
    float*    ad2    = (float*)take((size_t)NN * 4);
    unsigned* xs1u   = (unsigned*)take((size_t)NN * 256);  // 64 uints/row (bf16x2)
    unsigned* h1u    = (unsigned*)take((size_t)NN * 256);
    unsigned* xs2u   = (unsigned*)take((size_t)NN * 128);  // 32 uints/row, cols 0..39 used

    hipMemsetAsync(cnt, 0, (size_t)NN * 4, stream);
    hipMemsetAsync(cur, 0, (size_t)NN * 4, stream);

    fold_kernel<<<1, 64, 0, stream>>>(We1, ae1w, We2, ae2w, wf1, wf2);
    count_kernel<<<(NE + 255) / 256, 256, 0, stream>>>(dst0, cnt);
    scan1_kernel<<<SCAN_NB, 256, 0, stream>>>(cnt, off, bsum);
    scan2_kernel<<<1, 256, 0, stream>>>(bsum);
    scan3_kernel<<<SCAN_NB, 256, 0, stream>>>(off, bsum, cnt);
    fill_fold_kernel<<<(NE + 255) / 256, 256, 0, stream>>>(src0, dst0, eattr, wf1, wf2,
                                                           off, cur, csrsrc, ae1b, ae2p);
    gemm1_kernel<<<(NN + 63) / 64, 256, 0, stream>>>(x, W1, xs1u);
    alpha1_kernel<<<(NN + 3) / 4, 256, 0, stream>>>(xs1u, as1w, ad1w, as1, ad1);
    gat1_kernel<<<(NN + 3) / 4, 256, 0, stream>>>(csrsrc, off, ae1b, xs1u, (const float4*)as1,
                                                  (const float4*)ad1, b1, g1, be1, rm1, rv1, h1u);
    gemm2_kernel<<<(NN + 95) / 96, 256, 0, stream>>>(h1u, W2, xs2u);
    alpha2_kernel<<<(NN + 3) / 4, 256, 0, stream>>>(xs2u, as2w, ad2w, as2, ad2);
    gat2_kernel<<<(NN + 3) / 4, 256, 0, stream>>>(csrsrc, off, ae2p, xs2u, as2, ad2,
                                                  b2, g2, be2, rm2, rv2, (float*)d_out);
}

// Round 6
// 276.884 us; speedup vs baseline: 2.3141x; 1.0162x over previous
//
#include <hip/hip_runtime.h>
#include <hip/hip_bf16.h>

#define NN 50000
#define NE 800000
#define SCAN_NB ((NN + 255) / 256)   // 196 blocks
// IN=128, HID=32, HEADS=4, HC=128, OUT=40, EDIM=5

// bf16 pack/unpack helpers (RNE rounding).
__device__ __forceinline__ unsigned f2bf2(float a, float b) {
    unsigned ua = __float_as_uint(a);
    ua = (ua + 0x7fffu + ((ua >> 16) & 1u)) >> 16;
    unsigned ub = __float_as_uint(b);
    ub = (ub + 0x7fffu + ((ub >> 16) & 1u)) >> 16;
    return ua | (ub << 16);
}
__device__ __forceinline__ float bf_lo(unsigned u) { return __uint_as_float(u << 16); }
__device__ __forceinline__ float bf_hi(unsigned u) { return __uint_as_float(u & 0xffff0000u); }

// ---------------------------------------------------------------------------
// K0: fold edge-weight matrices with attention vectors.
__global__ void fold_kernel(const float* __restrict__ We1, const float* __restrict__ ae1w,
                            const float* __restrict__ We2, const float* __restrict__ ae2w,
                            float* __restrict__ wf1, float* __restrict__ wf2) {
    int t = threadIdx.x;
    if (t < 20) {
        int j = t >> 2, h = t & 3;
        float s = 0.f;
        for (int c = 0; c < 32; ++c) s += We1[j * 128 + h * 32 + c] * ae1w[h * 32 + c];
        wf1[j * 4 + h] = s;
    }
    if (t >= 32 && t < 37) {
        int j = t - 32;
        float s = 0.f;
        for (int c = 0; c < 40; ++c) s += We2[j * 40 + c] * ae2w[c];
        wf2[j] = s;
    }
}

// ---------------------------------------------------------------------------
// K1: in-degree count.
__global__ __launch_bounds__(256) void count_kernel(const int* __restrict__ dst0,
                                                    int* __restrict__ cnt) {
    int e = blockIdx.x * 256 + threadIdx.x;
    if (e >= NE) return;
    atomicAdd(&cnt[dst0[e]], 1);
}

// ---------------------------------------------------------------------------
// K2a/b/c: two-level exclusive scan.
__global__ __launch_bounds__(256) void scan1_kernel(const int* __restrict__ cnt,
                                                    int* __restrict__ off,
                                                    int* __restrict__ bsum) {
    __shared__ int tmp[256];
    int t = threadIdx.x;
    int g = blockIdx.x * 256 + t;
    int v = (g < NN) ? cnt[g] : 0;
    tmp[t] = v;
    __syncthreads();
#pragma unroll
    for (int d = 1; d < 256; d <<= 1) {
        int u = (t >= d) ? tmp[t - d] : 0;
        __syncthreads();
        tmp[t] += u;
        __syncthreads();
    }
    if (g < NN) off[g] = tmp[t] - v;
    if (t == 255) bsum[blockIdx.x] = tmp[255];
}

__global__ __launch_bounds__(256) void scan2_kernel(int* __restrict__ bsum) {
    __shared__ int tmp[256];
    int t = threadIdx.x;
    int v = (t < SCAN_NB) ? bsum[t] : 0;
    tmp[t] = v;
    __syncthreads();
#pragma unroll
    for (int d = 1; d < 256; d <<= 1) {
        int u = (t >= d) ? tmp[t - d] : 0;
        __syncthreads();
        tmp[t] += u;
        __syncthreads();
    }
    if (t < SCAN_NB) bsum[t] = tmp[t] - v;
}

__global__ __launch_bounds__(256) void scan3_kernel(int* __restrict__ off,
                                                    const int* __restrict__ bsum,
                                                    const int* __restrict__ cnt) {
    int g = blockIdx.x * 256 + threadIdx.x;
    if (g < NN) {
        int o = off[g] + bsum[blockIdx.x];
        off[g] = o;
        if (g == NN - 1) off[NN] = o + cnt[g];
    }
}

// ---------------------------------------------------------------------------
// K3: fill CSR in slot order. ONE fused 16B record per edge:
//   .x = src node, .y/.z = layer-1 folded logits (bf16x4), .w = layer-2
//   folded logit (fp32 bits). Single dwordx4 scatter -> 1 cache line/edge.
__global__ __launch_bounds__(256) void fill_fold_kernel(
    const int* __restrict__ src0, const int* __restrict__ dst0,
    const float* __restrict__ eattr, const float* __restrict__ wf1,
    const float* __restrict__ wf2, const int* __restrict__ off, int* __restrict__ cur,
    uint4* __restrict__ epk) {
    int e = blockIdx.x * 256 + threadIdx.x;
    if (e >= NE) return;
    float a[5];
#pragma unroll
    for (int j = 0; j < 5; ++j) a[j] = eattr[(size_t)e * 5 + j];
    float o[4];
#pragma unroll
    for (int h = 0; h < 4; ++h) {
        float s = 0.f;
#pragma unroll
        for (int j = 0; j < 5; ++j) s += a[j] * wf1[j * 4 + h];
        o[h] = s;
    }
    float s2 = 0.f;
#pragma unroll
    for (int j = 0; j < 5; ++j) s2 += a[j] * wf2[j];
    int d = dst0[e];
    int p = atomicAdd(&cur[d], 1);
    int pos = off[d] + p;
    epk[pos] = make_uint4((unsigned)src0[e], f2bf2(o[0], o[1]), f2bf2(o[2], o[3]),
                          __float_as_uint(s2));
}

// ---------------------------------------------------------------------------
// K5: GEMM1: xs1[N,128](bf16) = x[N,128] @ W1[128,128].
__global__ __launch_bounds__(256) void gemm1_kernel(
    const float* __restrict__ A, const float* __restrict__ W, unsigned* __restrict__ out) {
    __shared__ float sW[64 * 132];
    __shared__ float sXT[64 * 72];
    int t = threadIdx.x;
    int row0 = blockIdx.x * 64;
    int cg = t & 31;
    int rg = t >> 5;
    float acc[8][4];
#pragma unroll
    for (int i = 0; i < 8; ++i)
#pragma unroll
        for (int j = 0; j < 4; ++j) acc[i][j] = 0.f;

    for (int kk = 0; kk < 128; kk += 64) {
        for (int i = t; i < 64 * 128; i += 256) {
            int k = i >> 7, c = i & 127;
            sW[k * 132 + c] = W[(size_t)(kk + k) * 128 + c];
        }
        for (int i = t; i < 64 * 64; i += 256) {
            int r = i >> 6, k = i & 63;
            int gr = row0 + r;
            sXT[k * 72 + r] = (gr < NN) ? A[(size_t)gr * 128 + kk + k] : 0.f;
        }
        __syncthreads();
#pragma unroll 4
        for (int k = 0; k < 64; ++k) {
            float4 b = *(const float4*)&sW[k * 132 + cg * 4];
            float4 a0 = *(const float4*)&sXT[k * 72 + rg * 8];
            float4 a1 = *(const float4*)&sXT[k * 72 + rg * 8 + 4];
            float av[8] = {a0.x, a0.y, a0.z, a0.w, a1.x, a1.y, a1.z, a1.w};
#pragma unroll
            for (int i = 0; i < 8; ++i) {
                acc[i][0] += av[i] * b.x;
                acc[i][1] += av[i] * b.y;
                acc[i][2] += av[i] * b.z;
                acc[i][3] += av[i] * b.w;
            }
        }
        __syncthreads();
    }
#pragma unroll
    for (int i = 0; i < 8; ++i) {
        int gr = row0 + rg * 8 + i;
        if (gr < NN) {
            uint2 o = make_uint2(f2bf2(acc[i][0], acc[i][1]), f2bf2(acc[i][2], acc[i][3]));
            *(uint2*)&out[(size_t)gr * 64 + cg * 2] = o;
        }
    }
}

// ---------------------------------------------------------------------------
// K6: per-node attention coefficients for layer 1 (from bf16 xs1).
__global__ __launch_bounds__(256) void alpha1_kernel(
    const unsigned* __restrict__ xs1u, const float* __restrict__ asw,
    const float* __restrict__ adw, float* __restrict__ as1, float* __restrict__ ad1) {
    int wid = (blockIdx.x * 256 + threadIdx.x) >> 6;
    if (wid >= NN) return;
    int lane = threadIdx.x & 63;
    int c = lane * 2;
    unsigned u = xs1u[(size_t)wid * 64 + lane];
    float vx = bf_lo(u), vy = bf_hi(u);
    float pa = vx * asw[c] + vy * asw[c + 1];
    float pd = vx * adw[c] + vy * adw[c + 1];
#pragma unroll
    for (int d = 8; d >= 1; d >>= 1) {
        pa += __shfl_xor(pa, d, 16);
        pd += __shfl_xor(pd, d, 16);
    }
    if ((lane & 15) == 0) {
        as1[wid * 4 + (lane >> 4)] = pa;
        ad1[wid * 4 + (lane >> 4)] = pd;
    }
}

// ---------------------------------------------------------------------------
// K7: layer-1 GAT aggregation. One wave per node. Weight phase stages
// (s, w[4]) for a 64-edge chunk into per-wave LDS; gather phase processes
// 4 edges/iteration (16 lanes x uint4 each = full 256B row per edge).
__global__ __launch_bounds__(256) void gat1_kernel(
    const uint4* __restrict__ epk, const int* __restrict__ off,
    const unsigned* __restrict__ xs1u,
    const float4* __restrict__ as1, const float4* __restrict__ ad1,
    const float* __restrict__ b1, const float* __restrict__ g1, const float* __restrict__ be1,
    const float* __restrict__ rm1, const float* __restrict__ rv1, unsigned* __restrict__ h1u) {
    __shared__ int   lds_s[4][72];
    __shared__ float lds_w[4][288];
    int wid = (blockIdx.x * 256 + threadIdx.x) >> 6;
    if (wid >= NN) return;
    int lane = threadIdx.x & 63;
    int warp = threadIdx.x >> 6;
    int n = wid;
    int e0 = off[n], e1 = off[n + 1];
    int deg = e1 - e0;
    int grp = lane >> 4;        // which edge of the 4-pack
    int c4 = lane & 15;         // uint4 index within row (features 8c4..8c4+7)
    int qh = c4 >> 2;           // head owning these features
    if (lane < 8) {
        lds_s[warp][64 + lane] = 0;
        *(float4*)&lds_w[warp][(64 + lane) * 4] = make_float4(0.f, 0.f, 0.f, 0.f);
    }
    float4 adn = ad1[n];
    float4 asn = as1[n];
    float acc[8];
#pragma unroll
    for (int k = 0; k < 8; ++k) acc[k] = 0.f;
    float dsum0 = 0.f, dsum1 = 0.f, dsum2 = 0.f, dsum3 = 0.f;
    float aes0 = 0.f, aes1 = 0.f, aes2 = 0.f, aes3 = 0.f;

    for (int base = 0; base < deg; base += 64) {
        int i = base + lane;
        int cn = min(64, deg - base);
        int s = 0;
        float w0 = 0.f, w1 = 0.f, w2 = 0.f, w3 = 0.f;
        if (i < deg) {
            uint4 ep = epk[e0 + i];
            s = (int)ep.x;
            float aex = bf_lo(ep.y), aey = bf_hi(ep.y);
            float aez = bf_lo(ep.z), aew = bf_hi(ep.z);
            float4 av = as1[s];
            float a0 = av.x + adn.x + aex;
            float a1 = av.y + adn.y + aey;
            float a2 = av.z + adn.z + aez;
            float a3 = av.w + adn.w + aew;
            a0 = a0 >= 0.f ? a0 : 0.2f * a0;
            a1 = a1 >= 0.f ? a1 : 0.2f * a1;
            a2 = a2 >= 0.f ? a2 : 0.2f * a2;
            a3 = a3 >= 0.f ? a3 : 0.2f * a3;
            w0 = __expf(a0); w1 = __expf(a1); w2 = __expf(a2); w3 = __expf(a3);
            dsum0 += w0; dsum1 += w1; dsum2 += w2; dsum3 += w3;
            aes0 += aex; aes1 += aey; aes2 += aez; aes3 += aew;
        }
        lds_s[warp][lane] = s;
        *(float4*)&lds_w[warp][lane * 4] = make_float4(w0, w1, w2, w3);
        __builtin_amdgcn_wave_barrier();
#pragma unroll 2
        for (int j = 0; j < cn; j += 4) {
            int jj = j + grp;
            int sj = lds_s[warp][jj];
            float wj = lds_w[warp][jj * 4 + qh];
            uint4 u = *(const uint4*)&xs1u[(size_t)sj * 64 + c4 * 4];
            acc[0] += wj * bf_lo(u.x); acc[1] += wj * bf_hi(u.x);
            acc[2] += wj * bf_lo(u.y); acc[3] += wj * bf_hi(u.y);
            acc[4] += wj * bf_lo(u.z); acc[5] += wj * bf_hi(u.z);
            acc[6] += wj * bf_lo(u.w); acc[7] += wj * bf_hi(u.w);
        }
        __builtin_amdgcn_wave_barrier();
    }
#pragma unroll
    for (int k = 0; k < 8; ++k) {
        acc[k] += __shfl_xor(acc[k], 16);
        acc[k] += __shfl_xor(acc[k], 32);
    }
#pragma unroll
    for (int d = 32; d >= 1; d >>= 1) {
        dsum0 += __shfl_xor(dsum0, d);
        dsum1 += __shfl_xor(dsum1, d);
        dsum2 += __shfl_xor(dsum2, d);
        dsum3 += __shfl_xor(dsum3, d);
        aes0 += __shfl_xor(aes0, d);
        aes1 += __shfl_xor(aes1, d);
        aes2 += __shfl_xor(aes2, d);
        aes3 += __shfl_xor(aes3, d);
    }
    if (grp == 0) {  // lanes 0..15 own the full row now
        float invd = 1.f / fmaxf((float)deg, 1.f);
        float aL0 = asn.x + adn.x + aes0 * invd;
        float aL1 = asn.y + adn.y + aes1 * invd;
        float aL2 = asn.z + adn.z + aes2 * invd;
        float aL3 = asn.w + adn.w + aes3 * invd;
        aL0 = aL0 >= 0.f ? aL0 : 0.2f * aL0;
        aL1 = aL1 >= 0.f ? aL1 : 0.2f * aL1;
        aL2 = aL2 >= 0.f ? aL2 : 0.2f * aL2;
        aL3 = aL3 >= 0.f ? aL3 : 0.2f * aL3;
        float ws0 = __expf(aL0), ws1 = __expf(aL1), ws2 = __expf(aL2), ws3 = __expf(aL3);
        float wself = qh == 0 ? ws0 : (qh == 1 ? ws1 : (qh == 2 ? ws2 : ws3));
        float dh = qh == 0 ? dsum0 + ws0 : (qh == 1 ? dsum1 + ws1 : (qh == 2 ? dsum2 + ws2 : dsum3 + ws3));
        uint4 us = *(const uint4*)&xs1u[(size_t)n * 64 + c4 * 4];
        acc[0] += wself * bf_lo(us.x); acc[1] += wself * bf_hi(us.x);
        acc[2] += wself * bf_lo(us.y); acc[3] += wself * bf_hi(us.y);
        acc[4] += wself * bf_lo(us.z); acc[5] += wself * bf_hi(us.z);
        acc[6] += wself * bf_lo(us.w); acc[7] += wself * bf_hi(us.w);
        float inv = 1.f / (dh + 1e-16f);
        int c = c4 * 8;
        uint4 ou;
        unsigned* op = (unsigned*)&ou;
#pragma unroll
        for (int k2 = 0; k2 < 4; ++k2) {
            int c0 = c + 2 * k2, c1 = c + 2 * k2 + 1;
            float o0 = acc[2 * k2] * inv + b1[c0];
            float o1 = acc[2 * k2 + 1] * inv + b1[c1];
            float sc0 = g1[c0] * rsqrtf(rv1[c0] + 1e-5f);
            float sc1 = g1[c1] * rsqrtf(rv1[c1] + 1e-5f);
            o0 = (o0 - rm1[c0]) * sc0 + be1[c0];
            o1 = (o1 - rm1[c1]) * sc1 + be1[c1];
            o0 = o0 > 0.f ? o0 : __expf(o0) - 1.f;
            o1 = o1 > 0.f ? o1 : __expf(o1) - 1.f;
            op[k2] = f2bf2(o0, o1);
        }
        *(uint4*)&h1u[(size_t)n * 64 + c4 * 4] = ou;
    }
}

// ---------------------------------------------------------------------------
// K8: GEMM2: xs2[N,40](bf16, stride 64) = h1(bf16)[N,128] @ W2[128,40].
__global__ __launch_bounds__(256) void gemm2_kernel(
    const unsigned* __restrict__ A, const float* __restrict__ W, unsigned* __restrict__ out) {
    __shared__ float sW[128 * 40];
    __shared__ float sXT[128 * 104];
    int t = threadIdx.x;
    int row0 = blockIdx.x * 96;
    for (int i = t; i < 128 * 40; i += 256) sW[i] = W[i];
    for (int i = t; i < 96 * 64; i += 256) {
        int r = i >> 6, ku = i & 63;
        int gr = row0 + r;
        unsigned u = (gr < NN) ? A[(size_t)gr * 64 + ku] : 0u;
        sXT[(2 * ku) * 104 + r] = bf_lo(u);
        sXT[(2 * ku + 1) * 104 + r] = bf_hi(u);
    }
    __syncthreads();
    if (t < 240) {
        int cg = t % 20;
        int rg = t / 20;
        float acc[8][2];
#pragma unroll
        for (int i = 0; i < 8; ++i) { acc[i][0] = 0.f; acc[i][1] = 0.f; }
#pragma unroll 4
        for (int k = 0; k < 128; ++k) {
            float2 b = *(const float2*)&sW[k * 40 + cg * 2];
            float4 a0 = *(const float4*)&sXT[k * 104 + rg * 8];
            float4 a1 = *(const float4*)&sXT[k * 104 + rg * 8 + 4];
            float av[8] = {a0.x, a0.y, a0.z, a0.w, a1.x, a1.y, a1.z, a1.w};
#pragma unroll
            for (int i = 0; i < 8; ++i) {
                acc[i][0] += av[i] * b.x;
                acc[i][1] += av[i] * b.y;
            }
        }
#pragma unroll
        for (int i = 0; i < 8; ++i) {
            int gr = row0 + rg * 8 + i;
            if (gr < NN) out[(size_t)gr * 32 + cg] = f2bf2(acc[i][0], acc[i][1]);
        }
    }
}

// ---------------------------------------------------------------------------
// K9: per-node attention coefficients layer 2 (from bf16 xs2).
__global__ __launch_bounds__(256) void alpha2_kernel(
    const unsigned* __restrict__ xs2u, const float* __restrict__ asw,
    const float* __restrict__ adw, float* __restrict__ as2, float* __restrict__ ad2) {
    int wid = (blockIdx.x * 256 + threadIdx.x) >> 6;
    if (wid >= NN) return;
    int lane = threadIdx.x & 63;
    float pa = 0.f, pd = 0.f;
    if (lane < 20) {
        unsigned u = xs2u[(size_t)wid * 32 + lane];
        float vx = bf_lo(u), vy = bf_hi(u);
        int c = lane * 2;
        pa = vx * asw[c] + vy * asw[c + 1];
        pd = vx * adw[c] + vy * adw[c + 1];
    }
#pragma unroll
    for (int d = 16; d >= 1; d >>= 1) {
        pa += __shfl_xor(pa, d, 32);
        pd += __shfl_xor(pd, d, 32);
    }
    if (lane == 0) { as2[wid] = pa; ad2[wid] = pd; }
}

// ---------------------------------------------------------------------------
// K10: layer-2 GAT aggregation + bias + BN + log_softmax. LDS-staged weights,
// 3 edges/iteration (20 lanes each).
__global__ __launch_bounds__(256) void gat2_kernel(
    const uint4* __restrict__ epk, const int* __restrict__ off,
    const unsigned* __restrict__ xs2u,
    const float* __restrict__ as2, const float* __restrict__ ad2,
    const float* __restrict__ b2, const float* __restrict__ g2, const float* __restrict__ be2,
    const float* __restrict__ rm2, const float* __restrict__ rv2, float* __restrict__ outp) {
    __shared__ int   lds_s[4][72];
    __shared__ float lds_w[4][72];
    int wid = (blockIdx.x * 256 + threadIdx.x) >> 6;
    if (wid >= NN) return;
    int lane = threadIdx.x & 63;
    int warp = threadIdx.x >> 6;
    int n = wid;
    int e0 = off[n], e1 = off[n + 1];
    int deg = e1 - e0;
    int grp3 = lane / 20;               // 0,1,2 active; 3 = idle lanes 60..63
    int col = lane - grp3 * 20;
    bool act = grp3 < 3;
    if (lane < 8) {
        lds_s[warp][64 + lane] = 0;
        lds_w[warp][64 + lane] = 0.f;
    }
    float adn = ad2[n];
    float asn = as2[n];
    float acc0 = 0.f, acc1 = 0.f, dsum = 0.f, aesum = 0.f;

    for (int base = 0; base < deg; base += 64) {
        int i = base + lane;
        int cn = min(64, deg - base);
        int s = 0;
        float w = 0.f;
        if (i < deg) {
            uint4 ep = epk[e0 + i];
            s = (int)ep.x;
            float ae = __uint_as_float(ep.w);
            float a = as2[s] + adn + ae;
            a = a >= 0.f ? a : 0.2f * a;
            w = __expf(a);
            dsum += w;
            aesum += ae;
        }
        lds_s[warp][lane] = s;
        lds_w[warp][lane] = w;
        __builtin_amdgcn_wave_barrier();
#pragma unroll 2
        for (int j = 0; j < cn; j += 3) {
            int jj = j + (act ? grp3 : 0);
            int sj = lds_s[warp][jj];
            float wj = act ? lds_w[warp][jj] : 0.f;
            unsigned u = xs2u[(size_t)sj * 32 + col];
            acc0 += wj * bf_lo(u);
            acc1 += wj * bf_hi(u);
        }
        __builtin_amdgcn_wave_barrier();
    }
    {
        float p0 = __shfl(acc0, (lane + 20) & 63);
        float p1 = __shfl(acc1, (lane + 20) & 63);
        float q0 = __shfl(acc0, (lane + 40) & 63);
        float q1 = __shfl(acc1, (lane + 40) & 63);
        acc0 += p0 + q0;
        acc1 += p1 + q1;
    }
#pragma unroll
    for (int d = 32; d >= 1; d >>= 1) {
        dsum += __shfl_xor(dsum, d);
        aesum += __shfl_xor(aesum, d);
    }
    float invd = 1.f / fmaxf((float)deg, 1.f);
    float aL = asn + adn + aesum * invd;
    aL = aL >= 0.f ? aL : 0.2f * aL;
    float wself = __expf(aL);
    float denom = dsum + wself;

    float v0 = 0.f, v1 = 0.f;
    if (lane < 20) {
        unsigned u = xs2u[(size_t)n * 32 + lane];
        acc0 += wself * bf_lo(u);
        acc1 += wself * bf_hi(u);
        int c = lane * 2;
        float inv = 1.f / (denom + 1e-16f);
        v0 = acc0 * inv + b2[c];
        v1 = acc1 * inv + b2[c + 1];
        float sc0 = g2[c] * rsqrtf(rv2[c] + 1e-5f);
        float sc1 = g2[c + 1] * rsqrtf(rv2[c + 1] + 1e-5f);
        v0 = (v0 - rm2[c]) * sc0 + be2[c];
        v1 = (v1 - rm2[c + 1]) * sc1 + be2[c + 1];
    }
    float mx = (lane < 20) ? fmaxf(v0, v1) : -3.0e38f;
#pragma unroll
    for (int d = 32; d >= 1; d >>= 1) mx = fmaxf(mx, __shfl_xor(mx, d));
    float ex = (lane < 20) ? __expf(v0 - mx) + __expf(v1 - mx) : 0.f;
#pragma unroll
    for (int d = 32; d >= 1; d >>= 1) ex += __shfl_xor(ex, d);
    if (lane < 20) {
        float ls = __logf(ex);
        *(float2*)&outp[(size_t)n * 40 + lane * 2] = make_float2(v0 - mx - ls, v1 - mx - ls);
    }
}

// ---------------------------------------------------------------------------
extern "C" void kernel_launch(void* const* d_in, const int* in_sizes, int n_in,
                              void* d_out, int out_size, void* d_ws, size_t ws_size,
                              hipStream_t stream) {
    const float* x     = (const float*)d_in[0];
    const int*   ei    = (const int*)d_in[1];
    const float* eattr = (const float*)d_in[2];
    const float* W1    = (const float*)d_in[3];
    const float* as1w  = (const float*)d_in[4];
    const float* ad1w  = (const float*)d_in[5];
    const float* ae1w  = (const float*)d_in[6];
    const float* We1   = (const float*)d_in[7];
    const float* b1    = (const float*)d_in[8];
    const float* W2    = (const float*)d_in[9];
    const float* as2w  = (const float*)d_in[10];
    const float* ad2w  = (const float*)d_in[11];
    const float* ae2w  = (const float*)d_in[12];
    const float* We2   = (const float*)d_in[13];
    const float* b2    = (const float*)d_in[14];
    const float* g1    = (const float*)d_in[15];
    const float* be1   = (const float*)d_in[16];
    const float* rm1   = (const float*)d_in[17];
    const float* rv1   = (const float*)d_in[18];
    const float* g2    = (const float*)d_in[19];
    const float* be2   = (const float*)d_in[20];
    const float* rm2   = (const float*)d_in[21];
    const float* rv2   = (const float*)d_in[22];

    const int* src0 = ei;
    const int* dst0 = ei + NE;

    char* p = (char*)d_ws;
    auto take = [&](size_t nbytes) {
        void* r = (void*)p;
        p += (nbytes + 255) & ~(size_t)255;
        return r;
    };
    float*    wf1    = (float*)take(80);
    float*    wf2    = (float*)take(20);
    int*      cnt    = (int*)take((size_t)NN * 4);
    int*      off    = (int*)take((size_t)(NN + 1) * 4);
    int*      bsum   = (int*)take((size_t)SCAN_NB * 4);
    int*      cur    = (int*)take((size_t)NN * 4);
    uint4*    epk    = (uint4*)take((size_t)NE * 16);
    float*    as1    = (float*)take((size_t)NN * 16);
    float*    ad1    = (float*)take((size_t)NN * 16);
    float*    as2    = (float*)take((size_t)NN * 4);
    float*    ad2    = (float*)take((size_t)NN * 4);
    unsigned* xs1u   = (unsigned*)take((size_t)NN * 256);  // 64 uints/row (bf16x2)
    unsigned* h1u    = (unsigned*)take((size_t)NN * 256);
    unsigned* xs2u   = (unsigned*)take((size_t)NN * 128);  // 32 uints/row, cols 0..39 used

    hipMemsetAsync(cnt, 0, (size_t)NN * 4, stream);
    hipMemsetAsync(cur, 0, (size_t)NN * 4, stream);

    fold_kernel<<<1, 64, 0, stream>>>(We1, ae1w, We2, ae2w, wf1, wf2);
    count_kernel<<<(NE + 255) / 256, 256, 0, stream>>>(dst0, cnt);
    scan1_kernel<<<SCAN_NB, 256, 0, stream>>>(cnt, off, bsum);
    scan2_kernel<<<1, 256, 0, stream>>>(bsum);
    scan3_kernel<<<SCAN_NB, 256, 0, stream>>>(off, bsum, cnt);
    fill_fold_kernel<<<(NE + 255) / 256, 256, 0, stream>>>(src0, dst0, eattr, wf1, wf2,
                                                           off, cur, epk);
    gemm1_kernel<<<(NN + 63) / 64, 256, 0, stream>>>(x, W1, xs1u);
    alpha1_kernel<<<(NN + 3) / 4, 256, 0, stream>>>(xs1u, as1w, ad1w, as1, ad1);
    gat1_kernel<<<(NN + 3) / 4, 256, 0, stream>>>(epk, off, xs1u, (const float4*)as1,
                                                  (const float4*)ad1, b1, g1, be1, rm1, rv1, h1u);
    gemm2_kernel<<<(NN + 95) / 96, 256, 0, stream>>>(h1u, W2, xs2u);
    alpha2_kernel<<<(NN + 3) / 4, 256, 0, stream>>>(xs2u, as2w, ad2w, as2, ad2);
    gat2_kernel<<<(NN + 3) / 4, 256, 0, stream>>>(epk, off, xs2u, as2, ad2,
                                                  b2, g2, be2, rm2, rv2, (float*)d_out);
}

// Round 7
// 220.160 us; speedup vs baseline: 2.9103x; 1.2576x over previous
//
#include <hip/hip_runtime.h>
#include <hip/hip_bf16.h>

#define NN 50000
#define NE 800000
#define SCAN_NB ((NN + 255) / 256)   // 196 blocks
// IN=128, HID=32, HEADS=4, HC=128, OUT=40, EDIM=5

typedef float f32x4_t __attribute__((ext_vector_type(4)));
typedef short s16x8_t __attribute__((ext_vector_type(8)));

// bf16 pack/unpack helpers (RNE rounding).
__device__ __forceinline__ unsigned f2bf2(float a, float b) {
    unsigned ua = __float_as_uint(a);
    ua = (ua + 0x7fffu + ((ua >> 16) & 1u)) >> 16;
    unsigned ub = __float_as_uint(b);
    ub = (ub + 0x7fffu + ((ub >> 16) & 1u)) >> 16;
    return ua | (ub << 16);
}
__device__ __forceinline__ float bf_lo(unsigned u) { return __uint_as_float(u << 16); }
__device__ __forceinline__ float bf_hi(unsigned u) { return __uint_as_float(u & 0xffff0000u); }

// ---------------------------------------------------------------------------
// K0: prep — fold edge-weight matrices with attention vectors + build
// bf16-transposed weight matrices for the MFMA GEMMs.
// w1t[c][kp] packs W1[2kp][c],W1[2kp+1][c]; w2t likewise (cols 40..47 = 0).
__global__ __launch_bounds__(256) void prep_kernel(
    const float* __restrict__ We1, const float* __restrict__ ae1w,
    const float* __restrict__ We2, const float* __restrict__ ae2w,
    const float* __restrict__ W1, const float* __restrict__ W2,
    float* __restrict__ wf1, float* __restrict__ wf2,
    unsigned* __restrict__ w1t, unsigned* __restrict__ w2t) {
    int t = threadIdx.x;
    if (t < 20) {
        int j = t >> 2, h = t & 3;
        float s = 0.f;
        for (int c = 0; c < 32; ++c) s += We1[j * 128 + h * 32 + c] * ae1w[h * 32 + c];
        wf1[j * 4 + h] = s;
    }
    if (t >= 32 && t < 37) {
        int j = t - 32;
        float s = 0.f;
        for (int c = 0; c < 40; ++c) s += We2[j * 40 + c] * ae2w[c];
        wf2[j] = s;
    }
    for (int i = t; i < 128 * 64; i += 256) {
        int c = i >> 6, kp = i & 63;
        w1t[i] = f2bf2(W1[(size_t)(2 * kp) * 128 + c], W1[(size_t)(2 * kp + 1) * 128 + c]);
    }
    for (int i = t; i < 48 * 64; i += 256) {
        int c = i >> 6, kp = i & 63;
        w2t[i] = (c < 40) ? f2bf2(W2[(size_t)(2 * kp) * 40 + c], W2[(size_t)(2 * kp + 1) * 40 + c]) : 0u;
    }
}

// ---------------------------------------------------------------------------
// K1: in-degree count.
__global__ __launch_bounds__(256) void count_kernel(const int* __restrict__ dst0,
                                                    int* __restrict__ cnt) {
    int e = blockIdx.x * 256 + threadIdx.x;
    if (e >= NE) return;
    atomicAdd(&cnt[dst0[e]], 1);
}

// ---------------------------------------------------------------------------
// K2a/b/c: two-level exclusive scan.
__global__ __launch_bounds__(256) void scan1_kernel(const int* __restrict__ cnt,
                                                    int* __restrict__ off,
                                                    int* __restrict__ bsum) {
    __shared__ int tmp[256];
    int t = threadIdx.x;
    int g = blockIdx.x * 256 + t;
    int v = (g < NN) ? cnt[g] : 0;
    tmp[t] = v;
    __syncthreads();
#pragma unroll
    for (int d = 1; d < 256; d <<= 1) {
        int u = (t >= d) ? tmp[t - d] : 0;
        __syncthreads();
        tmp[t] += u;
        __syncthreads();
    }
    if (g < NN) off[g] = tmp[t] - v;
    if (t == 255) bsum[blockIdx.x] = tmp[255];
}

__global__ __launch_bounds__(256) void scan2_kernel(int* __restrict__ bsum) {
    __shared__ int tmp[256];
    int t = threadIdx.x;
    int v = (t < SCAN_NB) ? bsum[t] : 0;
    tmp[t] = v;
    __syncthreads();
#pragma unroll
    for (int d = 1; d < 256; d <<= 1) {
        int u = (t >= d) ? tmp[t - d] : 0;
        __syncthreads();
        tmp[t] += u;
        __syncthreads();
    }
    if (t < SCAN_NB) bsum[t] = tmp[t] - v;
}

__global__ __launch_bounds__(256) void scan3_kernel(int* __restrict__ off,
                                                    const int* __restrict__ bsum,
                                                    const int* __restrict__ cnt) {
    int g = blockIdx.x * 256 + threadIdx.x;
    if (g < NN) {
        int o = off[g] + bsum[blockIdx.x];
        off[g] = o;
        if (g == NN - 1) off[NN] = o + cnt[g];
    }
}

// ---------------------------------------------------------------------------
// K3: fill CSR in slot order. ONE fused 16B record per edge.
__global__ __launch_bounds__(256) void fill_fold_kernel(
    const int* __restrict__ src0, const int* __restrict__ dst0,
    const float* __restrict__ eattr, const float* __restrict__ wf1,
    const float* __restrict__ wf2, const int* __restrict__ off, int* __restrict__ cur,
    uint4* __restrict__ epk) {
    int e = blockIdx.x * 256 + threadIdx.x;
    if (e >= NE) return;
    float a[5];
#pragma unroll
    for (int j = 0; j < 5; ++j) a[j] = eattr[(size_t)e * 5 + j];
    float o[4];
#pragma unroll
    for (int h = 0; h < 4; ++h) {
        float s = 0.f;
#pragma unroll
        for (int j = 0; j < 5; ++j) s += a[j] * wf1[j * 4 + h];
        o[h] = s;
    }
    float s2 = 0.f;
#pragma unroll
    for (int j = 0; j < 5; ++j) s2 += a[j] * wf2[j];
    int d = dst0[e];
    int p = atomicAdd(&cur[d], 1);
    int pos = off[d] + p;
    epk[pos] = make_uint4((unsigned)src0[e], f2bf2(o[0], o[1]), f2bf2(o[2], o[3]),
                          __float_as_uint(s2));
}

// ---------------------------------------------------------------------------
// K5: MFMA GEMM1: xs1[N,128](bf16) = x[N,128] @ W1[128,128].
// 64 rows/block, 4 waves x 16 rows, B transposed bf16 in LDS (stride 68 u32).
__global__ __launch_bounds__(256) void gemm1_mfma(
    const float* __restrict__ A, const unsigned* __restrict__ w1t,
    unsigned* __restrict__ out) {
    __shared__ unsigned sA[64 * 68];
    __shared__ unsigned sB[128 * 68];
    int t = threadIdx.x;
    int row0 = blockIdx.x * 64;
    for (int i = t; i < 64 * 32; i += 256) {     // x rows -> bf16 LDS
        int r = i >> 5, q = i & 31;              // q: float4 idx (feats 4q..4q+3)
        int gr = row0 + r;
        float4 v = (gr < NN) ? *(const float4*)&A[(size_t)gr * 128 + q * 4]
                             : make_float4(0.f, 0.f, 0.f, 0.f);
        sA[r * 68 + q * 2]     = f2bf2(v.x, v.y);
        sA[r * 68 + q * 2 + 1] = f2bf2(v.z, v.w);
    }
    for (int i = t; i < 128 * 16; i += 256) {    // w1t -> LDS
        int c = i >> 4, q = i & 15;
        *(uint4*)&sB[c * 68 + q * 4] = *(const uint4*)&w1t[c * 64 + q * 4];
    }
    __syncthreads();
    int wv = t >> 6, lane = t & 63;
    int lr = lane & 15, kgrp = lane >> 4;
    f32x4_t acc[8];
#pragma unroll
    for (int i = 0; i < 8; ++i) acc[i] = (f32x4_t){0.f, 0.f, 0.f, 0.f};
    int arow = wv * 16 + lr;
#pragma unroll
    for (int kt = 0; kt < 4; ++kt) {
        int kw = kt * 16 + kgrp * 4;             // word offset: k = kt*32 + kgrp*8
        s16x8_t af = *(const s16x8_t*)&sA[arow * 68 + kw];
#pragma unroll
        for (int tc = 0; tc < 8; ++tc) {
            s16x8_t bf = *(const s16x8_t*)&sB[(tc * 16 + lr) * 68 + kw];
            acc[tc] = __builtin_amdgcn_mfma_f32_16x16x32_bf16(af, bf, acc[tc], 0, 0, 0);
        }
    }
    // C: col = tc*16 + lr, row = kgrp*4 + r. Pack col pairs via shfl_xor(1).
    int orow0 = row0 + wv * 16 + kgrp * 4;
#pragma unroll
    for (int tc = 0; tc < 8; ++tc) {
#pragma unroll
        for (int r = 0; r < 4; ++r) {
            float v = acc[tc][r];
            float other = __shfl_xor(v, 1);
            int gr = orow0 + r;
            if (!(lane & 1) && gr < NN)
                out[(size_t)gr * 64 + tc * 8 + (lr >> 1)] = f2bf2(v, other);
        }
    }
}

// ---------------------------------------------------------------------------
// K6: per-node attention coefficients for layer 1 (from bf16 xs1).
__global__ __launch_bounds__(256) void alpha1_kernel(
    const unsigned* __restrict__ xs1u, const float* __restrict__ asw,
    const float* __restrict__ adw, float* __restrict__ as1, float* __restrict__ ad1) {
    int wid = (blockIdx.x * 256 + threadIdx.x) >> 6;
    if (wid >= NN) return;
    int lane = threadIdx.x & 63;
    int c = lane * 2;
    unsigned u = xs1u[(size_t)wid * 64 + lane];
    float vx = bf_lo(u), vy = bf_hi(u);
    float pa = vx * asw[c] + vy * asw[c + 1];
    float pd = vx * adw[c] + vy * adw[c + 1];
#pragma unroll
    for (int d = 8; d >= 1; d >>= 1) {
        pa += __shfl_xor(pa, d, 16);
        pd += __shfl_xor(pd, d, 16);
    }
    if ((lane & 15) == 0) {
        as1[wid * 4 + (lane >> 4)] = pa;
        ad1[wid * 4 + (lane >> 4)] = pd;
    }
}

// ---------------------------------------------------------------------------
// K7: layer-1 GAT aggregation. 4 nodes per wave, 16 lanes per node
// (NN = 3125 blocks x 16 nodes exactly). Weight phase fully lane-utilized;
// no cross-group accumulator fold; width-16 reductions.
__global__ __launch_bounds__(256) void gat1_kernel(
    const uint4* __restrict__ epk, const int* __restrict__ off,
    const unsigned* __restrict__ xs1u,
    const float4* __restrict__ as1, const float4* __restrict__ ad1,
    const float* __restrict__ b1, const float* __restrict__ g1, const float* __restrict__ be1,
    const float* __restrict__ rm1, const float* __restrict__ rv1, unsigned* __restrict__ h1u) {
    __shared__ int   lds_s[4][4][16];
    __shared__ float lds_w[4][4][16][4];
    int wave = threadIdx.x >> 6;
    int lane = threadIdx.x & 63;
    int g = lane >> 4;          // group = node slot within wave
    int lr = lane & 15;         // lane within group: uint4 idx (feats 8lr..8lr+7)
    int qh = lr >> 2;           // head owning these features
    int n = blockIdx.x * 16 + wave * 4 + g;
    int e0 = off[n];
    int deg = off[n + 1] - e0;
    float4 adn = ad1[n];
    float4 asn = as1[n];
    float acc[8];
#pragma unroll
    for (int k = 0; k < 8; ++k) acc[k] = 0.f;
    float ds0 = 0.f, ds1 = 0.f, ds2 = 0.f, ds3 = 0.f;
    float s0 = 0.f, s1 = 0.f, s2 = 0.f, s3 = 0.f;   // ae sums (self-loop mean)
    int mc = (deg + 15) >> 4;
    mc = max(mc, __shfl_xor(mc, 16));
    mc = max(mc, __shfl_xor(mc, 32));

    for (int ch = 0; ch < mc; ++ch) {
        int i = ch * 16 + lr;
        int s = 0;
        float w0 = 0.f, w1 = 0.f, w2 = 0.f, w3 = 0.f;
        if (i < deg) {
            uint4 ep = epk[e0 + i];
            s = (int)ep.x;
            float ax = bf_lo(ep.y), ay = bf_hi(ep.y);
            float az = bf_lo(ep.z), aw = bf_hi(ep.z);
            float4 av = as1[s];
            float a0 = av.x + adn.x + ax;
            float a1 = av.y + adn.y + ay;
            float a2 = av.z + adn.z + az;
            float a3 = av.w + adn.w + aw;
            a0 = a0 >= 0.f ? a0 : 0.2f * a0;
            a1 = a1 >= 0.f ? a1 : 0.2f * a1;
            a2 = a2 >= 0.f ? a2 : 0.2f * a2;
            a3 = a3 >= 0.f ? a3 : 0.2f * a3;
            w0 = __expf(a0); w1 = __expf(a1); w2 = __expf(a2); w3 = __expf(a3);
            ds0 += w0; ds1 += w1; ds2 += w2; ds3 += w3;
            s0 += ax; s1 += ay; s2 += az; s3 += aw;
        }
        lds_s[wave][g][lr] = s;
        *(float4*)&lds_w[wave][g][lr][0] = make_float4(w0, w1, w2, w3);
        __builtin_amdgcn_wave_barrier();
        int cn = min(16, deg - ch * 16);
        for (int j = 0; j < cn; ++j) {
            int sj = lds_s[wave][g][j];
            float wj = lds_w[wave][g][j][qh];
            uint4 u = *(const uint4*)&xs1u[(size_t)sj * 64 + lr * 4];
            acc[0] += wj * bf_lo(u.x); acc[1] += wj * bf_hi(u.x);
            acc[2] += wj * bf_lo(u.y); acc[3] += wj * bf_hi(u.y);
            acc[4] += wj * bf_lo(u.z); acc[5] += wj * bf_hi(u.z);
            acc[6] += wj * bf_lo(u.w); acc[7] += wj * bf_hi(u.w);
        }
        __builtin_amdgcn_wave_barrier();
    }
    // width-16 reductions (per node)
#pragma unroll
    for (int d = 8; d >= 1; d >>= 1) {
        ds0 += __shfl_xor(ds0, d, 16); ds1 += __shfl_xor(ds1, d, 16);
        ds2 += __shfl_xor(ds2, d, 16); ds3 += __shfl_xor(ds3, d, 16);
        s0 += __shfl_xor(s0, d, 16);   s1 += __shfl_xor(s1, d, 16);
        s2 += __shfl_xor(s2, d, 16);   s3 += __shfl_xor(s3, d, 16);
    }
    float invd = 1.f / fmaxf((float)deg, 1.f);
    float aL0 = asn.x + adn.x + s0 * invd;
    float aL1 = asn.y + adn.y + s1 * invd;
    float aL2 = asn.z + adn.z + s2 * invd;
    float aL3 = asn.w + adn.w + s3 * invd;
    aL0 = aL0 >= 0.f ? aL0 : 0.2f * aL0;
    aL1 = aL1 >= 0.f ? aL1 : 0.2f * aL1;
    aL2 = aL2 >= 0.f ? aL2 : 0.2f * aL2;
    aL3 = aL3 >= 0.f ? aL3 : 0.2f * aL3;
    float ws0 = __expf(aL0), ws1 = __expf(aL1), ws2 = __expf(aL2), ws3 = __expf(aL3);
    float wself = qh == 0 ? ws0 : (qh == 1 ? ws1 : (qh == 2 ? ws2 : ws3));
    float dh = qh == 0 ? ds0 + ws0 : (qh == 1 ? ds1 + ws1 : (qh == 2 ? ds2 + ws2 : ds3 + ws3));
    uint4 us = *(const uint4*)&xs1u[(size_t)n * 64 + lr * 4];
    acc[0] += wself * bf_lo(us.x); acc[1] += wself * bf_hi(us.x);
    acc[2] += wself * bf_lo(us.y); acc[3] += wself * bf_hi(us.y);
    acc[4] += wself * bf_lo(us.z); acc[5] += wself * bf_hi(us.z);
    acc[6] += wself * bf_lo(us.w); acc[7] += wself * bf_hi(us.w);
    float inv = 1.f / (dh + 1e-16f);
    int c = lr * 8;
    uint4 ou;
    unsigned* op = (unsigned*)&ou;
#pragma unroll
    for (int k2 = 0; k2 < 4; ++k2) {
        int c0 = c + 2 * k2, c1 = c + 2 * k2 + 1;
        float o0 = acc[2 * k2] * inv + b1[c0];
        float o1 = acc[2 * k2 + 1] * inv + b1[c1];
        float sc0 = g1[c0] * rsqrtf(rv1[c0] + 1e-5f);
        float sc1 = g1[c1] * rsqrtf(rv1[c1] + 1e-5f);
        o0 = (o0 - rm1[c0]) * sc0 + be1[c0];
        o1 = (o1 - rm1[c1]) * sc1 + be1[c1];
        o0 = o0 > 0.f ? o0 : __expf(o0) - 1.f;
        o1 = o1 > 0.f ? o1 : __expf(o1) - 1.f;
        op[k2] = f2bf2(o0, o1);
    }
    *(uint4*)&h1u[(size_t)n * 64 + lr * 4] = ou;
}

// ---------------------------------------------------------------------------
// K8: MFMA GEMM2: xs2[N,40](bf16, stride 64) = h1(bf16) @ W2(bf16,48-pad).
__global__ __launch_bounds__(256) void gemm2_mfma(
    const unsigned* __restrict__ A, const unsigned* __restrict__ w2t,
    unsigned* __restrict__ out) {
    __shared__ unsigned sA[64 * 68];
    __shared__ unsigned sB[48 * 68];
    int t = threadIdx.x;
    int row0 = blockIdx.x * 64;
    for (int i = t; i < 64 * 16; i += 256) {
        int r = i >> 4, q = i & 15;
        int gr = row0 + r;
        uint4 v = (gr < NN) ? *(const uint4*)&A[(size_t)gr * 64 + q * 4]
                            : make_uint4(0u, 0u, 0u, 0u);
        *(uint4*)&sA[r * 68 + q * 4] = v;
    }
    for (int i = t; i < 48 * 16; i += 256) {
        int c = i >> 4, q = i & 15;
        *(uint4*)&sB[c * 68 + q * 4] = *(const uint4*)&w2t[c * 64 + q * 4];
    }
    __syncthreads();
    int wv = t >> 6, lane = t & 63;
    int lr = lane & 15, kgrp = lane >> 4;
    f32x4_t acc[3];
#pragma unroll
    for (int i = 0; i < 3; ++i) acc[i] = (f32x4_t){0.f, 0.f, 0.f, 0.f};
    int arow = wv * 16 + lr;
#pragma unroll
    for (int kt = 0; kt < 4; ++kt) {
        int kw = kt * 16 + kgrp * 4;
        s16x8_t af = *(const s16x8_t*)&sA[arow * 68 + kw];
#pragma unroll
        for (int tc = 0; tc < 3; ++tc) {
            s16x8_t bf = *(const s16x8_t*)&sB[(tc * 16 + lr) * 68 + kw];
            acc[tc] = __builtin_amdgcn_mfma_f32_16x16x32_bf16(af, bf, acc[tc], 0, 0, 0);
        }
    }
    int orow0 = row0 + wv * 16 + kgrp * 4;
#pragma unroll
    for (int tc = 0; tc < 3; ++tc) {
#pragma unroll
        for (int r = 0; r < 4; ++r) {
            float v = acc[tc][r];
            float other = __shfl_xor(v, 1);
            int gr = orow0 + r;
            if (!(lane & 1) && gr < NN && (tc < 2 || lr < 8))
                out[(size_t)gr * 32 + tc * 8 + (lr >> 1)] = f2bf2(v, other);
        }
    }
}

// ---------------------------------------------------------------------------
// K9: per-node attention coefficients layer 2 (from bf16 xs2).
__global__ __launch_bounds__(256) void alpha2_kernel(
    const unsigned* __restrict__ xs2u, const float* __restrict__ asw,
    const float* __restrict__ adw, float* __restrict__ as2, float* __restrict__ ad2) {
    int wid = (blockIdx.x * 256 + threadIdx.x) >> 6;
    if (wid >= NN) return;
    int lane = threadIdx.x & 63;
    float pa = 0.f, pd = 0.f;
    if (lane < 20) {
        unsigned u = xs2u[(size_t)wid * 32 + lane];
        float vx = bf_lo(u), vy = bf_hi(u);
        int c = lane * 2;
        pa = vx * asw[c] + vy * asw[c + 1];
        pd = vx * adw[c] + vy * adw[c + 1];
    }
#pragma unroll
    for (int d = 16; d >= 1; d >>= 1) {
        pa += __shfl_xor(pa, d, 32);
        pd += __shfl_xor(pd, d, 32);
    }
    if (lane == 0) { as2[wid] = pa; ad2[wid] = pd; }
}

// ---------------------------------------------------------------------------
// K10: layer-2 GAT aggregation + bias + BN + log_softmax. LDS-staged weights,
// 3 edges/iteration (20 lanes each).
__global__ __launch_bounds__(256) void gat2_kernel(
    const uint4* __restrict__ epk, const int* __restrict__ off,
    const unsigned* __restrict__ xs2u,
    const float* __restrict__ as2, const float* __restrict__ ad2,
    const float* __restrict__ b2, const float* __restrict__ g2, const float* __restrict__ be2,
    const float* __restrict__ rm2, const float* __restrict__ rv2, float* __restrict__ outp) {
    __shared__ int   lds_s[4][72];
    __shared__ float lds_w[4][72];
    int wid = (blockIdx.x * 256 + threadIdx.x) >> 6;
    if (wid >= NN) return;
    int lane = threadIdx.x & 63;
    int warp = threadIdx.x >> 6;
    int n = wid;
    int e0 = off[n], e1 = off[n + 1];
    int deg = e1 - e0;
    int grp3 = lane / 20;
    int col = lane - grp3 * 20;
    bool act = grp3 < 3;
    if (lane < 8) {
        lds_s[warp][64 + lane] = 0;
        lds_w[warp][64 + lane] = 0.f;
    }
    float adn = ad2[n];
    float asn = as2[n];
    float acc0 = 0.f, acc1 = 0.f, dsum = 0.f, aesum = 0.f;

    for (int base = 0; base < deg; base += 64) {
        int i = base + lane;
        int cn = min(64, deg - base);
        int s = 0;
        float w = 0.f;
        if (i < deg) {
            uint4 ep = epk[e0 + i];
            s = (int)ep.x;
            float ae = __uint_as_float(ep.w);
            float a = as2[s] + adn + ae;
            a = a >= 0.f ? a : 0.2f * a;
            w = __expf(a);
            dsum += w;
            aesum += ae;
        }
        lds_s[warp][lane] = s;
        lds_w[warp][lane] = w;
        __builtin_amdgcn_wave_barrier();
#pragma unroll 2
        for (int j = 0; j < cn; j += 3) {
            int jj = j + (act ? grp3 : 0);
            int sj = lds_s[warp][jj];
            float wj = act ? lds_w[warp][jj] : 0.f;
            unsigned u = xs2u[(size_t)sj * 32 + col];
            acc0 += wj * bf_lo(u);
            acc1 += wj * bf_hi(u);
        }
        __builtin_amdgcn_wave_barrier();
    }
    {
        float p0 = __shfl(acc0, (lane + 20) & 63);
        float p1 = __shfl(acc1, (lane + 20) & 63);
        float q0 = __shfl(acc0, (lane + 40) & 63);
        float q1 = __shfl(acc1, (lane + 40) & 63);
        acc0 += p0 + q0;
        acc1 += p1 + q1;
    }
#pragma unroll
    for (int d = 32; d >= 1; d >>= 1) {
        dsum += __shfl_xor(dsum, d);
        aesum += __shfl_xor(aesum, d);
    }
    float invd = 1.f / fmaxf((float)deg, 1.f);
    float aL = asn + adn + aesum * invd;
    aL = aL >= 0.f ? aL : 0.2f * aL;
    float wself = __expf(aL);
    float denom = dsum + wself;

    float v0 = 0.f, v1 = 0.f;
    if (lane < 20) {
        unsigned u = xs2u[(size_t)n * 32 + lane];
        acc0 += wself * bf_lo(u);
        acc1 += wself * bf_hi(u);
        int c = lane * 2;
        float inv = 1.f / (denom + 1e-16f);
        v0 = acc0 * inv + b2[c];
        v1 = acc1 * inv + b2[c + 1];
        float sc0 = g2[c] * rsqrtf(rv2[c] + 1e-5f);
        float sc1 = g2[c + 1] * rsqrtf(rv2[c + 1] + 1e-5f);
        v0 = (v0 - rm2[c]) * sc0 + be2[c];
        v1 = (v1 - rm2[c + 1]) * sc1 + be2[c + 1];
    }
    float mx = (lane < 20) ? fmaxf(v0, v1) : -3.0e38f;
#pragma unroll
    for (int d = 32; d >= 1; d >>= 1) mx = fmaxf(mx, __shfl_xor(mx, d));
    float ex = (lane < 20) ? __expf(v0 - mx) + __expf(v1 - mx) : 0.f;
#pragma unroll
    for (int d = 32; d >= 1; d >>= 1) ex += __shfl_xor(ex, d);
    if (lane < 20) {
        float ls = __logf(ex);
        *(float2*)&outp[(size_t)n * 40 + lane * 2] = make_float2(v0 - mx - ls, v1 - mx - ls);
    }
}

// ---------------------------------------------------------------------------
extern "C" void kernel_launch(void* const* d_in, const int* in_sizes, int n_in,
                              void* d_out, int out_size, void* d_ws, size_t ws_size,
                              hipStream_t stream) {
    const float* x     = (const float*)d_in[0];
    const int*   ei    = (const int*)d_in[1];
    const float* eattr = (const float*)d_in[2];
    const float* W1    = (const float*)d_in[3];
    const float* as1w  = (const float*)d_in[4];
    const float* ad1w  = (const float*)d_in[5];
    const float* ae1w  = (const float*)d_in[6];
    const float* We1   = (const float*)d_in[7];
    const float* b1    = (const float*)d_in[8];
    const float* W2    = (const float*)d_in[9];
    const float* as2w  = (const float*)d_in[10];
    const float* ad2w  = (const float*)d_in[11];
    const float* ae2w  = (const float*)d_in[12];
    const float* We2   = (const float*)d_in[13];
    const float* b2    = (const float*)d_in[14];
    const float* g1    = (const float*)d_in[15];
    const float* be1   = (const float*)d_in[16];
    const float* rm1   = (const float*)d_in[17];
    const float* rv1   = (const float*)d_in[18];
    const float* g2    = (const float*)d_in[19];
    const float* be2   = (const float*)d_in[20];
    const float* rm2   = (const float*)d_in[21];
    const float* rv2   = (const float*)d_in[22];

    const int* src0 = ei;
    const int* dst0 = ei + NE;

    char* p = (char*)d_ws;
    auto take = [&](size_t nbytes) {
        void* r = (void*)p;
        p += (nbytes + 255) & ~(size_t)255;
        return r;
    };
    float*    wf1    = (float*)take(80);
    float*    wf2    = (float*)take(20);
    unsigned* w1t    = (unsigned*)take((size_t)128 * 64 * 4);
    unsigned* w2t    = (unsigned*)take((size_t)48 * 64 * 4);
    int*      cnt    = (int*)take((size_t)NN * 4);
    int*      off    = (int*)take((size_t)(NN + 1) * 4);
    int*      bsum   = (int*)take((size_t)SCAN_NB * 4);
    int*      cur    = (int*)take((size_t)NN * 4);
    uint4*    epk    = (uint4*)take((size_t)NE * 16);
    float*    as1    = (float*)take((size_t)NN * 16);
    float*    ad1    = (float*)take((size_t)NN * 16);
    float*    as2    = (float*)take((size_t)NN * 4);
    float*    ad2    = (float*)take((size_t)NN * 4);
    unsigned* xs1u   = (unsigned*)take((size_t)NN * 256);  // 64 uints/row
    unsigned* h1u    = (unsigned*)take((size_t)NN * 256);
    unsigned* xs2u   = (unsigned*)take((size_t)NN * 128);  // 32 uints/row

    hipMemsetAsync(cnt, 0, (size_t)NN * 4, stream);
    hipMemsetAsync(cur, 0, (size_t)NN * 4, stream);

    prep_kernel<<<1, 256, 0, stream>>>(We1, ae1w, We2, ae2w, W1, W2, wf1, wf2, w1t, w2t);
    count_kernel<<<(NE + 255) / 256, 256, 0, stream>>>(dst0, cnt);
    scan1_kernel<<<SCAN_NB, 256, 0, stream>>>(cnt, off, bsum);
    scan2_kernel<<<1, 256, 0, stream>>>(bsum);
    scan3_kernel<<<SCAN_NB, 256, 0, stream>>>(off, bsum, cnt);
    fill_fold_kernel<<<(NE + 255) / 256, 256, 0, stream>>>(src0, dst0, eattr, wf1, wf2,
                                                           off, cur, epk);
    gemm1_mfma<<<(NN + 63) / 64, 256, 0, stream>>>(x, w1t, xs1u);
    alpha1_kernel<<<(NN + 3) / 4, 256, 0, stream>>>(xs1u, as1w, ad1w, as1, ad1);
    gat1_kernel<<<NN / 16, 256, 0, stream>>>(epk, off, xs1u, (const float4*)as1,
                                             (const float4*)ad1, b1, g1, be1, rm1, rv1, h1u);
    gemm2_mfma<<<(NN + 63) / 64, 256, 0, stream>>>(h1u, w2t, xs2u);
    alpha2_kernel<<<(NN + 3) / 4, 256, 0, stream>>>(xs2u, as2w, ad2w, as2, ad2);
    gat2_kernel<<<(NN + 3) / 4, 256, 0, stream>>>(epk, off, xs2u, as2, ad2,
                                                  b2, g2, be2, rm2, rv2, (float*)d_out);
}

// Round 8
// 190.645 us; speedup vs baseline: 3.3608x; 1.1548x over previous
//
#include <hip/hip_runtime.h>
#include <hip/hip_bf16.h>

#define NN 50000
#define NE 800000
#define SCAN_NB ((NN + 255) / 256)   // 196 blocks
// IN=128, HID=32, HEADS=4, HC=128, OUT=40, EDIM=5

typedef float f32x4_t __attribute__((ext_vector_type(4)));
typedef short s16x8_t __attribute__((ext_vector_type(8)));

// bf16 pack/unpack helpers (RNE rounding).
__device__ __forceinline__ unsigned f2bf2(float a, float b) {
    unsigned ua = __float_as_uint(a);
    ua = (ua + 0x7fffu + ((ua >> 16) & 1u)) >> 16;
    unsigned ub = __float_as_uint(b);
    ub = (ub + 0x7fffu + ((ub >> 16) & 1u)) >> 16;
    return ua | (ub << 16);
}
__device__ __forceinline__ float bf_lo(unsigned u) { return __uint_as_float(u << 16); }
__device__ __forceinline__ float bf_hi(unsigned u) { return __uint_as_float(u & 0xffff0000u); }

// ---------------------------------------------------------------------------
// K0: prep — fold edge-weight matrices with attention vectors + build
// bf16-transposed weight matrices for the MFMA GEMMs.
__global__ __launch_bounds__(256) void prep_kernel(
    const float* __restrict__ We1, const float* __restrict__ ae1w,
    const float* __restrict__ We2, const float* __restrict__ ae2w,
    const float* __restrict__ W1, const float* __restrict__ W2,
    float* __restrict__ wf1, float* __restrict__ wf2,
    unsigned* __restrict__ w1t, unsigned* __restrict__ w2t) {
    int t = threadIdx.x;
    if (t < 20) {
        int j = t >> 2, h = t & 3;
        float s = 0.f;
        for (int c = 0; c < 32; ++c) s += We1[j * 128 + h * 32 + c] * ae1w[h * 32 + c];
        wf1[j * 4 + h] = s;
    }
    if (t >= 32 && t < 37) {
        int j = t - 32;
        float s = 0.f;
        for (int c = 0; c < 40; ++c) s += We2[j * 40 + c] * ae2w[c];
        wf2[j] = s;
    }
    for (int i = t; i < 128 * 64; i += 256) {
        int c = i >> 6, kp = i & 63;
        w1t[i] = f2bf2(W1[(size_t)(2 * kp) * 128 + c], W1[(size_t)(2 * kp + 1) * 128 + c]);
    }
    for (int i = t; i < 48 * 64; i += 256) {
        int c = i >> 6, kp = i & 63;
        w2t[i] = (c < 40) ? f2bf2(W2[(size_t)(2 * kp) * 40 + c], W2[(size_t)(2 * kp + 1) * 40 + c]) : 0u;
    }
}

// ---------------------------------------------------------------------------
// K1: in-degree count + per-edge rank (slot within dst's CSR range).
// The atomic's return value is the rank — coalesced 4B write, arrival order
// (any permutation within a dst range is valid: segment ops are
// permutation-invariant).
__global__ __launch_bounds__(256) void count_kernel(const int* __restrict__ dst0,
                                                    int* __restrict__ cnt,
                                                    int* __restrict__ rank) {
    int e = blockIdx.x * 256 + threadIdx.x;
    if (e >= NE) return;
    rank[e] = atomicAdd(&cnt[dst0[e]], 1);
}

// ---------------------------------------------------------------------------
// K2a/b/c: two-level exclusive scan.
__global__ __launch_bounds__(256) void scan1_kernel(const int* __restrict__ cnt,
                                                    int* __restrict__ off,
                                                    int* __restrict__ bsum) {
    __shared__ int tmp[256];
    int t = threadIdx.x;
    int g = blockIdx.x * 256 + t;
    int v = (g < NN) ? cnt[g] : 0;
    tmp[t] = v;
    __syncthreads();
#pragma unroll
    for (int d = 1; d < 256; d <<= 1) {
        int u = (t >= d) ? tmp[t - d] : 0;
        __syncthreads();
        tmp[t] += u;
        __syncthreads();
    }
    if (g < NN) off[g] = tmp[t] - v;
    if (t == 255) bsum[blockIdx.x] = tmp[255];
}

__global__ __launch_bounds__(256) void scan2_kernel(int* __restrict__ bsum) {
    __shared__ int tmp[256];
    int t = threadIdx.x;
    int v = (t < SCAN_NB) ? bsum[t] : 0;
    tmp[t] = v;
    __syncthreads();
#pragma unroll
    for (int d = 1; d < 256; d <<= 1) {
        int u = (t >= d) ? tmp[t - d] : 0;
        __syncthreads();
        tmp[t] += u;
        __syncthreads();
    }
    if (t < SCAN_NB) bsum[t] = tmp[t] - v;
}

__global__ __launch_bounds__(256) void scan3_kernel(int* __restrict__ off,
                                                    const int* __restrict__ bsum,
                                                    const int* __restrict__ cnt) {
    int g = blockIdx.x * 256 + threadIdx.x;
    if (g < NN) {
        int o = off[g] + bsum[blockIdx.x];
        off[g] = o;
        if (g == NN - 1) off[NN] = o + cnt[g];
    }
}

// ---------------------------------------------------------------------------
// K3: fill CSR in slot order. Atomic-free: pos = off[dst] + rank (precomputed).
// 4 edges/thread (block-strided) for 4 independent latency chains; the
// scatter store is posted (no return dependency).
__global__ __launch_bounds__(256) void fill_fold_kernel(
    const int* __restrict__ src0, const int* __restrict__ dst0,
    const float* __restrict__ eattr, const float* __restrict__ wf1,
    const float* __restrict__ wf2, const int* __restrict__ off,
    const int* __restrict__ rank, uint4* __restrict__ epk) {
    int base = blockIdx.x * 1024 + threadIdx.x;
#pragma unroll
    for (int k = 0; k < 4; ++k) {
        int e = base + k * 256;
        if (e >= NE) continue;
        float a[5];
#pragma unroll
        for (int j = 0; j < 5; ++j) a[j] = eattr[(size_t)e * 5 + j];
        float o[4];
#pragma unroll
        for (int h = 0; h < 4; ++h) {
            float s = 0.f;
#pragma unroll
            for (int j = 0; j < 5; ++j) s += a[j] * wf1[j * 4 + h];
            o[h] = s;
        }
        float s2 = 0.f;
#pragma unroll
        for (int j = 0; j < 5; ++j) s2 += a[j] * wf2[j];
        int pos = off[dst0[e]] + rank[e];
        epk[pos] = make_uint4((unsigned)src0[e], f2bf2(o[0], o[1]), f2bf2(o[2], o[3]),
                              __float_as_uint(s2));
    }
}

// ---------------------------------------------------------------------------
// K5: MFMA GEMM1: xs1[N,128](bf16) = x[N,128] @ W1[128,128].
__global__ __launch_bounds__(256) void gemm1_mfma(
    const float* __restrict__ A, const unsigned* __restrict__ w1t,
    unsigned* __restrict__ out) {
    __shared__ unsigned sA[64 * 68];
    __shared__ unsigned sB[128 * 68];
    int t = threadIdx.x;
    int row0 = blockIdx.x * 64;
    for (int i = t; i < 64 * 32; i += 256) {
        int r = i >> 5, q = i & 31;
        int gr = row0 + r;
        float4 v = (gr < NN) ? *(const float4*)&A[(size_t)gr * 128 + q * 4]
                             : make_float4(0.f, 0.f, 0.f, 0.f);
        sA[r * 68 + q * 2]     = f2bf2(v.x, v.y);
        sA[r * 68 + q * 2 + 1] = f2bf2(v.z, v.w);
    }
    for (int i = t; i < 128 * 16; i += 256) {
        int c = i >> 4, q = i & 15;
        *(uint4*)&sB[c * 68 + q * 4] = *(const uint4*)&w1t[c * 64 + q * 4];
    }
    __syncthreads();
    int wv = t >> 6, lane = t & 63;
    int lr = lane & 15, kgrp = lane >> 4;
    f32x4_t acc[8];
#pragma unroll
    for (int i = 0; i < 8; ++i) acc[i] = (f32x4_t){0.f, 0.f, 0.f, 0.f};
    int arow = wv * 16 + lr;
#pragma unroll
    for (int kt = 0; kt < 4; ++kt) {
        int kw = kt * 16 + kgrp * 4;
        s16x8_t af = *(const s16x8_t*)&sA[arow * 68 + kw];
#pragma unroll
        for (int tc = 0; tc < 8; ++tc) {
            s16x8_t bf = *(const s16x8_t*)&sB[(tc * 16 + lr) * 68 + kw];
            acc[tc] = __builtin_amdgcn_mfma_f32_16x16x32_bf16(af, bf, acc[tc], 0, 0, 0);
        }
    }
    int orow0 = row0 + wv * 16 + kgrp * 4;
#pragma unroll
    for (int tc = 0; tc < 8; ++tc) {
#pragma unroll
        for (int r = 0; r < 4; ++r) {
            float v = acc[tc][r];
            float other = __shfl_xor(v, 1);
            int gr = orow0 + r;
            if (!(lane & 1) && gr < NN)
                out[(size_t)gr * 64 + tc * 8 + (lr >> 1)] = f2bf2(v, other);
        }
    }
}

// ---------------------------------------------------------------------------
// K6: per-node attention coefficients for layer 1 (from bf16 xs1).
__global__ __launch_bounds__(256) void alpha1_kernel(
    const unsigned* __restrict__ xs1u, const float* __restrict__ asw,
    const float* __restrict__ adw, float* __restrict__ as1, float* __restrict__ ad1) {
    int wid = (blockIdx.x * 256 + threadIdx.x) >> 6;
    if (wid >= NN) return;
    int lane = threadIdx.x & 63;
    int c = lane * 2;
    unsigned u = xs1u[(size_t)wid * 64 + lane];
    float vx = bf_lo(u), vy = bf_hi(u);
    float pa = vx * asw[c] + vy * asw[c + 1];
    float pd = vx * adw[c] + vy * adw[c + 1];
#pragma unroll
    for (int d = 8; d >= 1; d >>= 1) {
        pa += __shfl_xor(pa, d, 16);
        pd += __shfl_xor(pd, d, 16);
    }
    if ((lane & 15) == 0) {
        as1[wid * 4 + (lane >> 4)] = pa;
        ad1[wid * 4 + (lane >> 4)] = pd;
    }
}

// ---------------------------------------------------------------------------
// K7: layer-1 GAT aggregation. 4 nodes per wave, 16 lanes per node.
__global__ __launch_bounds__(256) void gat1_kernel(
    const uint4* __restrict__ epk, const int* __restrict__ off,
    const unsigned* __restrict__ xs1u,
    const float4* __restrict__ as1, const float4* __restrict__ ad1,
    const float* __restrict__ b1, const float* __restrict__ g1, const float* __restrict__ be1,
    const float* __restrict__ rm1, const float* __restrict__ rv1, unsigned* __restrict__ h1u) {
    __shared__ int   lds_s[4][4][16];
    __shared__ float lds_w[4][4][16][4];
    int wave = threadIdx.x >> 6;
    int lane = threadIdx.x & 63;
    int g = lane >> 4;
    int lr = lane & 15;
    int qh = lr >> 2;
    int n = blockIdx.x * 16 + wave * 4 + g;
    int e0 = off[n];
    int deg = off[n + 1] - e0;
    float4 adn = ad1[n];
    float4 asn = as1[n];
    float acc[8];
#pragma unroll
    for (int k = 0; k < 8; ++k) acc[k] = 0.f;
    float ds0 = 0.f, ds1 = 0.f, ds2 = 0.f, ds3 = 0.f;
    float s0 = 0.f, s1 = 0.f, s2 = 0.f, s3 = 0.f;
    int mc = (deg + 15) >> 4;
    mc = max(mc, __shfl_xor(mc, 16));
    mc = max(mc, __shfl_xor(mc, 32));

    for (int ch = 0; ch < mc; ++ch) {
        int i = ch * 16 + lr;
        int s = 0;
        float w0 = 0.f, w1 = 0.f, w2 = 0.f, w3 = 0.f;
        if (i < deg) {
            uint4 ep = epk[e0 + i];
            s = (int)ep.x;
            float ax = bf_lo(ep.y), ay = bf_hi(ep.y);
            float az = bf_lo(ep.z), aw = bf_hi(ep.z);
            float4 av = as1[s];
            float a0 = av.x + adn.x + ax;
            float a1 = av.y + adn.y + ay;
            float a2 = av.z + adn.z + az;
            float a3 = av.w + adn.w + aw;
            a0 = a0 >= 0.f ? a0 : 0.2f * a0;
            a1 = a1 >= 0.f ? a1 : 0.2f * a1;
            a2 = a2 >= 0.f ? a2 : 0.2f * a2;
            a3 = a3 >= 0.f ? a3 : 0.2f * a3;
            w0 = __expf(a0); w1 = __expf(a1); w2 = __expf(a2); w3 = __expf(a3);
            ds0 += w0; ds1 += w1; ds2 += w2; ds3 += w3;
            s0 += ax; s1 += ay; s2 += az; s3 += aw;
        }
        lds_s[wave][g][lr] = s;
        *(float4*)&lds_w[wave][g][lr][0] = make_float4(w0, w1, w2, w3);
        __builtin_amdgcn_wave_barrier();
        int cn = min(16, deg - ch * 16);
        for (int j = 0; j < cn; ++j) {
            int sj = lds_s[wave][g][j];
            float wj = lds_w[wave][g][j][qh];
            uint4 u = *(const uint4*)&xs1u[(size_t)sj * 64 + lr * 4];
            acc[0] += wj * bf_lo(u.x); acc[1] += wj * bf_hi(u.x);
            acc[2] += wj * bf_lo(u.y); acc[3] += wj * bf_hi(u.y);
            acc[4] += wj * bf_lo(u.z); acc[5] += wj * bf_hi(u.z);
            acc[6] += wj * bf_lo(u.w); acc[7] += wj * bf_hi(u.w);
        }
        __builtin_amdgcn_wave_barrier();
    }
#pragma unroll
    for (int d = 8; d >= 1; d >>= 1) {
        ds0 += __shfl_xor(ds0, d, 16); ds1 += __shfl_xor(ds1, d, 16);
        ds2 += __shfl_xor(ds2, d, 16); ds3 += __shfl_xor(ds3, d, 16);
        s0 += __shfl_xor(s0, d, 16);   s1 += __shfl_xor(s1, d, 16);
        s2 += __shfl_xor(s2, d, 16);   s3 += __shfl_xor(s3, d, 16);
    }
    float invd = 1.f / fmaxf((float)deg, 1.f);
    float aL0 = asn.x + adn.x + s0 * invd;
    float aL1 = asn.y + adn.y + s1 * invd;
    float aL2 = asn.z + adn.z + s2 * invd;
    float aL3 = asn.w + adn.w + s3 * invd;
    aL0 = aL0 >= 0.f ? aL0 : 0.2f * aL0;
    aL1 = aL1 >= 0.f ? aL1 : 0.2f * aL1;
    aL2 = aL2 >= 0.f ? aL2 : 0.2f * aL2;
    aL3 = aL3 >= 0.f ? aL3 : 0.2f * aL3;
    float ws0 = __expf(aL0), ws1 = __expf(aL1), ws2 = __expf(aL2), ws3 = __expf(aL3);
    float wself = qh == 0 ? ws0 : (qh == 1 ? ws1 : (qh == 2 ? ws2 : ws3));
    float dh = qh == 0 ? ds0 + ws0 : (qh == 1 ? ds1 + ws1 : (qh == 2 ? ds2 + ws2 : ds3 + ws3));
    uint4 us = *(const uint4*)&xs1u[(size_t)n * 64 + lr * 4];
    acc[0] += wself * bf_lo(us.x); acc[1] += wself * bf_hi(us.x);
    acc[2] += wself * bf_lo(us.y); acc[3] += wself * bf_hi(us.y);
    acc[4] += wself * bf_lo(us.z); acc[5] += wself * bf_hi(us.z);
    acc[6] += wself * bf_lo(us.w); acc[7] += wself * bf_hi(us.w);
    float inv = 1.f / (dh + 1e-16f);
    int c = lr * 8;
    uint4 ou;
    unsigned* op = (unsigned*)&ou;
#pragma unroll
    for (int k2 = 0; k2 < 4; ++k2) {
        int c0 = c + 2 * k2, c1 = c + 2 * k2 + 1;
        float o0 = acc[2 * k2] * inv + b1[c0];
        float o1 = acc[2 * k2 + 1] * inv + b1[c1];
        float sc0 = g1[c0] * rsqrtf(rv1[c0] + 1e-5f);
        float sc1 = g1[c1] * rsqrtf(rv1[c1] + 1e-5f);
        o0 = (o0 - rm1[c0]) * sc0 + be1[c0];
        o1 = (o1 - rm1[c1]) * sc1 + be1[c1];
        o0 = o0 > 0.f ? o0 : __expf(o0) - 1.f;
        o1 = o1 > 0.f ? o1 : __expf(o1) - 1.f;
        op[k2] = f2bf2(o0, o1);
    }
    *(uint4*)&h1u[(size_t)n * 64 + lr * 4] = ou;
}

// ---------------------------------------------------------------------------
// K8: MFMA GEMM2: xs2[N,40](bf16, stride 64) = h1(bf16) @ W2(bf16,48-pad).
__global__ __launch_bounds__(256) void gemm2_mfma(
    const unsigned* __restrict__ A, const unsigned* __restrict__ w2t,
    unsigned* __restrict__ out) {
    __shared__ unsigned sA[64 * 68];
    __shared__ unsigned sB[48 * 68];
    int t = threadIdx.x;
    int row0 = blockIdx.x * 64;
    for (int i = t; i < 64 * 16; i += 256) {
        int r = i >> 4, q = i & 15;
        int gr = row0 + r;
        uint4 v = (gr < NN) ? *(const uint4*)&A[(size_t)gr * 64 + q * 4]
                            : make_uint4(0u, 0u, 0u, 0u);
        *(uint4*)&sA[r * 68 + q * 4] = v;
    }
    for (int i = t; i < 48 * 16; i += 256) {
        int c = i >> 4, q = i & 15;
        *(uint4*)&sB[c * 68 + q * 4] = *(const uint4*)&w2t[c * 64 + q * 4];
    }
    __syncthreads();
    int wv = t >> 6, lane = t & 63;
    int lr = lane & 15, kgrp = lane >> 4;
    f32x4_t acc[3];
#pragma unroll
    for (int i = 0; i < 3; ++i) acc[i] = (f32x4_t){0.f, 0.f, 0.f, 0.f};
    int arow = wv * 16 + lr;
#pragma unroll
    for (int kt = 0; kt < 4; ++kt) {
        int kw = kt * 16 + kgrp * 4;
        s16x8_t af = *(const s16x8_t*)&sA[arow * 68 + kw];
#pragma unroll
        for (int tc = 0; tc < 3; ++tc) {
            s16x8_t bf = *(const s16x8_t*)&sB[(tc * 16 + lr) * 68 + kw];
            acc[tc] = __builtin_amdgcn_mfma_f32_16x16x32_bf16(af, bf, acc[tc], 0, 0, 0);
        }
    }
    int orow0 = row0 + wv * 16 + kgrp * 4;
#pragma unroll
    for (int tc = 0; tc < 3; ++tc) {
#pragma unroll
        for (int r = 0; r < 4; ++r) {
            float v = acc[tc][r];
            float other = __shfl_xor(v, 1);
            int gr = orow0 + r;
            if (!(lane & 1) && gr < NN && (tc < 2 || lr < 8))
                out[(size_t)gr * 32 + tc * 8 + (lr >> 1)] = f2bf2(v, other);
        }
    }
}

// ---------------------------------------------------------------------------
// K9: per-node attention coefficients layer 2 (from bf16 xs2).
__global__ __launch_bounds__(256) void alpha2_kernel(
    const unsigned* __restrict__ xs2u, const float* __restrict__ asw,
    const float* __restrict__ adw, float* __restrict__ as2, float* __restrict__ ad2) {
    int wid = (blockIdx.x * 256 + threadIdx.x) >> 6;
    if (wid >= NN) return;
    int lane = threadIdx.x & 63;
    float pa = 0.f, pd = 0.f;
    if (lane < 20) {
        unsigned u = xs2u[(size_t)wid * 32 + lane];
        float vx = bf_lo(u), vy = bf_hi(u);
        int c = lane * 2;
        pa = vx * asw[c] + vy * asw[c + 1];
        pd = vx * adw[c] + vy * adw[c + 1];
    }
#pragma unroll
    for (int d = 16; d >= 1; d >>= 1) {
        pa += __shfl_xor(pa, d, 32);
        pd += __shfl_xor(pd, d, 32);
    }
    if (lane == 0) { as2[wid] = pa; ad2[wid] = pd; }
}

// ---------------------------------------------------------------------------
// K10: layer-2 GAT aggregation + bias + BN + log_softmax.
__global__ __launch_bounds__(256) void gat2_kernel(
    const uint4* __restrict__ epk, const int* __restrict__ off,
    const unsigned* __restrict__ xs2u,
    const float* __restrict__ as2, const float* __restrict__ ad2,
    const float* __restrict__ b2, const float* __restrict__ g2, const float* __restrict__ be2,
    const float* __restrict__ rm2, const float* __restrict__ rv2, float* __restrict__ outp) {
    __shared__ int   lds_s[4][72];
    __shared__ float lds_w[4][72];
    int wid = (blockIdx.x * 256 + threadIdx.x) >> 6;
    if (wid >= NN) return;
    int lane = threadIdx.x & 63;
    int warp = threadIdx.x >> 6;
    int n = wid;
    int e0 = off[n], e1 = off[n + 1];
    int deg = e1 - e0;
    int grp3 = lane / 20;
    int col = lane - grp3 * 20;
    bool act = grp3 < 3;
    if (lane < 8) {
        lds_s[warp][64 + lane] = 0;
        lds_w[warp][64 + lane] = 0.f;
    }
    float adn = ad2[n];
    float asn = as2[n];
    float acc0 = 0.f, acc1 = 0.f, dsum = 0.f, aesum = 0.f;

    for (int base = 0; base < deg; base += 64) {
        int i = base + lane;
        int cn = min(64, deg - base);
        int s = 0;
        float w = 0.f;
        if (i < deg) {
            uint4 ep = epk[e0 + i];
            s = (int)ep.x;
            float ae = __uint_as_float(ep.w);
            float a = as2[s] + adn + ae;
            a = a >= 0.f ? a : 0.2f * a;
            w = __expf(a);
            dsum += w;
            aesum += ae;
        }
        lds_s[warp][lane] = s;
        lds_w[warp][lane] = w;
        __builtin_amdgcn_wave_barrier();
#pragma unroll 2
        for (int j = 0; j < cn; j += 3) {
            int jj = j + (act ? grp3 : 0);
            int sj = lds_s[warp][jj];
            float wj = act ? lds_w[warp][jj] : 0.f;
            unsigned u = xs2u[(size_t)sj * 32 + col];
            acc0 += wj * bf_lo(u);
            acc1 += wj * bf_hi(u);
        }
        __builtin_amdgcn_wave_barrier();
    }
    {
        float p0 = __shfl(acc0, (lane + 20) & 63);
        float p1 = __shfl(acc1, (lane + 20) & 63);
        float q0 = __shfl(acc0, (lane + 40) & 63);
        float q1 = __shfl(acc1, (lane + 40) & 63);
        acc0 += p0 + q0;
        acc1 += p1 + q1;
    }
#pragma unroll
    for (int d = 32; d >= 1; d >>= 1) {
        dsum += __shfl_xor(dsum, d);
        aesum += __shfl_xor(aesum, d);
    }
    float invd = 1.f / fmaxf((float)deg, 1.f);
    float aL = asn + adn + aesum * invd;
    aL = aL >= 0.f ? aL : 0.2f * aL;
    float wself = __expf(aL);
    float denom = dsum + wself;

    float v0 = 0.f, v1 = 0.f;
    if (lane < 20) {
        unsigned u = xs2u[(size_t)n * 32 + lane];
        acc0 += wself * bf_lo(u);
        acc1 += wself * bf_hi(u);
        int c = lane * 2;
        float inv = 1.f / (denom + 1e-16f);
        v0 = acc0 * inv + b2[c];
        v1 = acc1 * inv + b2[c + 1];
        float sc0 = g2[c] * rsqrtf(rv2[c] + 1e-5f);
        float sc1 = g2[c + 1] * rsqrtf(rv2[c + 1] + 1e-5f);
        v0 = (v0 - rm2[c]) * sc0 + be2[c];
        v1 = (v1 - rm2[c + 1]) * sc1 + be2[c + 1];
    }
    float mx = (lane < 20) ? fmaxf(v0, v1) : -3.0e38f;
#pragma unroll
    for (int d = 32; d >= 1; d >>= 1) mx = fmaxf(mx, __shfl_xor(mx, d));
    float ex = (lane < 20) ? __expf(v0 - mx) + __expf(v1 - mx) : 0.f;
#pragma unroll
    for (int d = 32; d >= 1; d >>= 1) ex += __shfl_xor(ex, d);
    if (lane < 20) {
        float ls = __logf(ex);
        *(float2*)&outp[(size_t)n * 40 + lane * 2] = make_float2(v0 - mx - ls, v1 - mx - ls);
    }
}

// ---------------------------------------------------------------------------
extern "C" void kernel_launch(void* const* d_in, const int* in_sizes, int n_in,
                              void* d_out, int out_size, void* d_ws, size_t ws_size,
                              hipStream_t stream) {
    const float* x     = (const float*)d_in[0];
    const int*   ei    = (const int*)d_in[1];
    const float* eattr = (const float*)d_in[2];
    const float* W1    = (const float*)d_in[3];
    const float* as1w  = (const float*)d_in[4];
    const float* ad1w  = (const float*)d_in[5];
    const float* ae1w  = (const float*)d_in[6];
    const float* We1   = (const float*)d_in[7];
    const float* b1    = (const float*)d_in[8];
    const float* W2    = (const float*)d_in[9];
    const float* as2w  = (const float*)d_in[10];
    const float* ad2w  = (const float*)d_in[11];
    const float* ae2w  = (const float*)d_in[12];
    const float* We2   = (const float*)d_in[13];
    const float* b2    = (const float*)d_in[14];
    const float* g1    = (const float*)d_in[15];
    const float* be1   = (const float*)d_in[16];
    const float* rm1   = (const float*)d_in[17];
    const float* rv1   = (const float*)d_in[18];
    const float* g2    = (const float*)d_in[19];
    const float* be2   = (const float*)d_in[20];
    const float* rm2   = (const float*)d_in[21];
    const float* rv2   = (const float*)d_in[22];

    const int* src0 = ei;
    const int* dst0 = ei + NE;

    char* p = (char*)d_ws;
    auto take = [&](size_t nbytes) {
        void* r = (void*)p;
        p += (nbytes + 255) & ~(size_t)255;
        return r;
    };
    float*    wf1    = (float*)take(80);
    float*    wf2    = (float*)take(20);
    unsigned* w1t    = (unsigned*)take((size_t)128 * 64 * 4);
    unsigned* w2t    = (unsigned*)take((size_t)48 * 64 * 4);
    int*      cnt    = (int*)take((size_t)NN * 4);
    int*      off    = (int*)take((size_t)(NN + 1) * 4);
    int*      bsum   = (int*)take((size_t)SCAN_NB * 4);
    int*      rank   = (int*)take((size_t)NE * 4);
    uint4*    epk    = (uint4*)take((size_t)NE * 16);
    float*    as1    = (float*)take((size_t)NN * 16);
    float*    ad1    = (float*)take((size_t)NN * 16);
    float*    as2    = (float*)take((size_t)NN * 4);
    float*    ad2    = (float*)take((size_t)NN * 4);
    unsigned* xs1u   = (unsigned*)take((size_t)NN * 256);  // 64 uints/row
    unsigned* h1u    = (unsigned*)take((size_t)NN * 256);
    unsigned* xs2u   = (unsigned*)take((size_t)NN * 128);  // 32 uints/row

    hipMemsetAsync(cnt, 0, (size_t)NN * 4, stream);

    prep_kernel<<<1, 256, 0, stream>>>(We1, ae1w, We2, ae2w, W1, W2, wf1, wf2, w1t, w2t);
    count_kernel<<<(NE + 255) / 256, 256, 0, stream>>>(dst0, cnt, rank);
    scan1_kernel<<<SCAN_NB, 256, 0, stream>>>(cnt, off, bsum);
    scan2_kernel<<<1, 256, 0, stream>>>(bsum);
    scan3_kernel<<<SCAN_NB, 256, 0, stream>>>(off, bsum, cnt);
    fill_fold_kernel<<<(NE + 1023) / 1024, 256, 0, stream>>>(src0, dst0, eattr, wf1, wf2,
                                                             off, rank, epk);
    gemm1_mfma<<<(NN + 63) / 64, 256, 0, stream>>>(x, w1t, xs1u);
    alpha1_kernel<<<(NN + 3) / 4, 256, 0, stream>>>(xs1u, as1w, ad1w, as1, ad1);
    gat1_kernel<<<NN / 16, 256, 0, stream>>>(epk, off, xs1u, (const float4*)as1,
                                             (const float4*)ad1, b1, g1, be1, rm1, rv1, h1u);
    gemm2_mfma<<<(NN + 63) / 64, 256, 0, stream>>>(h1u, w2t, xs2u);
    alpha2_kernel<<<(NN + 3) / 4, 256, 0, stream>>>(xs2u, as2w, ad2w, as2, ad2);
    gat2_kernel<<<(NN + 3) / 4, 256, 0, stream>>>(epk, off, xs2u, as2, ad2,
                                                  b2, g2, be2, rm2, rv2, (float*)d_out);
}

// Round 9
// 184.384 us; speedup vs baseline: 3.4749x; 1.0340x over previous
//
#include <hip/hip_runtime.h>
#include <hip/hip_bf16.h>

#define NN 50000
#define NE 800000
#define SCAN_NB ((NN + 255) / 256)   // 196 blocks
// IN=128, HID=32, HEADS=4, HC=128, OUT=40, EDIM=5

typedef float f32x4_t __attribute__((ext_vector_type(4)));
typedef float f32x2_t __attribute__((ext_vector_type(2)));
typedef short s16x8_t __attribute__((ext_vector_type(8)));

// bf16 pack/unpack helpers (RNE rounding).
__device__ __forceinline__ unsigned f2bf2(float a, float b) {
    unsigned ua = __float_as_uint(a);
    ua = (ua + 0x7fffu + ((ua >> 16) & 1u)) >> 16;
    unsigned ub = __float_as_uint(b);
    ub = (ub + 0x7fffu + ((ub >> 16) & 1u)) >> 16;
    return ua | (ub << 16);
}
__device__ __forceinline__ float bf_lo(unsigned u) { return __uint_as_float(u << 16); }
__device__ __forceinline__ float bf_hi(unsigned u) { return __uint_as_float(u & 0xffff0000u); }
__device__ __forceinline__ f32x2_t bfpair(unsigned u) {
    return (f32x2_t){__uint_as_float(u << 16), __uint_as_float(u & 0xffff0000u)};
}

// ---------------------------------------------------------------------------
// K0: prep — fold edge-weight matrices with attention vectors + build
// bf16-transposed weight matrices for the MFMA GEMMs.
__global__ __launch_bounds__(256) void prep_kernel(
    const float* __restrict__ We1, const float* __restrict__ ae1w,
    const float* __restrict__ We2, const float* __restrict__ ae2w,
    const float* __restrict__ W1, const float* __restrict__ W2,
    float* __restrict__ wf1, float* __restrict__ wf2,
    unsigned* __restrict__ w1t, unsigned* __restrict__ w2t) {
    int t = threadIdx.x;
    if (t < 20) {
        int j = t >> 2, h = t & 3;
        float s = 0.f;
        for (int c = 0; c < 32; ++c) s += We1[j * 128 + h * 32 + c] * ae1w[h * 32 + c];
        wf1[j * 4 + h] = s;
    }
    if (t >= 32 && t < 37) {
        int j = t - 32;
        float s = 0.f;
        for (int c = 0; c < 40; ++c) s += We2[j * 40 + c] * ae2w[c];
        wf2[j] = s;
    }
    for (int i = t; i < 128 * 64; i += 256) {
        int c = i >> 6, kp = i & 63;
        w1t[i] = f2bf2(W1[(size_t)(2 * kp) * 128 + c], W1[(size_t)(2 * kp + 1) * 128 + c]);
    }
    for (int i = t; i < 48 * 64; i += 256) {
        int c = i >> 6, kp = i & 63;
        w2t[i] = (c < 40) ? f2bf2(W2[(size_t)(2 * kp) * 40 + c], W2[(size_t)(2 * kp + 1) * 40 + c]) : 0u;
    }
}

// ---------------------------------------------------------------------------
// K1: in-degree count + per-edge rank.
__global__ __launch_bounds__(256) void count_kernel(const int* __restrict__ dst0,
                                                    int* __restrict__ cnt,
                                                    int* __restrict__ rank) {
    int e = blockIdx.x * 256 + threadIdx.x;
    if (e >= NE) return;
    rank[e] = atomicAdd(&cnt[dst0[e]], 1);
}

// ---------------------------------------------------------------------------
// K2a/b/c: two-level exclusive scan.
__global__ __launch_bounds__(256) void scan1_kernel(const int* __restrict__ cnt,
                                                    int* __restrict__ off,
                                                    int* __restrict__ bsum) {
    __shared__ int tmp[256];
    int t = threadIdx.x;
    int g = blockIdx.x * 256 + t;
    int v = (g < NN) ? cnt[g] : 0;
    tmp[t] = v;
    __syncthreads();
#pragma unroll
    for (int d = 1; d < 256; d <<= 1) {
        int u = (t >= d) ? tmp[t - d] : 0;
        __syncthreads();
        tmp[t] += u;
        __syncthreads();
    }
    if (g < NN) off[g] = tmp[t] - v;
    if (t == 255) bsum[blockIdx.x] = tmp[255];
}

__global__ __launch_bounds__(256) void scan2_kernel(int* __restrict__ bsum) {
    __shared__ int tmp[256];
    int t = threadIdx.x;
    int v = (t < SCAN_NB) ? bsum[t] : 0;
    tmp[t] = v;
    __syncthreads();
#pragma unroll
    for (int d = 1; d < 256; d <<= 1) {
        int u = (t >= d) ? tmp[t - d] : 0;
        __syncthreads();
        tmp[t] += u;
        __syncthreads();
    }
    if (t < SCAN_NB) bsum[t] = tmp[t] - v;
}

__global__ __launch_bounds__(256) void scan3_kernel(int* __restrict__ off,
                                                    const int* __restrict__ bsum,
                                                    const int* __restrict__ cnt) {
    int g = blockIdx.x * 256 + threadIdx.x;
    if (g < NN) {
        int o = off[g] + bsum[blockIdx.x];
        off[g] = o;
        if (g == NN - 1) off[NN] = o + cnt[g];
    }
}

// ---------------------------------------------------------------------------
// K3: fill CSR in slot order, atomic-free (pos = off[dst] + rank).
__global__ __launch_bounds__(256) void fill_fold_kernel(
    const int* __restrict__ src0, const int* __restrict__ dst0,
    const float* __restrict__ eattr, const float* __restrict__ wf1,
    const float* __restrict__ wf2, const int* __restrict__ off,
    const int* __restrict__ rank, uint4* __restrict__ epk) {
    int base = blockIdx.x * 1024 + threadIdx.x;
#pragma unroll
    for (int k = 0; k < 4; ++k) {
        int e = base + k * 256;
        if (e >= NE) continue;
        float a[5];
#pragma unroll
        for (int j = 0; j < 5; ++j) a[j] = eattr[(size_t)e * 5 + j];
        float o[4];
#pragma unroll
        for (int h = 0; h < 4; ++h) {
            float s = 0.f;
#pragma unroll
            for (int j = 0; j < 5; ++j) s += a[j] * wf1[j * 4 + h];
            o[h] = s;
        }
        float s2 = 0.f;
#pragma unroll
        for (int j = 0; j < 5; ++j) s2 += a[j] * wf2[j];
        int pos = off[dst0[e]] + rank[e];
        epk[pos] = make_uint4((unsigned)src0[e], f2bf2(o[0], o[1]), f2bf2(o[2], o[3]),
                              __float_as_uint(s2));
    }
}

// ---------------------------------------------------------------------------
// K5: MFMA GEMM1: xs1[N,128](bf16) = x[N,128] @ W1[128,128].
__global__ __launch_bounds__(256) void gemm1_mfma(
    const float* __restrict__ A, const unsigned* __restrict__ w1t,
    unsigned* __restrict__ out) {
    __shared__ unsigned sA[64 * 68];
    __shared__ unsigned sB[128 * 68];
    int t = threadIdx.x;
    int row0 = blockIdx.x * 64;
    for (int i = t; i < 64 * 32; i += 256) {
        int r = i >> 5, q = i & 31;
        int gr = row0 + r;
        float4 v = (gr < NN) ? *(const float4*)&A[(size_t)gr * 128 + q * 4]
                             : make_float4(0.f, 0.f, 0.f, 0.f);
        sA[r * 68 + q * 2]     = f2bf2(v.x, v.y);
        sA[r * 68 + q * 2 + 1] = f2bf2(v.z, v.w);
    }
    for (int i = t; i < 128 * 16; i += 256) {
        int c = i >> 4, q = i & 15;
        *(uint4*)&sB[c * 68 + q * 4] = *(const uint4*)&w1t[c * 64 + q * 4];
    }
    __syncthreads();
    int wv = t >> 6, lane = t & 63;
    int lr = lane & 15, kgrp = lane >> 4;
    f32x4_t acc[8];
#pragma unroll
    for (int i = 0; i < 8; ++i) acc[i] = (f32x4_t){0.f, 0.f, 0.f, 0.f};
    int arow = wv * 16 + lr;
#pragma unroll
    for (int kt = 0; kt < 4; ++kt) {
        int kw = kt * 16 + kgrp * 4;
        s16x8_t af = *(const s16x8_t*)&sA[arow * 68 + kw];
#pragma unroll
        for (int tc = 0; tc < 8; ++tc) {
            s16x8_t bf = *(const s16x8_t*)&sB[(tc * 16 + lr) * 68 + kw];
            acc[tc] = __builtin_amdgcn_mfma_f32_16x16x32_bf16(af, bf, acc[tc], 0, 0, 0);
        }
    }
    int orow0 = row0 + wv * 16 + kgrp * 4;
#pragma unroll
    for (int tc = 0; tc < 8; ++tc) {
#pragma unroll
        for (int r = 0; r < 4; ++r) {
            float v = acc[tc][r];
            float other = __shfl_xor(v, 1);
            int gr = orow0 + r;
            if (!(lane & 1) && gr < NN)
                out[(size_t)gr * 64 + tc * 8 + (lr >> 1)] = f2bf2(v, other);
        }
    }
}

// ---------------------------------------------------------------------------
// K6: per-node attention coefficients for layer 1 (from bf16 xs1).
__global__ __launch_bounds__(256) void alpha1_kernel(
    const unsigned* __restrict__ xs1u, const float* __restrict__ asw,
    const float* __restrict__ adw, float* __restrict__ as1, float* __restrict__ ad1) {
    int wid = (blockIdx.x * 256 + threadIdx.x) >> 6;
    if (wid >= NN) return;
    int lane = threadIdx.x & 63;
    int c = lane * 2;
    unsigned u = xs1u[(size_t)wid * 64 + lane];
    float vx = bf_lo(u), vy = bf_hi(u);
    float pa = vx * asw[c] + vy * asw[c + 1];
    float pd = vx * adw[c] + vy * adw[c + 1];
#pragma unroll
    for (int d = 8; d >= 1; d >>= 1) {
        pa += __shfl_xor(pa, d, 16);
        pd += __shfl_xor(pd, d, 16);
    }
    if ((lane & 15) == 0) {
        as1[wid * 4 + (lane >> 4)] = pa;
        ad1[wid * 4 + (lane >> 4)] = pd;
    }
}

// ---------------------------------------------------------------------------
// K7: layer-1 GAT aggregation. 4 nodes/wave, 16 lanes/node. Gather phase
// unrolled 4 edges/iteration via zero-padded round-up (pad slots have w=0,
// s=0 -> harmless row-0 loads); packed f32x2 accumulate (v_pk_fma_f32).
__global__ __launch_bounds__(256) void gat1_kernel(
    const uint4* __restrict__ epk, const int* __restrict__ off,
    const unsigned* __restrict__ xs1u,
    const float4* __restrict__ as1, const float4* __restrict__ ad1,
    const float* __restrict__ b1, const float* __restrict__ g1, const float* __restrict__ be1,
    const float* __restrict__ rm1, const float* __restrict__ rv1, unsigned* __restrict__ h1u) {
    __shared__ int   lds_s[4][4][16];
    __shared__ float lds_w[4][4][16][4];
    int wave = threadIdx.x >> 6;
    int lane = threadIdx.x & 63;
    int g = lane >> 4;
    int lr = lane & 15;
    int qh = lr >> 2;
    int n = blockIdx.x * 16 + wave * 4 + g;
    int e0 = off[n];
    int deg = off[n + 1] - e0;
    float4 adn = ad1[n];
    float4 asn = as1[n];
    f32x2_t acc2[4];
#pragma unroll
    for (int k = 0; k < 4; ++k) acc2[k] = (f32x2_t){0.f, 0.f};
    float ds0 = 0.f, ds1 = 0.f, ds2 = 0.f, ds3 = 0.f;
    float s0 = 0.f, s1 = 0.f, s2 = 0.f, s3 = 0.f;
    int mc = (deg + 15) >> 4;
    mc = max(mc, __shfl_xor(mc, 16));
    mc = max(mc, __shfl_xor(mc, 32));

    for (int ch = 0; ch < mc; ++ch) {
        int i = ch * 16 + lr;
        int s = 0;
        float w0 = 0.f, w1 = 0.f, w2 = 0.f, w3 = 0.f;
        if (i < deg) {
            uint4 ep = epk[e0 + i];
            s = (int)ep.x;
            float ax = bf_lo(ep.y), ay = bf_hi(ep.y);
            float az = bf_lo(ep.z), aw = bf_hi(ep.z);
            float4 av = as1[s];
            float a0 = av.x + adn.x + ax;
            float a1 = av.y + adn.y + ay;
            float a2 = av.z + adn.z + az;
            float a3 = av.w + adn.w + aw;
            a0 = a0 >= 0.f ? a0 : 0.2f * a0;
            a1 = a1 >= 0.f ? a1 : 0.2f * a1;
            a2 = a2 >= 0.f ? a2 : 0.2f * a2;
            a3 = a3 >= 0.f ? a3 : 0.2f * a3;
            w0 = __expf(a0); w1 = __expf(a1); w2 = __expf(a2); w3 = __expf(a3);
            ds0 += w0; ds1 += w1; ds2 += w2; ds3 += w3;
            s0 += ax; s1 += ay; s2 += az; s3 += aw;
        }
        lds_s[wave][g][lr] = s;
        *(float4*)&lds_w[wave][g][lr][0] = make_float4(w0, w1, w2, w3);
        __builtin_amdgcn_wave_barrier();
        int cn = deg - ch * 16;
        cn = cn > 16 ? 16 : (cn < 0 ? 0 : cn);
        int cnr = (cn + 3) & ~3;
        for (int j = 0; j < cnr; j += 4) {
            int sj0 = lds_s[wave][g][j];
            int sj1 = lds_s[wave][g][j + 1];
            int sj2 = lds_s[wave][g][j + 2];
            int sj3 = lds_s[wave][g][j + 3];
            float ww0 = lds_w[wave][g][j][qh];
            float ww1 = lds_w[wave][g][j + 1][qh];
            float ww2 = lds_w[wave][g][j + 2][qh];
            float ww3 = lds_w[wave][g][j + 3][qh];
            uint4 u0 = *(const uint4*)&xs1u[(size_t)sj0 * 64 + lr * 4];
            uint4 u1 = *(const uint4*)&xs1u[(size_t)sj1 * 64 + lr * 4];
            uint4 u2 = *(const uint4*)&xs1u[(size_t)sj2 * 64 + lr * 4];
            uint4 u3 = *(const uint4*)&xs1u[(size_t)sj3 * 64 + lr * 4];
            f32x2_t W0 = {ww0, ww0}, W1v = {ww1, ww1}, W2v = {ww2, ww2}, W3v = {ww3, ww3};
            acc2[0] += W0 * bfpair(u0.x); acc2[1] += W0 * bfpair(u0.y);
            acc2[2] += W0 * bfpair(u0.z); acc2[3] += W0 * bfpair(u0.w);
            acc2[0] += W1v * bfpair(u1.x); acc2[1] += W1v * bfpair(u1.y);
            acc2[2] += W1v * bfpair(u1.z); acc2[3] += W1v * bfpair(u1.w);
            acc2[0] += W2v * bfpair(u2.x); acc2[1] += W2v * bfpair(u2.y);
            acc2[2] += W2v * bfpair(u2.z); acc2[3] += W2v * bfpair(u2.w);
            acc2[0] += W3v * bfpair(u3.x); acc2[1] += W3v * bfpair(u3.y);
            acc2[2] += W3v * bfpair(u3.z); acc2[3] += W3v * bfpair(u3.w);
        }
        __builtin_amdgcn_wave_barrier();
    }
#pragma unroll
    for (int d = 8; d >= 1; d >>= 1) {
        ds0 += __shfl_xor(ds0, d, 16); ds1 += __shfl_xor(ds1, d, 16);
        ds2 += __shfl_xor(ds2, d, 16); ds3 += __shfl_xor(ds3, d, 16);
        s0 += __shfl_xor(s0, d, 16);   s1 += __shfl_xor(s1, d, 16);
        s2 += __shfl_xor(s2, d, 16);   s3 += __shfl_xor(s3, d, 16);
    }
    float invd = 1.f / fmaxf((float)deg, 1.f);
    float aL0 = asn.x + adn.x + s0 * invd;
    float aL1 = asn.y + adn.y + s1 * invd;
    float aL2 = asn.z + adn.z + s2 * invd;
    float aL3 = asn.w + adn.w + s3 * invd;
    aL0 = aL0 >= 0.f ? aL0 : 0.2f * aL0;
    aL1 = aL1 >= 0.f ? aL1 : 0.2f * aL1;
    aL2 = aL2 >= 0.f ? aL2 : 0.2f * aL2;
    aL3 = aL3 >= 0.f ? aL3 : 0.2f * aL3;
    float ws0 = __expf(aL0), ws1 = __expf(aL1), ws2 = __expf(aL2), ws3 = __expf(aL3);
    float wself = qh == 0 ? ws0 : (qh == 1 ? ws1 : (qh == 2 ? ws2 : ws3));
    float dh = qh == 0 ? ds0 + ws0 : (qh == 1 ? ds1 + ws1 : (qh == 2 ? ds2 + ws2 : ds3 + ws3));
    uint4 us = *(const uint4*)&xs1u[(size_t)n * 64 + lr * 4];
    f32x2_t Ws = {wself, wself};
    acc2[0] += Ws * bfpair(us.x); acc2[1] += Ws * bfpair(us.y);
    acc2[2] += Ws * bfpair(us.z); acc2[3] += Ws * bfpair(us.w);
    float inv = 1.f / (dh + 1e-16f);
    int c = lr * 8;
    uint4 ou;
    unsigned* op = (unsigned*)&ou;
#pragma unroll
    for (int k2 = 0; k2 < 4; ++k2) {
        int c0 = c + 2 * k2, c1 = c + 2 * k2 + 1;
        float o0 = acc2[k2][0] * inv + b1[c0];
        float o1 = acc2[k2][1] * inv + b1[c1];
        float sc0 = g1[c0] * rsqrtf(rv1[c0] + 1e-5f);
        float sc1 = g1[c1] * rsqrtf(rv1[c1] + 1e-5f);
        o0 = (o0 - rm1[c0]) * sc0 + be1[c0];
        o1 = (o1 - rm1[c1]) * sc1 + be1[c1];
        o0 = o0 > 0.f ? o0 : __expf(o0) - 1.f;
        o1 = o1 > 0.f ? o1 : __expf(o1) - 1.f;
        op[k2] = f2bf2(o0, o1);
    }
    *(uint4*)&h1u[(size_t)n * 64 + lr * 4] = ou;
}

// ---------------------------------------------------------------------------
// K8: MFMA GEMM2: xs2[N,40](bf16, stride 64) = h1(bf16) @ W2(bf16,48-pad).
__global__ __launch_bounds__(256) void gemm2_mfma(
    const unsigned* __restrict__ A, const unsigned* __restrict__ w2t,
    unsigned* __restrict__ out) {
    __shared__ unsigned sA[64 * 68];
    __shared__ unsigned sB[48 * 68];
    int t = threadIdx.x;
    int row0 = blockIdx.x * 64;
    for (int i = t; i < 64 * 16; i += 256) {
        int r = i >> 4, q = i & 15;
        int gr = row0 + r;
        uint4 v = (gr < NN) ? *(const uint4*)&A[(size_t)gr * 64 + q * 4]
                            : make_uint4(0u, 0u, 0u, 0u);
        *(uint4*)&sA[r * 68 + q * 4] = v;
    }
    for (int i = t; i < 48 * 16; i += 256) {
        int c = i >> 4, q = i & 15;
        *(uint4*)&sB[c * 68 + q * 4] = *(const uint4*)&w2t[c * 64 + q * 4];
    }
    __syncthreads();
    int wv = t >> 6, lane = t & 63;
    int lr = lane & 15, kgrp = lane >> 4;
    f32x4_t acc[3];
#pragma unroll
    for (int i = 0; i < 3; ++i) acc[i] = (f32x4_t){0.f, 0.f, 0.f, 0.f};
    int arow = wv * 16 + lr;
#pragma unroll
    for (int kt = 0; kt < 4; ++kt) {
        int kw = kt * 16 + kgrp * 4;
        s16x8_t af = *(const s16x8_t*)&sA[arow * 68 + kw];
#pragma unroll
        for (int tc = 0; tc < 3; ++tc) {
            s16x8_t bf = *(const s16x8_t*)&sB[(tc * 16 + lr) * 68 + kw];
            acc[tc] = __builtin_amdgcn_mfma_f32_16x16x32_bf16(af, bf, acc[tc], 0, 0, 0);
        }
    }
    int orow0 = row0 + wv * 16 + kgrp * 4;
#pragma unroll
    for (int tc = 0; tc < 3; ++tc) {
#pragma unroll
        for (int r = 0; r < 4; ++r) {
            float v = acc[tc][r];
            float other = __shfl_xor(v, 1);
            int gr = orow0 + r;
            if (!(lane & 1) && gr < NN && (tc < 2 || lr < 8))
                out[(size_t)gr * 32 + tc * 8 + (lr >> 1)] = f2bf2(v, other);
        }
    }
}

// ---------------------------------------------------------------------------
// K9: per-node attention coefficients layer 2 (from bf16 xs2).
__global__ __launch_bounds__(256) void alpha2_kernel(
    const unsigned* __restrict__ xs2u, const float* __restrict__ asw,
    const float* __restrict__ adw, float* __restrict__ as2, float* __restrict__ ad2) {
    int wid = (blockIdx.x * 256 + threadIdx.x) >> 6;
    if (wid >= NN) return;
    int lane = threadIdx.x & 63;
    float pa = 0.f, pd = 0.f;
    if (lane < 20) {
        unsigned u = xs2u[(size_t)wid * 32 + lane];
        float vx = bf_lo(u), vy = bf_hi(u);
        int c = lane * 2;
        pa = vx * asw[c] + vy * asw[c + 1];
        pd = vx * adw[c] + vy * adw[c + 1];
    }
#pragma unroll
    for (int d = 16; d >= 1; d >>= 1) {
        pa += __shfl_xor(pa, d, 32);
        pd += __shfl_xor(pd, d, 32);
    }
    if (lane == 0) { as2[wid] = pa; ad2[wid] = pd; }
}

// ---------------------------------------------------------------------------
// K10: layer-2 GAT aggregation + bias + BN + log_softmax. LDS-staged weights,
// 12 edges/iteration (4 sub-groups of 3 x 20 lanes), zero-padded round-up.
__global__ __launch_bounds__(256) void gat2_kernel(
    const uint4* __restrict__ epk, const int* __restrict__ off,
    const unsigned* __restrict__ xs2u,
    const float* __restrict__ as2, const float* __restrict__ ad2,
    const float* __restrict__ b2, const float* __restrict__ g2, const float* __restrict__ be2,
    const float* __restrict__ rm2, const float* __restrict__ rv2, float* __restrict__ outp) {
    __shared__ int   lds_s[4][72];
    __shared__ float lds_w[4][72];
    int wid = (blockIdx.x * 256 + threadIdx.x) >> 6;
    if (wid >= NN) return;
    int lane = threadIdx.x & 63;
    int warp = threadIdx.x >> 6;
    int n = wid;
    int e0 = off[n], e1 = off[n + 1];
    int deg = e1 - e0;
    int grp3 = lane / 20;               // 0,1,2 active; 3 = lanes 60..63
    int col = lane - grp3 * 20;
    bool act = grp3 < 3;
    int grpo = act ? grp3 : 0;
    if (lane < 8) {
        lds_s[warp][64 + lane] = 0;
        lds_w[warp][64 + lane] = 0.f;
    }
    float adn = ad2[n];
    float asn = as2[n];
    f32x2_t acc2 = {0.f, 0.f};
    float dsum = 0.f, aesum = 0.f;

    for (int base = 0; base < deg; base += 64) {
        int i = base + lane;
        int cn = min(64, deg - base);
        int s = 0;
        float w = 0.f;
        if (i < deg) {
            uint4 ep = epk[e0 + i];
            s = (int)ep.x;
            float ae = __uint_as_float(ep.w);
            float a = as2[s] + adn + ae;
            a = a >= 0.f ? a : 0.2f * a;
            w = __expf(a);
            dsum += w;
            aesum += ae;
        }
        lds_s[warp][lane] = s;
        lds_w[warp][lane] = w;
        __builtin_amdgcn_wave_barrier();
        int cnr = ((cn + 11) / 12) * 12;            // <= 72; jj max = cnr-1 <= 71
        for (int j = 0; j < cnr; j += 12) {
            int jj0 = j + grpo, jj1 = jj0 + 3, jj2 = jj0 + 6, jj3 = jj0 + 9;
            int sj0 = lds_s[warp][jj0];
            int sj1 = lds_s[warp][jj1];
            int sj2 = lds_s[warp][jj2];
            int sj3 = lds_s[warp][jj3];
            float w0 = act ? lds_w[warp][jj0] : 0.f;
            float w1 = act ? lds_w[warp][jj1] : 0.f;
            float w2 = act ? lds_w[warp][jj2] : 0.f;
            float w3 = act ? lds_w[warp][jj3] : 0.f;
            unsigned u0 = xs2u[(size_t)sj0 * 32 + col];
            unsigned u1 = xs2u[(size_t)sj1 * 32 + col];
            unsigned u2 = xs2u[(size_t)sj2 * 32 + col];
            unsigned u3 = xs2u[(size_t)sj3 * 32 + col];
            acc2 += (f32x2_t){w0, w0} * bfpair(u0);
            acc2 += (f32x2_t){w1, w1} * bfpair(u1);
            acc2 += (f32x2_t){w2, w2} * bfpair(u2);
            acc2 += (f32x2_t){w3, w3} * bfpair(u3);
        }
        __builtin_amdgcn_wave_barrier();
    }
    {
        float p0 = __shfl(acc2[0], (lane + 20) & 63);
        float p1 = __shfl(acc2[1], (lane + 20) & 63);
        float q0 = __shfl(acc2[0], (lane + 40) & 63);
        float q1 = __shfl(acc2[1], (lane + 40) & 63);
        acc2[0] += p0 + q0;
        acc2[1] += p1 + q1;
    }
#pragma unroll
    for (int d = 32; d >= 1; d >>= 1) {
        dsum += __shfl_xor(dsum, d);
        aesum += __shfl_xor(aesum, d);
    }
    float invd = 1.f / fmaxf((float)deg, 1.f);
    float aL = asn + adn + aesum * invd;
    aL = aL >= 0.f ? aL : 0.2f * aL;
    float wself = __expf(aL);
    float denom = dsum + wself;

    float v0 = 0.f, v1 = 0.f;
    if (lane < 20) {
        unsigned u = xs2u[(size_t)n * 32 + lane];
        acc2[0] += wself * bf_lo(u);
        acc2[1] += wself * bf_hi(u);
        int c = lane * 2;
        float inv = 1.f / (denom + 1e-16f);
        v0 = acc2[0] * inv + b2[c];
        v1 = acc2[1] * inv + b2[c + 1];
        float sc0 = g2[c] * rsqrtf(rv2[c] + 1e-5f);
        float sc1 = g2[c + 1] * rsqrtf(rv2[c + 1] + 1e-5f);
        v0 = (v0 - rm2[c]) * sc0 + be2[c];
        v1 = (v1 - rm2[c + 1]) * sc1 + be2[c + 1];
    }
    float mx = (lane < 20) ? fmaxf(v0, v1) : -3.0e38f;
#pragma unroll
    for (int d = 32; d >= 1; d >>= 1) mx = fmaxf(mx, __shfl_xor(mx, d));
    float ex = (lane < 20) ? __expf(v0 - mx) + __expf(v1 - mx) : 0.f;
#pragma unroll
    for (int d = 32; d >= 1; d >>= 1) ex += __shfl_xor(ex, d);
    if (lane < 20) {
        float ls = __logf(ex);
        *(float2*)&outp[(size_t)n * 40 + lane * 2] = make_float2(v0 - mx - ls, v1 - mx - ls);
    }
}

// ---------------------------------------------------------------------------
extern "C" void kernel_launch(void* const* d_in, const int* in_sizes, int n_in,
                              void* d_out, int out_size, void* d_ws, size_t ws_size,
                              hipStream_t stream) {
    const float* x     = (const float*)d_in[0];
    const int*   ei    = (const int*)d_in[1];
    const float* eattr = (const float*)d_in[2];
    const float* W1    = (const float*)d_in[3];
    const float* as1w  = (const float*)d_in[4];
    const float* ad1w  = (const float*)d_in[5];
    const float* ae1w  = (const float*)d_in[6];
    const float* We1   = (const float*)d_in[7];
    const float* b1    = (const float*)d_in[8];
    const float* W2    = (const float*)d_in[9];
    const float* as2w  = (const float*)d_in[10];
    const float* ad2w  = (const float*)d_in[11];
    const float* ae2w  = (const float*)d_in[12];
    const float* We2   = (const float*)d_in[13];
    const float* b2    = (const float*)d_in[14];
    const float* g1    = (const float*)d_in[15];
    const float* be1   = (const float*)d_in[16];
    const float* rm1   = (const float*)d_in[17];
    const float* rv1   = (const float*)d_in[18];
    const float* g2    = (const float*)d_in[19];
    const float* be2   = (const float*)d_in[20];
    const float* rm2   = (const float*)d_in[21];
    const float* rv2   = (const float*)d_in[22];

    const int* src0 = ei;
    const int* dst0 = ei + NE;

    char* p = (char*)d_ws;
    auto take = [&](size_t nbytes) {
        void* r = (void*)p;
        p += (nbytes + 255) & ~(size_t)255;
        return r;
    };
    float*    wf1    = (float*)take(80);
    float*    wf2    = (float*)take(20);
    unsigned* w1t    = (unsigned*)take((size_t)128 * 64 * 4);
    unsigned* w2t    = (unsigned*)take((size_t)48 * 64 * 4);
    int*      cnt    = (int*)take((size_t)NN * 4);
    int*      off    = (int*)take((size_t)(NN + 1) * 4);
    int*      bsum   = (int*)take((size_t)SCAN_NB * 4);
    int*      rank   = (int*)take((size_t)NE * 4);
    uint4*    epk    = (uint4*)take((size_t)NE * 16);
    float*    as1    = (float*)take((size_t)NN * 16);
    float*    ad1    = (float*)take((size_t)NN * 16);
    float*    as2    = (float*)take((size_t)NN * 4);
    float*    ad2    = (float*)take((size_t)NN * 4);
    unsigned* xs1u   = (unsigned*)take((size_t)NN * 256);  // 64 uints/row
    unsigned* h1u    = (unsigned*)take((size_t)NN * 256);
    unsigned* xs2u   = (unsigned*)take((size_t)NN * 128);  // 32 uints/row

    hipMemsetAsync(cnt, 0, (size_t)NN * 4, stream);

    prep_kernel<<<1, 256, 0, stream>>>(We1, ae1w, We2, ae2w, W1, W2, wf1, wf2, w1t, w2t);
    count_kernel<<<(NE + 255) / 256, 256, 0, stream>>>(dst0, cnt, rank);
    scan1_kernel<<<SCAN_NB, 256, 0, stream>>>(cnt, off, bsum);
    scan2_kernel<<<1, 256, 0, stream>>>(bsum);
    scan3_kernel<<<SCAN_NB, 256, 0, stream>>>(off, bsum, cnt);
    fill_fold_kernel<<<(NE + 1023) / 1024, 256, 0, stream>>>(src0, dst0, eattr, wf1, wf2,
                                                             off, rank, epk);
    gemm1_mfma<<<(NN + 63) / 64, 256, 0, stream>>>(x, w1t, xs1u);
    alpha1_kernel<<<(NN + 3) / 4, 256, 0, stream>>>(xs1u, as1w, ad1w, as1, ad1);
    gat1_kernel<<<NN / 16, 256, 0, stream>>>(epk, off, xs1u, (const float4*)as1,
                                             (const float4*)ad1, b1, g1, be1, rm1, rv1, h1u);
    gemm2_mfma<<<(NN + 63) / 64, 256, 0, stream>>>(h1u, w2t, xs2u);
    alpha2_kernel<<<(NN + 3) / 4, 256, 0, stream>>>(xs2u, as2w, ad2w, as2, ad2);
    gat2_kernel<<<(NN + 3) / 4, 256, 0, stream>>>(epk, off, xs2u, as2, ad2,
                                                  b2, g2, be2, rm2, rv2, (float*)d_out);
}

// Round 10
// 180.101 us; speedup vs baseline: 3.5576x; 1.0238x over previous
//
#include <hip/hip_runtime.h>
#include <hip/hip_bf16.h>

#define NN 50000
#define NE 800000
#define SCAN_NB ((NN + 255) / 256)   // 196 blocks
// IN=128, HID=32, HEADS=4, HC=128, OUT=40, EDIM=5

typedef float f32x4_t __attribute__((ext_vector_type(4)));
typedef float f32x2_t __attribute__((ext_vector_type(2)));
typedef short s16x8_t __attribute__((ext_vector_type(8)));

// bf16 pack/unpack helpers (RNE rounding).
__device__ __forceinline__ unsigned f2bf2(float a, float b) {
    unsigned ua = __float_as_uint(a);
    ua = (ua + 0x7fffu + ((ua >> 16) & 1u)) >> 16;
    unsigned ub = __float_as_uint(b);
    ub = (ub + 0x7fffu + ((ub >> 16) & 1u)) >> 16;
    return ua | (ub << 16);
}
__device__ __forceinline__ float bf_lo(unsigned u) { return __uint_as_float(u << 16); }
__device__ __forceinline__ float bf_hi(unsigned u) { return __uint_as_float(u & 0xffff0000u); }
__device__ __forceinline__ f32x2_t bfpair(unsigned u) {
    return (f32x2_t){__uint_as_float(u << 16), __uint_as_float(u & 0xffff0000u)};
}

// ---------------------------------------------------------------------------
// K0: prep — zero cnt (grid-wide, replaces runtime memset which cost ~40us)
// + fold edge-weight matrices + build bf16-transposed GEMM weights (block 0).
__global__ __launch_bounds__(256) void prep_kernel(
    const float* __restrict__ We1, const float* __restrict__ ae1w,
    const float* __restrict__ We2, const float* __restrict__ ae2w,
    const float* __restrict__ W1, const float* __restrict__ W2,
    float* __restrict__ wf1, float* __restrict__ wf2,
    unsigned* __restrict__ w1t, unsigned* __restrict__ w2t,
    int* __restrict__ cnt) {
    int t = threadIdx.x;
    int g = blockIdx.x * 256 + t;
    if (g < NN) cnt[g] = 0;
    if (blockIdx.x != 0) return;
    if (t < 20) {
        int j = t >> 2, h = t & 3;
        float s = 0.f;
        for (int c = 0; c < 32; ++c) s += We1[j * 128 + h * 32 + c] * ae1w[h * 32 + c];
        wf1[j * 4 + h] = s;
    }
    if (t >= 32 && t < 37) {
        int j = t - 32;
        float s = 0.f;
        for (int c = 0; c < 40; ++c) s += We2[j * 40 + c] * ae2w[c];
        wf2[j] = s;
    }
    for (int i = t; i < 128 * 64; i += 256) {
        int c = i >> 6, kp = i & 63;
        w1t[i] = f2bf2(W1[(size_t)(2 * kp) * 128 + c], W1[(size_t)(2 * kp + 1) * 128 + c]);
    }
    for (int i = t; i < 48 * 64; i += 256) {
        int c = i >> 6, kp = i & 63;
        w2t[i] = (c < 40) ? f2bf2(W2[(size_t)(2 * kp) * 40 + c], W2[(size_t)(2 * kp + 1) * 40 + c]) : 0u;
    }
}

// ---------------------------------------------------------------------------
// K1: in-degree count + per-edge rank.
__global__ __launch_bounds__(256) void count_kernel(const int* __restrict__ dst0,
                                                    int* __restrict__ cnt,
                                                    int* __restrict__ rank) {
    int e = blockIdx.x * 256 + threadIdx.x;
    if (e >= NE) return;
    rank[e] = atomicAdd(&cnt[dst0[e]], 1);
}

// ---------------------------------------------------------------------------
// K2a/b/c: two-level exclusive scan.
__global__ __launch_bounds__(256) void scan1_kernel(const int* __restrict__ cnt,
                                                    int* __restrict__ off,
                                                    int* __restrict__ bsum) {
    __shared__ int tmp[256];
    int t = threadIdx.x;
    int g = blockIdx.x * 256 + t;
    int v = (g < NN) ? cnt[g] : 0;
    tmp[t] = v;
    __syncthreads();
#pragma unroll
    for (int d = 1; d < 256; d <<= 1) {
        int u = (t >= d) ? tmp[t - d] : 0;
        __syncthreads();
        tmp[t] += u;
        __syncthreads();
    }
    if (g < NN) off[g] = tmp[t] - v;
    if (t == 255) bsum[blockIdx.x] = tmp[255];
}

__global__ __launch_bounds__(256) void scan2_kernel(int* __restrict__ bsum) {
    __shared__ int tmp[256];
    int t = threadIdx.x;
    int v = (t < SCAN_NB) ? bsum[t] : 0;
    tmp[t] = v;
    __syncthreads();
#pragma unroll
    for (int d = 1; d < 256; d <<= 1) {
        int u = (t >= d) ? tmp[t - d] : 0;
        __syncthreads();
        tmp[t] += u;
        __syncthreads();
    }
    if (t < SCAN_NB) bsum[t] = tmp[t] - v;
}

__global__ __launch_bounds__(256) void scan3_kernel(int* __restrict__ off,
                                                    const int* __restrict__ bsum,
                                                    const int* __restrict__ cnt) {
    int g = blockIdx.x * 256 + threadIdx.x;
    if (g < NN) {
        int o = off[g] + bsum[blockIdx.x];
        off[g] = o;
        if (g == NN - 1) off[NN] = o + cnt[g];
    }
}

// ---------------------------------------------------------------------------
// K3: fill CSR in slot order, atomic-free (pos = off[dst] + rank).
__global__ __launch_bounds__(256) void fill_fold_kernel(
    const int* __restrict__ src0, const int* __restrict__ dst0,
    const float* __restrict__ eattr, const float* __restrict__ wf1,
    const float* __restrict__ wf2, const int* __restrict__ off,
    const int* __restrict__ rank, uint4* __restrict__ epk) {
    int base = blockIdx.x * 1024 + threadIdx.x;
#pragma unroll
    for (int k = 0; k < 4; ++k) {
        int e = base + k * 256;
        if (e >= NE) continue;
        float a[5];
#pragma unroll
        for (int j = 0; j < 5; ++j) a[j] = eattr[(size_t)e * 5 + j];
        float o[4];
#pragma unroll
        for (int h = 0; h < 4; ++h) {
            float s = 0.f;
#pragma unroll
            for (int j = 0; j < 5; ++j) s += a[j] * wf1[j * 4 + h];
            o[h] = s;
        }
        float s2 = 0.f;
#pragma unroll
        for (int j = 0; j < 5; ++j) s2 += a[j] * wf2[j];
        int pos = off[dst0[e]] + rank[e];
        epk[pos] = make_uint4((unsigned)src0[e], f2bf2(o[0], o[1]), f2bf2(o[2], o[3]),
                              __float_as_uint(s2));
    }
}

// ---------------------------------------------------------------------------
// K5: MFMA GEMM1: xs1[N,128](bf16) = x[N,128] @ W1[128,128].
__global__ __launch_bounds__(256) void gemm1_mfma(
    const float* __restrict__ A, const unsigned* __restrict__ w1t,
    unsigned* __restrict__ out) {
    __shared__ unsigned sA[64 * 68];
    __shared__ unsigned sB[128 * 68];
    int t = threadIdx.x;
    int row0 = blockIdx.x * 64;
    for (int i = t; i < 64 * 32; i += 256) {
        int r = i >> 5, q = i & 31;
        int gr = row0 + r;
        float4 v = (gr < NN) ? *(const float4*)&A[(size_t)gr * 128 + q * 4]
                             : make_float4(0.f, 0.f, 0.f, 0.f);
        sA[r * 68 + q * 2]     = f2bf2(v.x, v.y);
        sA[r * 68 + q * 2 + 1] = f2bf2(v.z, v.w);
    }
    for (int i = t; i < 128 * 16; i += 256) {
        int c = i >> 4, q = i & 15;
        *(uint4*)&sB[c * 68 + q * 4] = *(const uint4*)&w1t[c * 64 + q * 4];
    }
    __syncthreads();
    int wv = t >> 6, lane = t & 63;
    int lr = lane & 15, kgrp = lane >> 4;
    f32x4_t acc[8];
#pragma unroll
    for (int i = 0; i < 8; ++i) acc[i] = (f32x4_t){0.f, 0.f, 0.f, 0.f};
    int arow = wv * 16 + lr;
#pragma unroll
    for (int kt = 0; kt < 4; ++kt) {
        int kw = kt * 16 + kgrp * 4;
        s16x8_t af = *(const s16x8_t*)&sA[arow * 68 + kw];
#pragma unroll
        for (int tc = 0; tc < 8; ++tc) {
            s16x8_t bf = *(const s16x8_t*)&sB[(tc * 16 + lr) * 68 + kw];
            acc[tc] = __builtin_amdgcn_mfma_f32_16x16x32_bf16(af, bf, acc[tc], 0, 0, 0);
        }
    }
    int orow0 = row0 + wv * 16 + kgrp * 4;
#pragma unroll
    for (int tc = 0; tc < 8; ++tc) {
#pragma unroll
        for (int r = 0; r < 4; ++r) {
            float v = acc[tc][r];
            float other = __shfl_xor(v, 1);
            int gr = orow0 + r;
            if (!(lane & 1) && gr < NN)
                out[(size_t)gr * 64 + tc * 8 + (lr >> 1)] = f2bf2(v, other);
        }
    }
}

// ---------------------------------------------------------------------------
// K6: per-node attention coefficients for layer 1 (from bf16 xs1).
__global__ __launch_bounds__(256) void alpha1_kernel(
    const unsigned* __restrict__ xs1u, const float* __restrict__ asw,
    const float* __restrict__ adw, float* __restrict__ as1, float* __restrict__ ad1) {
    int wid = (blockIdx.x * 256 + threadIdx.x) >> 6;
    if (wid >= NN) return;
    int lane = threadIdx.x & 63;
    int c = lane * 2;
    unsigned u = xs1u[(size_t)wid * 64 + lane];
    float vx = bf_lo(u), vy = bf_hi(u);
    float pa = vx * asw[c] + vy * asw[c + 1];
    float pd = vx * adw[c] + vy * adw[c + 1];
#pragma unroll
    for (int d = 8; d >= 1; d >>= 1) {
        pa += __shfl_xor(pa, d, 16);
        pd += __shfl_xor(pd, d, 16);
    }
    if ((lane & 15) == 0) {
        as1[wid * 4 + (lane >> 4)] = pa;
        ad1[wid * 4 + (lane >> 4)] = pd;
    }
}

// ---------------------------------------------------------------------------
// K7: layer-1 GAT aggregation. 4 nodes/wave, 16 lanes/node. Gather phase
// unrolled 4 edges/iteration via zero-padded round-up.
__global__ __launch_bounds__(256) void gat1_kernel(
    const uint4* __restrict__ epk, const int* __restrict__ off,
    const unsigned* __restrict__ xs1u,
    const float4* __restrict__ as1, const float4* __restrict__ ad1,
    const float* __restrict__ b1, const float* __restrict__ g1, const float* __restrict__ be1,
    const float* __restrict__ rm1, const float* __restrict__ rv1, unsigned* __restrict__ h1u) {
    __shared__ int   lds_s[4][4][16];
    __shared__ float lds_w[4][4][16][4];
    int wave = threadIdx.x >> 6;
    int lane = threadIdx.x & 63;
    int g = lane >> 4;
    int lr = lane & 15;
    int qh = lr >> 2;
    int n = blockIdx.x * 16 + wave * 4 + g;
    int e0 = off[n];
    int deg = off[n + 1] - e0;
    float4 adn = ad1[n];
    float4 asn = as1[n];
    f32x2_t acc2[4];
#pragma unroll
    for (int k = 0; k < 4; ++k) acc2[k] = (f32x2_t){0.f, 0.f};
    float ds0 = 0.f, ds1 = 0.f, ds2 = 0.f, ds3 = 0.f;
    float s0 = 0.f, s1 = 0.f, s2 = 0.f, s3 = 0.f;
    int mc = (deg + 15) >> 4;
    mc = max(mc, __shfl_xor(mc, 16));
    mc = max(mc, __shfl_xor(mc, 32));

    for (int ch = 0; ch < mc; ++ch) {
        int i = ch * 16 + lr;
        int s = 0;
        float w0 = 0.f, w1 = 0.f, w2 = 0.f, w3 = 0.f;
        if (i < deg) {
            uint4 ep = epk[e0 + i];
            s = (int)ep.x;
            float ax = bf_lo(ep.y), ay = bf_hi(ep.y);
            float az = bf_lo(ep.z), aw = bf_hi(ep.z);
            float4 av = as1[s];
            float a0 = av.x + adn.x + ax;
            float a1 = av.y + adn.y + ay;
            float a2 = av.z + adn.z + az;
            float a3 = av.w + adn.w + aw;
            a0 = a0 >= 0.f ? a0 : 0.2f * a0;
            a1 = a1 >= 0.f ? a1 : 0.2f * a1;
            a2 = a2 >= 0.f ? a2 : 0.2f * a2;
            a3 = a3 >= 0.f ? a3 : 0.2f * a3;
            w0 = __expf(a0); w1 = __expf(a1); w2 = __expf(a2); w3 = __expf(a3);
            ds0 += w0; ds1 += w1; ds2 += w2; ds3 += w3;
            s0 += ax; s1 += ay; s2 += az; s3 += aw;
        }
        lds_s[wave][g][lr] = s;
        *(float4*)&lds_w[wave][g][lr][0] = make_float4(w0, w1, w2, w3);
        __builtin_amdgcn_wave_barrier();
        int cn = deg - ch * 16;
        cn = cn > 16 ? 16 : (cn < 0 ? 0 : cn);
        int cnr = (cn + 3) & ~3;
        for (int j = 0; j < cnr; j += 4) {
            int sj0 = lds_s[wave][g][j];
            int sj1 = lds_s[wave][g][j + 1];
            int sj2 = lds_s[wave][g][j + 2];
            int sj3 = lds_s[wave][g][j + 3];
            float ww0 = lds_w[wave][g][j][qh];
            float ww1 = lds_w[wave][g][j + 1][qh];
            float ww2 = lds_w[wave][g][j + 2][qh];
            float ww3 = lds_w[wave][g][j + 3][qh];
            uint4 u0 = *(const uint4*)&xs1u[(size_t)sj0 * 64 + lr * 4];
            uint4 u1 = *(const uint4*)&xs1u[(size_t)sj1 * 64 + lr * 4];
            uint4 u2 = *(const uint4*)&xs1u[(size_t)sj2 * 64 + lr * 4];
            uint4 u3 = *(const uint4*)&xs1u[(size_t)sj3 * 64 + lr * 4];
            f32x2_t W0 = {ww0, ww0}, W1v = {ww1, ww1}, W2v = {ww2, ww2}, W3v = {ww3, ww3};
            acc2[0] += W0 * bfpair(u0.x); acc2[1] += W0 * bfpair(u0.y);
            acc2[2] += W0 * bfpair(u0.z); acc2[3] += W0 * bfpair(u0.w);
            acc2[0] += W1v * bfpair(u1.x); acc2[1] += W1v * bfpair(u1.y);
            acc2[2] += W1v * bfpair(u1.z); acc2[3] += W1v * bfpair(u1.w);
            acc2[0] += W2v * bfpair(u2.x); acc2[1] += W2v * bfpair(u2.y);
            acc2[2] += W2v * bfpair(u2.z); acc2[3] += W2v * bfpair(u2.w);
            acc2[0] += W3v * bfpair(u3.x); acc2[1] += W3v * bfpair(u3.y);
            acc2[2] += W3v * bfpair(u3.z); acc2[3] += W3v * bfpair(u3.w);
        }
        __builtin_amdgcn_wave_barrier();
    }
#pragma unroll
    for (int d = 8; d >= 1; d >>= 1) {
        ds0 += __shfl_xor(ds0, d, 16); ds1 += __shfl_xor(ds1, d, 16);
        ds2 += __shfl_xor(ds2, d, 16); ds3 += __shfl_xor(ds3, d, 16);
        s0 += __shfl_xor(s0, d, 16);   s1 += __shfl_xor(s1, d, 16);
        s2 += __shfl_xor(s2, d, 16);   s3 += __shfl_xor(s3, d, 16);
    }
    float invd = 1.f / fmaxf((float)deg, 1.f);
    float aL0 = asn.x + adn.x + s0 * invd;
    float aL1 = asn.y + adn.y + s1 * invd;
    float aL2 = asn.z + adn.z + s2 * invd;
    float aL3 = asn.w + adn.w + s3 * invd;
    aL0 = aL0 >= 0.f ? aL0 : 0.2f * aL0;
    aL1 = aL1 >= 0.f ? aL1 : 0.2f * aL1;
    aL2 = aL2 >= 0.f ? aL2 : 0.2f * aL2;
    aL3 = aL3 >= 0.f ? aL3 : 0.2f * aL3;
    float ws0 = __expf(aL0), ws1 = __expf(aL1), ws2 = __expf(aL2), ws3 = __expf(aL3);
    float wself = qh == 0 ? ws0 : (qh == 1 ? ws1 : (qh == 2 ? ws2 : ws3));
    float dh = qh == 0 ? ds0 + ws0 : (qh == 1 ? ds1 + ws1 : (qh == 2 ? ds2 + ws2 : ds3 + ws3));
    uint4 us = *(const uint4*)&xs1u[(size_t)n * 64 + lr * 4];
    f32x2_t Ws = {wself, wself};
    acc2[0] += Ws * bfpair(us.x); acc2[1] += Ws * bfpair(us.y);
    acc2[2] += Ws * bfpair(us.z); acc2[3] += Ws * bfpair(us.w);
    float inv = 1.f / (dh + 1e-16f);
    int c = lr * 8;
    uint4 ou;
    unsigned* op = (unsigned*)&ou;
#pragma unroll
    for (int k2 = 0; k2 < 4; ++k2) {
        int c0 = c + 2 * k2, c1 = c + 2 * k2 + 1;
        float o0 = acc2[k2][0] * inv + b1[c0];
        float o1 = acc2[k2][1] * inv + b1[c1];
        float sc0 = g1[c0] * rsqrtf(rv1[c0] + 1e-5f);
        float sc1 = g1[c1] * rsqrtf(rv1[c1] + 1e-5f);
        o0 = (o0 - rm1[c0]) * sc0 + be1[c0];
        o1 = (o1 - rm1[c1]) * sc1 + be1[c1];
        o0 = o0 > 0.f ? o0 : __expf(o0) - 1.f;
        o1 = o1 > 0.f ? o1 : __expf(o1) - 1.f;
        op[k2] = f2bf2(o0, o1);
    }
    *(uint4*)&h1u[(size_t)n * 64 + lr * 4] = ou;
}

// ---------------------------------------------------------------------------
// K8: MFMA GEMM2: xs2[N,40](bf16, stride 64) = h1(bf16) @ W2(bf16,48-pad).
__global__ __launch_bounds__(256) void gemm2_mfma(
    const unsigned* __restrict__ A, const unsigned* __restrict__ w2t,
    unsigned* __restrict__ out) {
    __shared__ unsigned sA[64 * 68];
    __shared__ unsigned sB[48 * 68];
    int t = threadIdx.x;
    int row0 = blockIdx.x * 64;
    for (int i = t; i < 64 * 16; i += 256) {
        int r = i >> 4, q = i & 15;
        int gr = row0 + r;
        uint4 v = (gr < NN) ? *(const uint4*)&A[(size_t)gr * 64 + q * 4]
                            : make_uint4(0u, 0u, 0u, 0u);
        *(uint4*)&sA[r * 68 + q * 4] = v;
    }
    for (int i = t; i < 48 * 16; i += 256) {
        int c = i >> 4, q = i & 15;
        *(uint4*)&sB[c * 68 + q * 4] = *(const uint4*)&w2t[c * 64 + q * 4];
    }
    __syncthreads();
    int wv = t >> 6, lane = t & 63;
    int lr = lane & 15, kgrp = lane >> 4;
    f32x4_t acc[3];
#pragma unroll
    for (int i = 0; i < 3; ++i) acc[i] = (f32x4_t){0.f, 0.f, 0.f, 0.f};
    int arow = wv * 16 + lr;
#pragma unroll
    for (int kt = 0; kt < 4; ++kt) {
        int kw = kt * 16 + kgrp * 4;
        s16x8_t af = *(const s16x8_t*)&sA[arow * 68 + kw];
#pragma unroll
        for (int tc = 0; tc < 3; ++tc) {
            s16x8_t bf = *(const s16x8_t*)&sB[(tc * 16 + lr) * 68 + kw];
            acc[tc] = __builtin_amdgcn_mfma_f32_16x16x32_bf16(af, bf, acc[tc], 0, 0, 0);
        }
    }
    int orow0 = row0 + wv * 16 + kgrp * 4;
#pragma unroll
    for (int tc = 0; tc < 3; ++tc) {
#pragma unroll
        for (int r = 0; r < 4; ++r) {
            float v = acc[tc][r];
            float other = __shfl_xor(v, 1);
            int gr = orow0 + r;
            if (!(lane & 1) && gr < NN && (tc < 2 || lr < 8))
                out[(size_t)gr * 32 + tc * 8 + (lr >> 1)] = f2bf2(v, other);
        }
    }
}

// ---------------------------------------------------------------------------
// K9: per-node attention coefficients layer 2 (from bf16 xs2).
__global__ __launch_bounds__(256) void alpha2_kernel(
    const unsigned* __restrict__ xs2u, const float* __restrict__ asw,
    const float* __restrict__ adw, float* __restrict__ as2, float* __restrict__ ad2) {
    int wid = (blockIdx.x * 256 + threadIdx.x) >> 6;
    if (wid >= NN) return;
    int lane = threadIdx.x & 63;
    float pa = 0.f, pd = 0.f;
    if (lane < 20) {
        unsigned u = xs2u[(size_t)wid * 32 + lane];
        float vx = bf_lo(u), vy = bf_hi(u);
        int c = lane * 2;
        pa = vx * asw[c] + vy * asw[c + 1];
        pd = vx * adw[c] + vy * adw[c + 1];
    }
#pragma unroll
    for (int d = 16; d >= 1; d >>= 1) {
        pa += __shfl_xor(pa, d, 32);
        pd += __shfl_xor(pd, d, 32);
    }
    if (lane == 0) { as2[wid] = pa; ad2[wid] = pd; }
}

// ---------------------------------------------------------------------------
// K10: layer-2 GAT aggregation + bias + BN + log_softmax. LDS-staged weights,
// 12 edges/iteration (4 sub-groups of 3 x 20 lanes), zero-padded round-up.
__global__ __launch_bounds__(256) void gat2_kernel(
    const uint4* __restrict__ epk, const int* __restrict__ off,
    const unsigned* __restrict__ xs2u,
    const float* __restrict__ as2, const float* __restrict__ ad2,
    const float* __restrict__ b2, const float* __restrict__ g2, const float* __restrict__ be2,
    const float* __restrict__ rm2, const float* __restrict__ rv2, float* __restrict__ outp) {
    __shared__ int   lds_s[4][72];
    __shared__ float lds_w[4][72];
    int wid = (blockIdx.x * 256 + threadIdx.x) >> 6;
    if (wid >= NN) return;
    int lane = threadIdx.x & 63;
    int warp = threadIdx.x >> 6;
    int n = wid;
    int e0 = off[n], e1 = off[n + 1];
    int deg = e1 - e0;
    int grp3 = lane / 20;
    int col = lane - grp3 * 20;
    bool act = grp3 < 3;
    int grpo = act ? grp3 : 0;
    if (lane < 8) {
        lds_s[warp][64 + lane] = 0;
        lds_w[warp][64 + lane] = 0.f;
    }
    float adn = ad2[n];
    float asn = as2[n];
    f32x2_t acc2 = {0.f, 0.f};
    float dsum = 0.f, aesum = 0.f;

    for (int base = 0; base < deg; base += 64) {
        int i = base + lane;
        int cn = min(64, deg - base);
        int s = 0;
        float w = 0.f;
        if (i < deg) {
            uint4 ep = epk[e0 + i];
            s = (int)ep.x;
            float ae = __uint_as_float(ep.w);
            float a = as2[s] + adn + ae;
            a = a >= 0.f ? a : 0.2f * a;
            w = __expf(a);
            dsum += w;
            aesum += ae;
        }
        lds_s[warp][lane] = s;
        lds_w[warp][lane] = w;
        __builtin_amdgcn_wave_barrier();
        int cnr = ((cn + 11) / 12) * 12;            // <= 72; jj max = 71
        for (int j = 0; j < cnr; j += 12) {
            int jj0 = j + grpo, jj1 = jj0 + 3, jj2 = jj0 + 6, jj3 = jj0 + 9;
            int sj0 = lds_s[warp][jj0];
            int sj1 = lds_s[warp][jj1];
            int sj2 = lds_s[warp][jj2];
            int sj3 = lds_s[warp][jj3];
            float w0 = act ? lds_w[warp][jj0] : 0.f;
            float w1 = act ? lds_w[warp][jj1] : 0.f;
            float w2 = act ? lds_w[warp][jj2] : 0.f;
            float w3 = act ? lds_w[warp][jj3] : 0.f;
            unsigned u0 = xs2u[(size_t)sj0 * 32 + col];
            unsigned u1 = xs2u[(size_t)sj1 * 32 + col];
            unsigned u2 = xs2u[(size_t)sj2 * 32 + col];
            unsigned u3 = xs2u[(size_t)sj3 * 32 + col];
            acc2 += (f32x2_t){w0, w0} * bfpair(u0);
            acc2 += (f32x2_t){w1, w1} * bfpair(u1);
            acc2 += (f32x2_t){w2, w2} * bfpair(u2);
            acc2 += (f32x2_t){w3, w3} * bfpair(u3);
        }
        __builtin_amdgcn_wave_barrier();
    }
    {
        float p0 = __shfl(acc2[0], (lane + 20) & 63);
        float p1 = __shfl(acc2[1], (lane + 20) & 63);
        float q0 = __shfl(acc2[0], (lane + 40) & 63);
        float q1 = __shfl(acc2[1], (lane + 40) & 63);
        acc2[0] += p0 + q0;
        acc2[1] += p1 + q1;
    }
#pragma unroll
    for (int d = 32; d >= 1; d >>= 1) {
        dsum += __shfl_xor(dsum, d);
        aesum += __shfl_xor(aesum, d);
    }
    float invd = 1.f / fmaxf((float)deg, 1.f);
    float aL = asn + adn + aesum * invd;
    aL = aL >= 0.f ? aL : 0.2f * aL;
    float wself = __expf(aL);
    float denom = dsum + wself;

    float v0 = 0.f, v1 = 0.f;
    if (lane < 20) {
        unsigned u = xs2u[(size_t)n * 32 + lane];
        acc2[0] += wself * bf_lo(u);
        acc2[1] += wself * bf_hi(u);
        int c = lane * 2;
        float inv = 1.f / (denom + 1e-16f);
        v0 = acc2[0] * inv + b2[c];
        v1 = acc2[1] * inv + b2[c + 1];
        float sc0 = g2[c] * rsqrtf(rv2[c] + 1e-5f);
        float sc1 = g2[c + 1] * rsqrtf(rv2[c + 1] + 1e-5f);
        v0 = (v0 - rm2[c]) * sc0 + be2[c];
        v1 = (v1 - rm2[c + 1]) * sc1 + be2[c + 1];
    }
    float mx = (lane < 20) ? fmaxf(v0, v1) : -3.0e38f;
#pragma unroll
    for (int d = 32; d >= 1; d >>= 1) mx = fmaxf(mx, __shfl_xor(mx, d));
    float ex = (lane < 20) ? __expf(v0 - mx) + __expf(v1 - mx) : 0.f;
#pragma unroll
    for (int d = 32; d >= 1; d >>= 1) ex += __shfl_xor(ex, d);
    if (lane < 20) {
        float ls = __logf(ex);
        *(float2*)&outp[(size_t)n * 40 + lane * 2] = make_float2(v0 - mx - ls, v1 - mx - ls);
    }
}

// ---------------------------------------------------------------------------
extern "C" void kernel_launch(void* const* d_in, const int* in_sizes, int n_in,
                              void* d_out, int out_size, void* d_ws, size_t ws_size,
                              hipStream_t stream) {
    const float* x     = (const float*)d_in[0];
    const int*   ei    = (const int*)d_in[1];
    const float* eattr = (const float*)d_in[2];
    const float* W1    = (const float*)d_in[3];
    const float* as1w  = (const float*)d_in[4];
    const float* ad1w  = (const float*)d_in[5];
    const float* ae1w  = (const float*)d_in[6];
    const float* We1   = (const float*)d_in[7];
    const float* b1    = (const float*)d_in[8];
    const float* W2    = (const float*)d_in[9];
    const float* as2w  = (const float*)d_in[10];
    const float* ad2w  = (const float*)d_in[11];
    const float* ae2w  = (const float*)d_in[12];
    const float* We2   = (const float*)d_in[13];
    const float* b2    = (const float*)d_in[14];
    const float* g1    = (const float*)d_in[15];
    const float* be1   = (const float*)d_in[16];
    const float* rm1   = (const float*)d_in[17];
    const float* rv1   = (const float*)d_in[18];
    const float* g2    = (const float*)d_in[19];
    const float* be2   = (const float*)d_in[20];
    const float* rm2   = (const float*)d_in[21];
    const float* rv2   = (const float*)d_in[22];

    const int* src0 = ei;
    const int* dst0 = ei + NE;

    char* p = (char*)d_ws;
    auto take = [&](size_t nbytes) {
        void* r = (void*)p;
        p += (nbytes + 255) & ~(size_t)255;
        return r;
    };
    float*    wf1    = (float*)take(80);
    float*    wf2    = (float*)take(20);
    unsigned* w1t    = (unsigned*)take((size_t)128 * 64 * 4);
    unsigned* w2t    = (unsigned*)take((size_t)48 * 64 * 4);
    int*      cnt    = (int*)take((size_t)NN * 4);
    int*      off    = (int*)take((size_t)(NN + 1) * 4);
    int*      bsum   = (int*)take((size_t)SCAN_NB * 4);
    int*      rank   = (int*)take((size_t)NE * 4);
    uint4*    epk    = (uint4*)take((size_t)NE * 16);
    float*    as1    = (float*)take((size_t)NN * 16);
    float*    ad1    = (float*)take((size_t)NN * 16);
    float*    as2    = (float*)take((size_t)NN * 4);
    float*    ad2    = (float*)take((size_t)NN * 4);
    unsigned* xs1u   = (unsigned*)take((size_t)NN * 256);  // 64 uints/row
    unsigned* h1u    = (unsigned*)take((size_t)NN * 256);
    unsigned* xs2u   = (unsigned*)take((size_t)NN * 128);  // 32 uints/row

    prep_kernel<<<SCAN_NB, 256, 0, stream>>>(We1, ae1w, We2, ae2w, W1, W2, wf1, wf2,
                                             w1t, w2t, cnt);
    count_kernel<<<(NE + 255) / 256, 256, 0, stream>>>(dst0, cnt, rank);
    scan1_kernel<<<SCAN_NB, 256, 0, stream>>>(cnt, off, bsum);
    scan2_kernel<<<1, 256, 0, stream>>>(bsum);
    scan3_kernel<<<SCAN_NB, 256, 0, stream>>>(off, bsum, cnt);
    fill_fold_kernel<<<(NE + 1023) / 1024, 256, 0, stream>>>(src0, dst0, eattr, wf1, wf2,
                                                             off, rank, epk);
    gemm1_mfma<<<(NN + 63) / 64, 256, 0, stream>>>(x, w1t, xs1u);
    alpha1_kernel<<<(NN + 3) / 4, 256, 0, stream>>>(xs1u, as1w, ad1w, as1, ad1);
    gat1_kernel<<<NN / 16, 256, 0, stream>>>(epk, off, xs1u, (const float4*)as1,
                                             (const float4*)ad1, b1, g1, be1, rm1, rv1, h1u);
    gemm2_mfma<<<(NN + 63) / 64, 256, 0, stream>>>(h1u, w2t, xs2u);
    alpha2_kernel<<<(NN + 3) / 4, 256, 0, stream>>>(xs2u, as2w, ad2w, as2, ad2);
    gat2_kernel<<<(NN + 3) / 4, 256, 0, stream>>>(epk, off, xs2u, as2, ad2,
                                                  b2, g2, be2, rm2, rv2, (float*)d_out);
}